// Round 4
// baseline (354.147 us; speedup 1.0000x reference)
//
#include <hip/hip_runtime.h>
#include <hip/hip_bf16.h>
#include <cstdint>

#define B_SZ   2
#define S_LEN  2048
#define C_LEN  2048
#define T_LEN  4096
#define EMB_   1024
#define HEADS_ 16
#define D_     64

typedef __attribute__((ext_vector_type(8))) short bf16x8;
typedef __attribute__((ext_vector_type(4))) float f32x4;
typedef __attribute__((ext_vector_type(16))) float f32x16;
typedef __attribute__((ext_vector_type(2))) float f32x2;

__device__ __forceinline__ unsigned short f2bf(float f) {
    unsigned u = __builtin_bit_cast(unsigned, f);
    u += 0x7fffu + ((u >> 16) & 1u);
    return (unsigned short)(u >> 16);
}
__device__ __forceinline__ float bf2f(unsigned short h) {
    return __builtin_bit_cast(float, (unsigned)h << 16);
}
__device__ __forceinline__ f32x2 pk_mul(f32x2 a, f32x2 b) {
    f32x2 d;
    asm("v_pk_mul_f32 %0, %1, %2" : "=v"(d) : "v"(a), "v"(b));
    return d;
}
__device__ __forceinline__ f32x2 pk_add(f32x2 a, f32x2 b) {
    f32x2 d;
    asm("v_pk_add_f32 %0, %1, %2" : "=v"(d) : "v"(a), "v"(b));
    return d;
}

// ---------------------------------------------------------------- xcb build
__global__ void build_xcb_k(const float* __restrict__ x, const float* __restrict__ ctx,
                            unsigned short* __restrict__ xcb) {
    int i = blockIdx.x * blockDim.x + threadIdx.x;      // one 8-elem chunk
    size_t e8 = (size_t)i * 8;
    int b = (int)(e8 / ((size_t)T_LEN * EMB_));
    size_t rem = e8 % ((size_t)T_LEN * EMB_);
    int t = (int)(rem / EMB_);
    int c = (int)(rem % EMB_);
    const float* src = (t < S_LEN)
        ? &x[((size_t)b * S_LEN + t) * EMB_ + c]
        : &ctx[((size_t)b * C_LEN + (t - S_LEN)) * EMB_ + c];
    float4 v0 = ((const float4*)src)[0];
    float4 v1 = ((const float4*)src)[1];
    uint4 o;
    o.x = (unsigned)f2bf(v0.x) | ((unsigned)f2bf(v0.y) << 16);
    o.y = (unsigned)f2bf(v0.z) | ((unsigned)f2bf(v0.w) << 16);
    o.z = (unsigned)f2bf(v1.x) | ((unsigned)f2bf(v1.y) << 16);
    o.w = (unsigned)f2bf(v1.z) | ((unsigned)f2bf(v1.w) << 16);
    *(uint4*)&xcb[e8] = o;
}

// --------------------------------------------------------------- mask concat
__global__ void mcat_k(const float* __restrict__ mask, const float* __restrict__ cmask,
                       float* __restrict__ Mcat) {
    int i = blockIdx.x * 256 + threadIdx.x;   // B*T total
    int b = i / T_LEN, t = i % T_LEN;
    Mcat[i] = (t < S_LEN) ? mask[(size_t)b * S_LEN + t]
                          : cmask[(size_t)b * C_LEN + (t - S_LEN)];
}

// ------------------------------------------------- weight transpose+convert
__global__ void wtrans_k(const float* __restrict__ W, unsigned short* __restrict__ WT) {
    __shared__ __align__(16) unsigned short tile[64][72];
    int bx = blockIdx.x, by = blockIdx.y;   // bx: n-tile, by: k-tile
    int tid = threadIdx.x;
#pragma unroll
    for (int r = 0; r < 4; ++r) {
        int idx = tid + r * 256;
        int row = idx >> 4, c4 = idx & 15;
        float4 v = ((const float4*)&W[((size_t)(by * 64 + row)) * EMB_ + bx * 64])[c4];
        tile[row][c4 * 4 + 0] = f2bf(v.x);
        tile[row][c4 * 4 + 1] = f2bf(v.y);
        tile[row][c4 * 4 + 2] = f2bf(v.z);
        tile[row][c4 * 4 + 3] = f2bf(v.w);
    }
    __syncthreads();
#pragma unroll
    for (int r = 0; r < 2; ++r) {
        int idx = tid + r * 256;
        int n = idx >> 3, k8 = idx & 7;
        uint4 o;
        unsigned q[4];
#pragma unroll
        for (int j = 0; j < 4; ++j)
            q[j] = (unsigned)tile[k8 * 8 + 2 * j][n] | ((unsigned)tile[k8 * 8 + 2 * j + 1][n] << 16);
        o.x = q[0]; o.y = q[1]; o.z = q[2]; o.w = q[3];
        *(uint4*)&WT[((size_t)(bx * 64 + n)) * EMB_ + by * 64 + k8 * 8] = o;
    }
}

// ---------------------------------------------------------------- GEMM (m97-style)
template <bool F32OUT>
__global__ __launch_bounds__(256) void gemm_bt_k(
    const unsigned short* __restrict__ A,
    const unsigned short* __restrict__ Bt,
    void* __restrict__ Cout,
    const float* __restrict__ bias,
    int mtiles_per_chunk, int chunk_stride) {
    constexpr int KTOT = 1024, NTOT = 1024;
    __shared__ __align__(16) unsigned short As[128 * 32];
    __shared__ __align__(16) unsigned short Bs[128 * 32];
    int nt = blockIdx.x, mt = blockIdx.y;
    int in_row0 = (mt / mtiles_per_chunk) * chunk_stride + (mt % mtiles_per_chunk) * 128;
    int out_row0 = mt * 128;
    int tid = threadIdx.x, w = tid >> 6, l = tid & 63, l15 = l & 15, lg = l >> 4;
    int wr = (w >> 1) * 64, wc = (w & 1) * 64;

    f32x4 zero4 = {0.f, 0.f, 0.f, 0.f};
    f32x4 acc[4][4];
#pragma unroll
    for (int i = 0; i < 4; ++i)
#pragma unroll
        for (int j = 0; j < 4; ++j) acc[i][j] = zero4;

    for (int k0 = 0; k0 < KTOT; k0 += 32) {
#pragma unroll
        for (int j = 0; j < 2; ++j) {
            int o = tid * 16 + j * 4096;        // byte offset in 8KB tile
            int row = o >> 6;                   // 64B per row (32 bf16)
            int ke = (o & 63) >> 1;             // element offset in row
            __builtin_amdgcn_global_load_lds(
                (const __attribute__((address_space(1))) void*)&A[(size_t)(in_row0 + row) * KTOT + k0 + ke],
                (__attribute__((address_space(3))) void*)&As[o >> 1], 16, 0, 0);
            __builtin_amdgcn_global_load_lds(
                (const __attribute__((address_space(1))) void*)&Bt[(size_t)(nt * 128 + row) * KTOT + k0 + ke],
                (__attribute__((address_space(3))) void*)&Bs[o >> 1], 16, 0, 0);
        }
        __syncthreads();
        bf16x8 af[4], bf[4];
#pragma unroll
        for (int fr = 0; fr < 4; ++fr)
            af[fr] = *(const bf16x8*)&As[(wr + fr * 16 + l15) * 32 + lg * 8];
#pragma unroll
        for (int fc = 0; fc < 4; ++fc)
            bf[fc] = *(const bf16x8*)&Bs[(wc + fc * 16 + l15) * 32 + lg * 8];
#pragma unroll
        for (int fr = 0; fr < 4; ++fr)
#pragma unroll
            for (int fc = 0; fc < 4; ++fc)
                acc[fr][fc] = __builtin_amdgcn_mfma_f32_16x16x32_bf16(af[fr], bf[fc], acc[fr][fc], 0, 0, 0);
        __syncthreads();
    }
#pragma unroll
    for (int fr = 0; fr < 4; ++fr) {
#pragma unroll
        for (int fc = 0; fc < 4; ++fc) {
            int row = out_row0 + wr + fr * 16 + lg * 4;
            int col = nt * 128 + wc + fc * 16 + l15;
#pragma unroll
            for (int i = 0; i < 4; ++i) {
                float v = acc[fr][fc][i];
                if (F32OUT) {
                    ((float*)Cout)[(size_t)(row + i) * NTOT + col] = v + bias[col];
                } else {
                    ((unsigned short*)Cout)[(size_t)(row + i) * NTOT + col] = f2bf(v);
                }
            }
        }
    }
}

// -------------------------------------------------- per-head LayerNorm (+scale)
__global__ void ln_head_k(const unsigned short* __restrict__ Y,
                          unsigned short* __restrict__ Out,
                          const float* __restrict__ lw, const float* __restrict__ lb,
                          int rows_per_b, float scale) {
    int gw = blockIdx.x * 4 + (threadIdx.x >> 6);
    int lane = threadIdx.x & 63;
    int h = gw % HEADS_;
    int row = gw / HEADS_;                   // [0, B*rows_per_b)
    int b = row / rows_per_b, r = row % rows_per_b;
    float v = bf2f(Y[(size_t)row * EMB_ + h * 64 + lane]);
    float s = v, s2 = v * v;
#pragma unroll
    for (int m = 1; m <= 32; m <<= 1) {
        s += __shfl_xor(s, m);
        s2 += __shfl_xor(s2, m);
    }
    float mu = s * (1.f / 64.f);
    float var = s2 * (1.f / 64.f) - mu * mu;
    float o = (v - mu) * rsqrtf(var + 1e-5f) * lw[lane] + lb[lane];
    Out[(((size_t)b * HEADS_ + h) * rows_per_b + r) * 64 + lane] = f2bf(o * scale);
}

// ------------------------- K LayerNorm + pack into MFMA-fragment order
// KF[bh][kt][s][l][j] = K[t=kt*32+(l&31)][d = s*16 + (l>>5)*8 + j]
__global__ void ln_head_pack_k(const unsigned short* __restrict__ Y,
                               unsigned short* __restrict__ KF,
                               const float* __restrict__ lw, const float* __restrict__ lb,
                               float scale) {
    int gw = blockIdx.x * 4 + (threadIdx.x >> 6);
    int lane = threadIdx.x & 63;
    int h = gw % HEADS_;
    int row = gw / HEADS_;                   // [0, B*T)
    int b = row / T_LEN, r = row % T_LEN;
    float v = bf2f(Y[(size_t)row * EMB_ + h * 64 + lane]);
    float s = v, s2 = v * v;
#pragma unroll
    for (int m = 1; m <= 32; m <<= 1) {
        s += __shfl_xor(s, m);
        s2 += __shfl_xor(s2, m);
    }
    float mu = s * (1.f / 64.f);
    float var = s2 * (1.f / 64.f) - mu * mu;
    float o = (v - mu) * rsqrtf(var + 1e-5f) * lw[lane] + lb[lane];
    int bh = b * HEADS_ + h;
    int kt = r >> 5, l31 = r & 31;
    int sf = lane >> 4, hi = (lane >> 3) & 1, j = lane & 7;
    size_t flat = ((((size_t)bh * 128 + kt) * 4 + sf) * 64 + hi * 32 + l31) * 8 + j;
    KF[flat] = f2bf(o * scale);
}

// ------------------------- V pack into MFMA-fragment order
// VF[bh][kt][f][l][j] = V^T[d][t]:
//   d = (f>>1)*32 + (l&31)
//   t = kt*32 + (f&1)*16 + (j>>2)*8 + 4*(l>>5) + (j&3)
__global__ void vpack_k(const unsigned short* __restrict__ Yv, unsigned short* __restrict__ VF) {
    __shared__ __align__(16) unsigned short tile[64][72];   // [t][d]
    int t0 = blockIdx.x * 64;      // 64 t-rows = 2 kt tiles
    int bh = blockIdx.y;
    int b = bh >> 4, h = bh & 15;
    int tid = threadIdx.x;
#pragma unroll
    for (int rr = 0; rr < 2; ++rr) {
        int idx = tid + rr * 256;
        int row = idx >> 3, c8 = idx & 7;
        *(uint4*)&tile[row][c8 * 8] =
            *(const uint4*)&Yv[((size_t)b * T_LEN + t0 + row) * EMB_ + h * 64 + c8 * 8];
    }
    __syncthreads();
    int f = tid >> 6, l = tid & 63;
    int d = (f >> 1) * 32 + (l & 31);
    int tb = (f & 1) * 16 + 4 * (l >> 5);
#pragma unroll
    for (int ktl = 0; ktl < 2; ++ktl) {
        unsigned short e[8];
#pragma unroll
        for (int j = 0; j < 8; ++j)
            e[j] = tile[ktl * 32 + tb + (j >> 2) * 8 + (j & 3)][d];
        uint4 o;
        o.x = (unsigned)e[0] | ((unsigned)e[1] << 16);
        o.y = (unsigned)e[2] | ((unsigned)e[3] << 16);
        o.z = (unsigned)e[4] | ((unsigned)e[5] << 16);
        o.w = (unsigned)e[6] | ((unsigned)e[7] << 16);
        size_t kt = (size_t)blockIdx.x * 2 + ktl;
        *(uint4*)&VF[((((size_t)bh * 128 + kt) * 4 + f) * 64 + l) * 8] = o;
    }
}

// ---------------------------------------------------------- flash attention
// 32x32x16 MFMA, zero-LDS main loop, swapped QK^T, sigma-permuted PV,
// fragment-packed K/V (coalesced 16B/lane loads), 32q/wave, 4-way t-split,
// XCD-swizzled blocks, packed-f32 softmax. Q pre-scaled by log2(e).
#define LOADK(DST, KT) do {                                                       \
    const unsigned short* p_ = KFl + (size_t)(KT) * 2048;                         \
    DST[0] = *(const uint4*)(p_);                                                 \
    DST[1] = *(const uint4*)(p_ + 512);                                           \
    DST[2] = *(const uint4*)(p_ + 1024);                                          \
    DST[3] = *(const uint4*)(p_ + 1536);                                          \
} while (0)

__global__ __launch_bounds__(256, 4) void attn32_k(
    const unsigned short* __restrict__ Q,    // [B,H,S,64], pre-scaled w/ log2e
    const unsigned short* __restrict__ KF,   // fragment-packed K
    const unsigned short* __restrict__ VF,   // fragment-packed V^T
    const float* __restrict__ Mcat,          // [B,T]
    unsigned short* __restrict__ O) {        // [B,S,EMB]
    __shared__ float Olds[4][64][32];
    __shared__ float Mlds[4][32];
    __shared__ float Llds[4][32];

    // XCD swizzle: each XCD owns 4 consecutive bh (K/V fits its L2)
    int bid = blockIdx.x;
    int xcd = bid & 7, slot = bid >> 3;        // 8 XCDs, 256 slots each
    int bh = xcd * 4 + (slot >> 6);            // 4 bh per XCD
    int qb = slot & 63;                        // 64 q-blocks of 32 rows
    int b = bh >> 4, h = bh & 15;
    int tid = threadIdx.x;
    int w = tid >> 6;
    int lane = tid & 63;
    int l31 = lane & 31;
    int hi = lane >> 5;
    int q0 = qb * 32;

    const unsigned short* KFl = KF + (size_t)bh * 262144 + lane * 8;
    const unsigned short* VFl = VF + (size_t)bh * 262144 + lane * 8;
    const float* Mb = Mcat + (size_t)b * T_LEN;

    // Q fragments (held for whole kernel): 32 q rows per wave
    bf16x8 qf[4];
    {
        const unsigned short* Qp = Q + ((size_t)bh * S_LEN + q0 + l31) * 64 + hi * 8;
#pragma unroll
        for (int s = 0; s < 4; ++s) qf[s] = *(const bf16x8*)(Qp + s * 16);
    }
    float mq = Mb[q0 + l31];
    f32x2 mq2 = {mq, mq};

    f32x16 Z16;
#pragma unroll
    for (int i = 0; i < 16; ++i) Z16[i] = 0.f;
    f32x16 acc0 = Z16, acc1 = Z16;             // O^T halves: d 0..31, 32..63
    float mM = -1e38f, lS = 0.f;

    uint4 ka[4];
    LOADK(ka, w);                              // prologue: tile w

    for (int it = 0; it < 32; ++it) {
        int kt = w + it * 4;
        // --- V fragment + mask loads (used after softmax; L2-hit latency) ---
        const unsigned short* pv = VFl + (size_t)kt * 2048;
        uint4 vfr0 = *(const uint4*)(pv);
        uint4 vfr1 = *(const uint4*)(pv + 512);
        uint4 vfr2 = *(const uint4*)(pv + 1024);
        uint4 vfr3 = *(const uint4*)(pv + 1536);
        const float* mbase = Mb + kt * 32;
        float4 mf0 = *(const float4*)(mbase + 4 * hi);
        float4 mf1 = *(const float4*)(mbase + 8 + 4 * hi);
        float4 mf2 = *(const float4*)(mbase + 16 + 4 * hi);
        float4 mf3 = *(const float4*)(mbase + 24 + 4 * hi);
        // --- S^T = K · Q^T ---
        f32x16 sa = Z16;
#pragma unroll
        for (int s = 0; s < 4; ++s)
            sa = __builtin_amdgcn_mfma_f32_32x32x16_bf16(
                __builtin_bit_cast(bf16x8, ka[s]), qf[s], sa, 0, 0, 0);
        // --- prefetch next K tile into same regs (anti-dep: after QK issue) ---
        {
            int ktn = kt + ((it < 31) ? 4 : 0);
            LOADK(ka, ktn);
        }
        // --- online softmax (packed f32) ---
        f32x2 mp2[8], e2[8];
        mp2[0] = pk_mul((f32x2){mf0.x, mf0.y}, mq2);
        mp2[1] = pk_mul((f32x2){mf0.z, mf0.w}, mq2);
        mp2[2] = pk_mul((f32x2){mf1.x, mf1.y}, mq2);
        mp2[3] = pk_mul((f32x2){mf1.z, mf1.w}, mq2);
        mp2[4] = pk_mul((f32x2){mf2.x, mf2.y}, mq2);
        mp2[5] = pk_mul((f32x2){mf2.z, mf2.w}, mq2);
        mp2[6] = pk_mul((f32x2){mf3.x, mf3.y}, mq2);
        mp2[7] = pk_mul((f32x2){mf3.z, mf3.w}, mq2);
#pragma unroll
        for (int i = 0; i < 8; ++i)
            e2[i] = pk_mul((f32x2){sa[2 * i], sa[2 * i + 1]}, mp2[i]);
        float t0_ = fmaxf(fmaxf(e2[0][0], e2[0][1]), e2[1][0]);
        float t1_ = fmaxf(fmaxf(e2[1][1], e2[2][0]), e2[2][1]);
        float t2_ = fmaxf(fmaxf(e2[3][0], e2[3][1]), e2[4][0]);
        float t3_ = fmaxf(fmaxf(e2[4][1], e2[5][0]), e2[5][1]);
        float t4_ = fmaxf(fmaxf(e2[6][0], e2[6][1]), e2[7][0]);
        float tm = fmaxf(fmaxf(fmaxf(t0_, t1_), t2_),
                         fmaxf(fmaxf(t3_, t4_), e2[7][1]));
        tm = fmaxf(tm, __shfl_xor(tm, 32));
        if (__any(tm > mM)) {
            float mn = fmaxf(mM, tm);
            float al = __builtin_amdgcn_exp2f(mM - mn);
            mM = mn; lS *= al;
#pragma unroll
            for (int i = 0; i < 16; ++i) { acc0[i] *= al; acc1[i] *= al; }
        }
        f32x2 nM = {-mM, -mM};
#pragma unroll
        for (int i = 0; i < 8; ++i) {
            e2[i] = pk_add(e2[i], nM);
            e2[i][0] = __builtin_amdgcn_exp2f(e2[i][0]);
            e2[i][1] = __builtin_amdgcn_exp2f(e2[i][1]);
            e2[i] = pk_mul(e2[i], mp2[i]);       // p = e * mt * mq
        }
        {
            f32x2 s0 = pk_add(e2[0], e2[1]);
            f32x2 s1 = pk_add(e2[2], e2[3]);
            f32x2 s2 = pk_add(e2[4], e2[5]);
            f32x2 s3 = pk_add(e2[6], e2[7]);
            s0 = pk_add(s0, s1); s2 = pk_add(s2, s3); s0 = pk_add(s0, s2);
            float rs = s0[0] + s0[1];
            rs += __shfl_xor(rs, 32);
            lS += rs;
        }
        unsigned pk_[8];
#pragma unroll
        for (int d_ = 0; d_ < 8; ++d_)
            asm("v_cvt_pk_bf16_f32 %0, %1, %2" : "=v"(pk_[d_])
                : "v"(e2[d_][0]), "v"(e2[d_][1]));
        bf16x8 p0 = __builtin_bit_cast(bf16x8, (uint4){pk_[0], pk_[1], pk_[2], pk_[3]});
        bf16x8 p1 = __builtin_bit_cast(bf16x8, (uint4){pk_[4], pk_[5], pk_[6], pk_[7]});
        // --- O^T += V^T · P^T ---
        acc0 = __builtin_amdgcn_mfma_f32_32x32x16_bf16(__builtin_bit_cast(bf16x8, vfr0), p0, acc0, 0, 0, 0);
        acc0 = __builtin_amdgcn_mfma_f32_32x32x16_bf16(__builtin_bit_cast(bf16x8, vfr1), p1, acc0, 0, 0, 0);
        acc1 = __builtin_amdgcn_mfma_f32_32x32x16_bf16(__builtin_bit_cast(bf16x8, vfr2), p0, acc1, 0, 0, 0);
        acc1 = __builtin_amdgcn_mfma_f32_32x32x16_bf16(__builtin_bit_cast(bf16x8, vfr3), p1, acc1, 0, 0, 0);
    }

    // --- merge 4 waves' partial (m, l, O^T) via LDS, single pass ---
    if (hi == 0) { Mlds[w][l31] = mM; Llds[w][l31] = lS; }
#pragma unroll
    for (int r = 0; r < 16; ++r) {
        int dl = (r & 3) + 8 * (r >> 2) + 4 * hi;
        Olds[w][dl][l31] = acc0[r];
        Olds[w][dl + 32][l31] = acc1[r];
    }
    __syncthreads();
    {
        int q = l31;
        float m0_ = Mlds[0][q], m1_ = Mlds[1][q], m2_ = Mlds[2][q], m3_ = Mlds[3][q];
        float Mx = fmaxf(fmaxf(m0_, m1_), fmaxf(m2_, m3_));
        float f0 = __builtin_amdgcn_exp2f(m0_ - Mx);
        float f1 = __builtin_amdgcn_exp2f(m1_ - Mx);
        float f2 = __builtin_amdgcn_exp2f(m2_ - Mx);
        float f3 = __builtin_amdgcn_exp2f(m3_ - Mx);
        float L = Llds[0][q] * f0 + Llds[1][q] * f1 + Llds[2][q] * f2 + Llds[3][q] * f3;
        float invL = 1.f / (L + 1e-13f);
        float v_[8];
#pragma unroll
        for (int dd = 0; dd < 8; ++dd) {
            int d = w * 16 + hi * 8 + dd;
            v_[dd] = (Olds[0][d][q] * f0 + Olds[1][d][q] * f1 +
                      Olds[2][d][q] * f2 + Olds[3][d][q] * f3) * invL;
        }
        unsigned po_[4];
#pragma unroll
        for (int d2 = 0; d2 < 4; ++d2)
            asm("v_cvt_pk_bf16_f32 %0, %1, %2" : "=v"(po_[d2]) : "v"(v_[2*d2]), "v"(v_[2*d2+1]));
        uint4 st; st.x = po_[0]; st.y = po_[1]; st.z = po_[2]; st.w = po_[3];
        *(uint4*)&O[((size_t)b * S_LEN + q0 + q) * EMB_ + h * 64 + w * 16 + hi * 8] = st;
    }
}

// ------------------------------------------------------------------ launch
extern "C" void kernel_launch(void* const* d_in, const int* in_sizes, int n_in,
                              void* d_out, int out_size, void* d_ws, size_t ws_size,
                              hipStream_t stream) {
    const float* x     = (const float*)d_in[0];
    const float* ctx   = (const float*)d_in[1];
    const float* mask  = (const float*)d_in[2];
    const float* cmask = (const float*)d_in[3];
    const float* Wq    = (const float*)d_in[4];
    const float* Wk    = (const float*)d_in[5];
    const float* Wv    = (const float*)d_in[6];
    const float* Wu    = (const float*)d_in[7];
    const float* bu    = (const float*)d_in[8];
    const float* qlnw  = (const float*)d_in[9];
    const float* qlnb  = (const float*)d_in[10];
    const float* klnw  = (const float*)d_in[11];
    const float* klnb  = (const float*)d_in[12];

    unsigned short* ws = (unsigned short*)d_ws;
    unsigned short* xcb = ws + 0;               //  8,388,608 elems
    unsigned short* WqT = ws + 8388608;         //  1,048,576
    unsigned short* WkT = ws + 9437184;
    unsigned short* WvT = ws + 10485760;
    unsigned short* Qb  = ws + 0;               //  4,194,304 (over dead xcb)
    unsigned short* KFb = ws + 4194304;         //  8,388,608 (over dead xcb/W*T)
    unsigned short* WuT = ws + 12582912;        //  1,048,576 (lives to the end)
    unsigned short* Yq  = ws + 13631488;        //  4,194,304 ; reused as O
    unsigned short* Ob  = Yq;
    unsigned short* Yk  = ws + 17825792;        //  8,388,608 ; reused as VF
    unsigned short* VFb = Yk;
    unsigned short* Yv  = ws + 26214400;        //  8,388,608
    float* Mcat         = (float*)(ws + 34603008);  // 8192 floats

    const float scale = 0.17677669529663687f;               // 1024^-0.25
    const float qscale = 0.17677669529663687f * 1.4426950408889634f; // * log2(e)

    build_xcb_k<<<4096, 256, 0, stream>>>(x, ctx, xcb);
    mcat_k<<<32, 256, 0, stream>>>(mask, cmask, Mcat);
    dim3 wt(16, 16);
    wtrans_k<<<wt, 256, 0, stream>>>(Wq, WqT);
    wtrans_k<<<wt, 256, 0, stream>>>(Wk, WkT);
    wtrans_k<<<wt, 256, 0, stream>>>(Wv, WvT);
    wtrans_k<<<wt, 256, 0, stream>>>(Wu, WuT);

    gemm_bt_k<false><<<dim3(8, 64), 256, 0, stream>>>(xcb, WkT, Yk, nullptr, 64, 8192);
    gemm_bt_k<false><<<dim3(8, 64), 256, 0, stream>>>(xcb, WvT, Yv, nullptr, 64, 8192);
    gemm_bt_k<false><<<dim3(8, 32), 256, 0, stream>>>(xcb, WqT, Yq, nullptr, 16, 4096);

    ln_head_k<<<16384, 256, 0, stream>>>(Yq, Qb, qlnw, qlnb, S_LEN, qscale);
    ln_head_pack_k<<<32768, 256, 0, stream>>>(Yk, KFb, klnw, klnb, scale);
    vpack_k<<<dim3(64, 32), 256, 0, stream>>>(Yv, VFb);

    attn32_k<<<2048, 256, 0, stream>>>(Qb, KFb, VFb, Mcat, Ob);

    gemm_bt_k<true><<<dim3(8, 32), 256, 0, stream>>>(Ob, WuT, d_out, bu, 32, 4096);
}

// Round 6
// 322.799 us; speedup vs baseline: 1.0971x; 1.0971x over previous
//
#include <hip/hip_runtime.h>
#include <hip/hip_bf16.h>
#include <cstdint>

#define B_SZ   2
#define S_LEN  2048
#define C_LEN  2048
#define T_LEN  4096
#define EMB_   1024
#define HEADS_ 16
#define D_     64

typedef __attribute__((ext_vector_type(8))) short bf16x8;
typedef __attribute__((ext_vector_type(4))) float f32x4;
typedef __attribute__((ext_vector_type(16))) float f32x16;

__device__ __forceinline__ unsigned short f2bf(float f) {
    unsigned u = __builtin_bit_cast(unsigned, f);
    u += 0x7fffu + ((u >> 16) & 1u);
    return (unsigned short)(u >> 16);
}
__device__ __forceinline__ float bf2f(unsigned short h) {
    return __builtin_bit_cast(float, (unsigned)h << 16);
}

// ---------------------------------------------------------------- xcb build
__global__ void build_xcb_k(const float* __restrict__ x, const float* __restrict__ ctx,
                            unsigned short* __restrict__ xcb) {
    int i = blockIdx.x * blockDim.x + threadIdx.x;      // one 8-elem chunk
    size_t e8 = (size_t)i * 8;
    int b = (int)(e8 / ((size_t)T_LEN * EMB_));
    size_t rem = e8 % ((size_t)T_LEN * EMB_);
    int t = (int)(rem / EMB_);
    int c = (int)(rem % EMB_);
    const float* src = (t < S_LEN)
        ? &x[((size_t)b * S_LEN + t) * EMB_ + c]
        : &ctx[((size_t)b * C_LEN + (t - S_LEN)) * EMB_ + c];
    float4 v0 = ((const float4*)src)[0];
    float4 v1 = ((const float4*)src)[1];
    uint4 o;
    o.x = (unsigned)f2bf(v0.x) | ((unsigned)f2bf(v0.y) << 16);
    o.y = (unsigned)f2bf(v0.z) | ((unsigned)f2bf(v0.w) << 16);
    o.z = (unsigned)f2bf(v1.x) | ((unsigned)f2bf(v1.y) << 16);
    o.w = (unsigned)f2bf(v1.z) | ((unsigned)f2bf(v1.w) << 16);
    *(uint4*)&xcb[e8] = o;
}

// --------------------------------------------------------------- mask concat
__global__ void mcat_k(const float* __restrict__ mask, const float* __restrict__ cmask,
                       float* __restrict__ Mcat) {
    int i = blockIdx.x * 256 + threadIdx.x;   // B*T total
    int b = i / T_LEN, t = i % T_LEN;
    Mcat[i] = (t < S_LEN) ? mask[(size_t)b * S_LEN + t]
                          : cmask[(size_t)b * C_LEN + (t - S_LEN)];
}

// ------------------------------------------------- weight transpose+convert
__global__ void wtrans_k(const float* __restrict__ W, unsigned short* __restrict__ WT) {
    __shared__ __align__(16) unsigned short tile[64][72];
    int bx = blockIdx.x, by = blockIdx.y;   // bx: n-tile, by: k-tile
    int tid = threadIdx.x;
#pragma unroll
    for (int r = 0; r < 4; ++r) {
        int idx = tid + r * 256;
        int row = idx >> 4, c4 = idx & 15;
        float4 v = ((const float4*)&W[((size_t)(by * 64 + row)) * EMB_ + bx * 64])[c4];
        tile[row][c4 * 4 + 0] = f2bf(v.x);
        tile[row][c4 * 4 + 1] = f2bf(v.y);
        tile[row][c4 * 4 + 2] = f2bf(v.z);
        tile[row][c4 * 4 + 3] = f2bf(v.w);
    }
    __syncthreads();
#pragma unroll
    for (int r = 0; r < 2; ++r) {
        int idx = tid + r * 256;
        int n = idx >> 3, k8 = idx & 7;
        uint4 o;
        unsigned q[4];
#pragma unroll
        for (int j = 0; j < 4; ++j)
            q[j] = (unsigned)tile[k8 * 8 + 2 * j][n] | ((unsigned)tile[k8 * 8 + 2 * j + 1][n] << 16);
        o.x = q[0]; o.y = q[1]; o.z = q[2]; o.w = q[3];
        *(uint4*)&WT[((size_t)(bx * 64 + n)) * EMB_ + by * 64 + k8 * 8] = o;
    }
}

// ---------------------------------------------------------------- GEMM (m97-style)
template <bool F32OUT>
__global__ __launch_bounds__(256) void gemm_bt_k(
    const unsigned short* __restrict__ A,
    const unsigned short* __restrict__ Bt,
    void* __restrict__ Cout,
    const float* __restrict__ bias,
    int mtiles_per_chunk, int chunk_stride) {
    constexpr int KTOT = 1024, NTOT = 1024;
    __shared__ __align__(16) unsigned short As[128 * 32];
    __shared__ __align__(16) unsigned short Bs[128 * 32];
    int nt = blockIdx.x, mt = blockIdx.y;
    int in_row0 = (mt / mtiles_per_chunk) * chunk_stride + (mt % mtiles_per_chunk) * 128;
    int out_row0 = mt * 128;
    int tid = threadIdx.x, w = tid >> 6, l = tid & 63, l15 = l & 15, lg = l >> 4;
    int wr = (w >> 1) * 64, wc = (w & 1) * 64;

    f32x4 zero4 = {0.f, 0.f, 0.f, 0.f};
    f32x4 acc[4][4];
#pragma unroll
    for (int i = 0; i < 4; ++i)
#pragma unroll
        for (int j = 0; j < 4; ++j) acc[i][j] = zero4;

    for (int k0 = 0; k0 < KTOT; k0 += 32) {
#pragma unroll
        for (int j = 0; j < 2; ++j) {
            int o = tid * 16 + j * 4096;        // byte offset in 8KB tile
            int row = o >> 6;                   // 64B per row (32 bf16)
            int ke = (o & 63) >> 1;             // element offset in row
            __builtin_amdgcn_global_load_lds(
                (const __attribute__((address_space(1))) void*)&A[(size_t)(in_row0 + row) * KTOT + k0 + ke],
                (__attribute__((address_space(3))) void*)&As[o >> 1], 16, 0, 0);
            __builtin_amdgcn_global_load_lds(
                (const __attribute__((address_space(1))) void*)&Bt[(size_t)(nt * 128 + row) * KTOT + k0 + ke],
                (__attribute__((address_space(3))) void*)&Bs[o >> 1], 16, 0, 0);
        }
        __syncthreads();
        bf16x8 af[4], bf[4];
#pragma unroll
        for (int fr = 0; fr < 4; ++fr)
            af[fr] = *(const bf16x8*)&As[(wr + fr * 16 + l15) * 32 + lg * 8];
#pragma unroll
        for (int fc = 0; fc < 4; ++fc)
            bf[fc] = *(const bf16x8*)&Bs[(wc + fc * 16 + l15) * 32 + lg * 8];
#pragma unroll
        for (int fr = 0; fr < 4; ++fr)
#pragma unroll
            for (int fc = 0; fc < 4; ++fc)
                acc[fr][fc] = __builtin_amdgcn_mfma_f32_16x16x32_bf16(af[fr], bf[fc], acc[fr][fc], 0, 0, 0);
        __syncthreads();
    }
#pragma unroll
    for (int fr = 0; fr < 4; ++fr) {
#pragma unroll
        for (int fc = 0; fc < 4; ++fc) {
            int row = out_row0 + wr + fr * 16 + lg * 4;
            int col = nt * 128 + wc + fc * 16 + l15;
#pragma unroll
            for (int i = 0; i < 4; ++i) {
                float v = acc[fr][fc][i];
                if (F32OUT) {
                    ((float*)Cout)[(size_t)(row + i) * NTOT + col] = v + bias[col];
                } else {
                    ((unsigned short*)Cout)[(size_t)(row + i) * NTOT + col] = f2bf(v);
                }
            }
        }
    }
}

// -------------------------------------------------- per-head LayerNorm (+scale)
__global__ void ln_head_k(const unsigned short* __restrict__ Y,
                          unsigned short* __restrict__ Out,
                          const float* __restrict__ lw, const float* __restrict__ lb,
                          int rows_per_b, float scale) {
    int gw = blockIdx.x * 4 + (threadIdx.x >> 6);
    int lane = threadIdx.x & 63;
    int h = gw % HEADS_;
    int row = gw / HEADS_;                   // [0, B*rows_per_b)
    int b = row / rows_per_b, r = row % rows_per_b;
    float v = bf2f(Y[(size_t)row * EMB_ + h * 64 + lane]);
    float s = v, s2 = v * v;
#pragma unroll
    for (int m = 1; m <= 32; m <<= 1) {
        s += __shfl_xor(s, m);
        s2 += __shfl_xor(s2, m);
    }
    float mu = s * (1.f / 64.f);
    float var = s2 * (1.f / 64.f) - mu * mu;
    float o = (v - mu) * rsqrtf(var + 1e-5f) * lw[lane] + lb[lane];
    Out[(((size_t)b * HEADS_ + h) * rows_per_b + r) * 64 + lane] = f2bf(o * scale);
}

// ------------------------- K LayerNorm + pack into MFMA-fragment order
// KF[bh][kt][s][l][j] = K[t=kt*32+(l&31)][d = s*16 + (l>>5)*8 + j]
__global__ void ln_head_pack_k(const unsigned short* __restrict__ Y,
                               unsigned short* __restrict__ KF,
                               const float* __restrict__ lw, const float* __restrict__ lb,
                               float scale) {
    int gw = blockIdx.x * 4 + (threadIdx.x >> 6);
    int lane = threadIdx.x & 63;
    int h = gw % HEADS_;
    int row = gw / HEADS_;                   // [0, B*T)
    int b = row / T_LEN, r = row % T_LEN;
    float v = bf2f(Y[(size_t)row * EMB_ + h * 64 + lane]);
    float s = v, s2 = v * v;
#pragma unroll
    for (int m = 1; m <= 32; m <<= 1) {
        s += __shfl_xor(s, m);
        s2 += __shfl_xor(s2, m);
    }
    float mu = s * (1.f / 64.f);
    float var = s2 * (1.f / 64.f) - mu * mu;
    float o = (v - mu) * rsqrtf(var + 1e-5f) * lw[lane] + lb[lane];
    int bh = b * HEADS_ + h;
    int kt = r >> 5, l31 = r & 31;
    int sf = lane >> 4, hi = (lane >> 3) & 1, j = lane & 7;
    size_t flat = ((((size_t)bh * 128 + kt) * 4 + sf) * 64 + hi * 32 + l31) * 8 + j;
    KF[flat] = f2bf(o * scale);
}

// ------------------------- V pack into MFMA-fragment order
// VF[bh][kt][f][l][j] = V^T[d][t]:
//   d = (f>>1)*32 + (l&31)
//   t = kt*32 + (f&1)*16 + (j>>2)*8 + 4*(l>>5) + (j&3)
__global__ void vpack_k(const unsigned short* __restrict__ Yv, unsigned short* __restrict__ VF) {
    __shared__ __align__(16) unsigned short tile[64][72];   // [t][d]
    int t0 = blockIdx.x * 64;      // 64 t-rows = 2 kt tiles
    int bh = blockIdx.y;
    int b = bh >> 4, h = bh & 15;
    int tid = threadIdx.x;
#pragma unroll
    for (int rr = 0; rr < 2; ++rr) {
        int idx = tid + rr * 256;
        int row = idx >> 3, c8 = idx & 7;
        *(uint4*)&tile[row][c8 * 8] =
            *(const uint4*)&Yv[((size_t)b * T_LEN + t0 + row) * EMB_ + h * 64 + c8 * 8];
    }
    __syncthreads();
    int f = tid >> 6, l = tid & 63;
    int d = (f >> 1) * 32 + (l & 31);
    int tb = (f & 1) * 16 + 4 * (l >> 5);
#pragma unroll
    for (int ktl = 0; ktl < 2; ++ktl) {
        unsigned short e[8];
#pragma unroll
        for (int j = 0; j < 8; ++j)
            e[j] = tile[ktl * 32 + tb + (j >> 2) * 8 + (j & 3)][d];
        uint4 o;
        o.x = (unsigned)e[0] | ((unsigned)e[1] << 16);
        o.y = (unsigned)e[2] | ((unsigned)e[3] << 16);
        o.z = (unsigned)e[4] | ((unsigned)e[5] << 16);
        o.w = (unsigned)e[6] | ((unsigned)e[7] << 16);
        size_t kt = (size_t)blockIdx.x * 2 + ktl;
        *(uint4*)&VF[((((size_t)bh * 128 + kt) * 4 + f) * 64 + l) * 8] = o;
    }
}

// ---------------------------------------------------------- flash attention
// 32x32x16 MFMA, zero-LDS main loop, swapped QK^T, sigma-permuted PV,
// fragment-packed K/V (coalesced 16B/lane loads), 64q/wave dual-chain,
// 4-way t-split, XCD-swizzled blocks. Q pre-scaled by log2(e).
#define SOFTMAX(SA, MQ, MM, LS, ACA, ACB, PB0, PB1) do {                          \
    float z_[16];                                                                 \
    _Pragma("unroll") for (int r_ = 0; r_ < 16; ++r_) {                          \
        float mp_ = mt_[r_] * (MQ);                                              \
        z_[r_] = SA[r_] * mp_;                                                   \
        SA[r_] = mp_;                                                            \
    }                                                                             \
    float ta_ = fmaxf(fmaxf(z_[0], z_[1]), z_[2]);                                \
    float tb_ = fmaxf(fmaxf(z_[3], z_[4]), z_[5]);                                \
    float tc_ = fmaxf(fmaxf(z_[6], z_[7]), z_[8]);                                \
    float td_ = fmaxf(fmaxf(z_[9], z_[10]), z_[11]);                              \
    float te_ = fmaxf(fmaxf(z_[12], z_[13]), z_[14]);                             \
    float tm_ = fmaxf(fmaxf(fmaxf(ta_, tb_), tc_),                                \
                      fmaxf(fmaxf(td_, te_), z_[15]));                            \
    tm_ = fmaxf(tm_, __shfl_xor(tm_, 32));                                        \
    if (__any(tm_ > (MM))) {                                                      \
        float mn_ = fmaxf((MM), tm_);                                            \
        float al_ = __builtin_amdgcn_exp2f((MM) - mn_);                          \
        (MM) = mn_; (LS) *= al_; (ACA) *= al_; (ACB) *= al_;                      \
    }                                                                             \
    float rsA_ = 0.f, rsB_ = 0.f;                                                 \
    _Pragma("unroll") for (int r_ = 0; r_ < 16; r_ += 2) {                        \
        z_[r_]     = __builtin_amdgcn_exp2f(z_[r_] - (MM)) * SA[r_];              \
        z_[r_ + 1] = __builtin_amdgcn_exp2f(z_[r_ + 1] - (MM)) * SA[r_ + 1];      \
        rsA_ += z_[r_]; rsB_ += z_[r_ + 1];                                       \
    }                                                                             \
    float rs_ = rsA_ + rsB_;                                                      \
    rs_ += __shfl_xor(rs_, 32); (LS) += rs_;                                      \
    unsigned pk_[8];                                                              \
    _Pragma("unroll") for (int d_ = 0; d_ < 8; ++d_)                              \
        asm("v_cvt_pk_bf16_f32 %0, %1, %2" : "=v"(pk_[d_])                        \
            : "v"(z_[2*d_]), "v"(z_[2*d_+1]));                                    \
    { uint4 u0_; u0_.x=pk_[0]; u0_.y=pk_[1]; u0_.z=pk_[2]; u0_.w=pk_[3];          \
      uint4 u1_; u1_.x=pk_[4]; u1_.y=pk_[5]; u1_.z=pk_[6]; u1_.w=pk_[7];          \
      (PB0) = __builtin_bit_cast(bf16x8, u0_);                                    \
      (PB1) = __builtin_bit_cast(bf16x8, u1_); }                                  \
} while (0)

#define LOADK(DST, KT) do {                                                       \
    const unsigned short* p_ = KFl + (size_t)(KT) * 2048;                         \
    DST[0] = *(const uint4*)(p_);                                                 \
    DST[1] = *(const uint4*)(p_ + 512);                                           \
    DST[2] = *(const uint4*)(p_ + 1024);                                          \
    DST[3] = *(const uint4*)(p_ + 1536);                                          \
} while (0)

__global__ __launch_bounds__(256) void attn32_k(
    const unsigned short* __restrict__ Q,    // [B,H,S,64], pre-scaled w/ log2e
    const unsigned short* __restrict__ KF,   // fragment-packed K
    const unsigned short* __restrict__ VF,   // fragment-packed V^T
    const float* __restrict__ Mcat,          // [B,T]
    unsigned short* __restrict__ O) {        // [B,S,EMB]
    __shared__ float Olds[4][32][64];
    __shared__ float Mlds[4][64];
    __shared__ float Llds[4][64];

    // XCD swizzle: each XCD owns 4 consecutive bh -> K/V fits its private L2.
    int bid = blockIdx.x;
    int xcd = bid & 7, slot = bid >> 3;        // 8 XCDs x 128 slots
    int bh = xcd * 4 + (slot >> 5);            // 4 bh per XCD
    int qblk = slot & 31;                      // 32 q-blocks of 64 rows
    int b = bh >> 4, h = bh & 15;
    int tid = threadIdx.x;
    int w = tid >> 6;
    int lane = tid & 63;
    int l31 = lane & 31;
    int hi = lane >> 5;
    int q0 = qblk * 64;

    const unsigned short* KFl = KF + (size_t)bh * 262144 + lane * 8;
    const unsigned short* VFl = VF + (size_t)bh * 262144 + lane * 8;
    const float* Mb = Mcat + (size_t)b * T_LEN;

    // Q fragments (held for whole kernel)
    bf16x8 qf0[4], qf1[4];
    {
        const unsigned short* Qp0 = Q + ((size_t)bh * S_LEN + q0 + l31) * 64 + hi * 8;
        const unsigned short* Qp1 = Qp0 + (size_t)32 * 64;
#pragma unroll
        for (int s = 0; s < 4; ++s) {
            qf0[s] = *(const bf16x8*)(Qp0 + s * 16);
            qf1[s] = *(const bf16x8*)(Qp1 + s * 16);
        }
    }
    float mq0 = Mb[q0 + l31];          // q rows are in [0,S)
    float mq1 = Mb[q0 + 32 + l31];

    f32x16 Z16;
#pragma unroll
    for (int i = 0; i < 16; ++i) Z16[i] = 0.f;
    f32x16 acc00 = Z16, acc01 = Z16, acc10 = Z16, acc11 = Z16;  // acc[db][qb]
    float mM0 = -1e38f, mM1 = -1e38f, lS0 = 0.f, lS1 = 0.f;

    auto TILE = [&](const uint4* kf, int kt) {
        // --- V fragment loads (coalesced; latency hides under QK+softmax) ---
        const unsigned short* pv = VFl + (size_t)kt * 2048;
        uint4 vfr0 = *(const uint4*)(pv);
        uint4 vfr1 = *(const uint4*)(pv + 512);
        uint4 vfr2 = *(const uint4*)(pv + 1024);
        uint4 vfr3 = *(const uint4*)(pv + 1536);
        // --- t-mask loads ---
        const float* mbase = Mb + kt * 32;
        float4 mf0 = *(const float4*)(mbase + 4 * hi);
        float4 mf1 = *(const float4*)(mbase + 8 + 4 * hi);
        float4 mf2 = *(const float4*)(mbase + 16 + 4 * hi);
        float4 mf3 = *(const float4*)(mbase + 24 + 4 * hi);
        // --- S^T = K · Q^T ---
        f32x16 sa0 = Z16, sa1 = Z16;
#pragma unroll
        for (int s = 0; s < 4; ++s) {
            bf16x8 kfr = __builtin_bit_cast(bf16x8, kf[s]);
            sa0 = __builtin_amdgcn_mfma_f32_32x32x16_bf16(kfr, qf0[s], sa0, 0, 0, 0);
            sa1 = __builtin_amdgcn_mfma_f32_32x32x16_bf16(kfr, qf1[s], sa1, 0, 0, 0);
        }
        float mt_[16];
        mt_[0] = mf0.x; mt_[1] = mf0.y; mt_[2]  = mf0.z; mt_[3]  = mf0.w;
        mt_[4] = mf1.x; mt_[5] = mf1.y; mt_[6]  = mf1.z; mt_[7]  = mf1.w;
        mt_[8] = mf2.x; mt_[9] = mf2.y; mt_[10] = mf2.z; mt_[11] = mf2.w;
        mt_[12] = mf3.x; mt_[13] = mf3.y; mt_[14] = mf3.z; mt_[15] = mf3.w;
        // --- online softmax (lane-local, one shuffle per reduction) ---
        bf16x8 p00, p01, p10, p11;
        SOFTMAX(sa0, mq0, mM0, lS0, acc00, acc10, p00, p01);
        SOFTMAX(sa1, mq1, mM1, lS1, acc01, acc11, p10, p11);
        // --- O^T += V^T · P^T (sigma-permuted k so P frags are lane-local) ---
        bf16x8 vf;
        vf = __builtin_bit_cast(bf16x8, vfr0);
        acc00 = __builtin_amdgcn_mfma_f32_32x32x16_bf16(vf, p00, acc00, 0, 0, 0);
        acc01 = __builtin_amdgcn_mfma_f32_32x32x16_bf16(vf, p10, acc01, 0, 0, 0);
        vf = __builtin_bit_cast(bf16x8, vfr1);
        acc00 = __builtin_amdgcn_mfma_f32_32x32x16_bf16(vf, p01, acc00, 0, 0, 0);
        acc01 = __builtin_amdgcn_mfma_f32_32x32x16_bf16(vf, p11, acc01, 0, 0, 0);
        vf = __builtin_bit_cast(bf16x8, vfr2);
        acc10 = __builtin_amdgcn_mfma_f32_32x32x16_bf16(vf, p00, acc10, 0, 0, 0);
        acc11 = __builtin_amdgcn_mfma_f32_32x32x16_bf16(vf, p10, acc11, 0, 0, 0);
        vf = __builtin_bit_cast(bf16x8, vfr3);
        acc10 = __builtin_amdgcn_mfma_f32_32x32x16_bf16(vf, p01, acc10, 0, 0, 0);
        acc11 = __builtin_amdgcn_mfma_f32_32x32x16_bf16(vf, p11, acc11, 0, 0, 0);
    };

    // --- main t-loop: wave w owns tiles kt = w, w+4, ..., w+124 (no barriers) ---
    uint4 ka[4], kb[4];
    LOADK(ka, w);
    for (int it = 0; it < 32; it += 2) {
        int kt0 = w + it * 4;
        LOADK(kb, kt0 + 4);
        TILE(ka, kt0);
        LOADK(ka, (it + 2 < 32) ? kt0 + 8 : kt0);
        TILE(kb, kt0 + 4);
    }

    // --- merge 4 waves' partial (m, l, O^T) via LDS, two d-halves ---
    if (hi == 0) {
        Mlds[w][l31] = mM0;      Llds[w][l31] = lS0;
        Mlds[w][32 + l31] = mM1; Llds[w][32 + l31] = lS1;
    }
    int qm = tid & 63;
    float f0, f1, f2, f3, invL;

    // pass 0: db = 0
#pragma unroll
    for (int r = 0; r < 16; ++r) {
        int dl = (r & 3) + 8 * (r >> 2) + 4 * hi;
        Olds[w][dl][l31] = acc00[r];
        Olds[w][dl][32 + l31] = acc01[r];
    }
    __syncthreads();
    {
        float m0_ = Mlds[0][qm], m1_ = Mlds[1][qm], m2_ = Mlds[2][qm], m3_ = Mlds[3][qm];
        float Mx = fmaxf(fmaxf(m0_, m1_), fmaxf(m2_, m3_));
        f0 = __builtin_amdgcn_exp2f(m0_ - Mx);
        f1 = __builtin_amdgcn_exp2f(m1_ - Mx);
        f2 = __builtin_amdgcn_exp2f(m2_ - Mx);
        f3 = __builtin_amdgcn_exp2f(m3_ - Mx);
        float L = Llds[0][qm] * f0 + Llds[1][qm] * f1 + Llds[2][qm] * f2 + Llds[3][qm] * f3;
        invL = 1.f / (L + 1e-13f);
    }
    {
        float v_[8];
#pragma unroll
        for (int dd = 0; dd < 8; ++dd) {
            int d = w * 8 + dd;
            v_[dd] = (Olds[0][d][qm] * f0 + Olds[1][d][qm] * f1 +
                      Olds[2][d][qm] * f2 + Olds[3][d][qm] * f3) * invL;
        }
        unsigned po_[4];
#pragma unroll
        for (int d2 = 0; d2 < 4; ++d2)
            asm("v_cvt_pk_bf16_f32 %0, %1, %2" : "=v"(po_[d2]) : "v"(v_[2*d2]), "v"(v_[2*d2+1]));
        uint4 st; st.x = po_[0]; st.y = po_[1]; st.z = po_[2]; st.w = po_[3];
        *(uint4*)&O[((size_t)b * S_LEN + q0 + qm) * EMB_ + h * 64 + w * 8] = st;
    }
    __syncthreads();
    // pass 1: db = 1
#pragma unroll
    for (int r = 0; r < 16; ++r) {
        int dl = (r & 3) + 8 * (r >> 2) + 4 * hi;
        Olds[w][dl][l31] = acc10[r];
        Olds[w][dl][32 + l31] = acc11[r];
    }
    __syncthreads();
    {
        float v_[8];
#pragma unroll
        for (int dd = 0; dd < 8; ++dd) {
            int d = w * 8 + dd;
            v_[dd] = (Olds[0][d][qm] * f0 + Olds[1][d][qm] * f1 +
                      Olds[2][d][qm] * f2 + Olds[3][d][qm] * f3) * invL;
        }
        unsigned po_[4];
#pragma unroll
        for (int d2 = 0; d2 < 4; ++d2)
            asm("v_cvt_pk_bf16_f32 %0, %1, %2" : "=v"(po_[d2]) : "v"(v_[2*d2]), "v"(v_[2*d2+1]));
        uint4 st; st.x = po_[0]; st.y = po_[1]; st.z = po_[2]; st.w = po_[3];
        *(uint4*)&O[((size_t)b * S_LEN + q0 + qm) * EMB_ + h * 64 + 32 + w * 8] = st;
    }
}

// ------------------------------------------------------------------ launch
extern "C" void kernel_launch(void* const* d_in, const int* in_sizes, int n_in,
                              void* d_out, int out_size, void* d_ws, size_t ws_size,
                              hipStream_t stream) {
    const float* x     = (const float*)d_in[0];
    const float* ctx   = (const float*)d_in[1];
    const float* mask  = (const float*)d_in[2];
    const float* cmask = (const float*)d_in[3];
    const float* Wq    = (const float*)d_in[4];
    const float* Wk    = (const float*)d_in[5];
    const float* Wv    = (const float*)d_in[6];
    const float* Wu    = (const float*)d_in[7];
    const float* bu    = (const float*)d_in[8];
    const float* qlnw  = (const float*)d_in[9];
    const float* qlnb  = (const float*)d_in[10];
    const float* klnw  = (const float*)d_in[11];
    const float* klnb  = (const float*)d_in[12];

    unsigned short* ws = (unsigned short*)d_ws;
    unsigned short* xcb = ws + 0;               //  8,388,608 elems
    unsigned short* WqT = ws + 8388608;         //  1,048,576
    unsigned short* WkT = ws + 9437184;
    unsigned short* WvT = ws + 10485760;
    unsigned short* Qb  = ws + 0;               //  4,194,304 (over dead xcb)
    unsigned short* KFb = ws + 4194304;         //  8,388,608 (over dead xcb/W*T)
    unsigned short* WuT = ws + 12582912;        //  1,048,576 (lives to the end)
    unsigned short* Yq  = ws + 13631488;        //  4,194,304 ; reused as O
    unsigned short* Ob  = Yq;
    unsigned short* Yk  = ws + 17825792;        //  8,388,608 ; reused as VF
    unsigned short* VFb = Yk;
    unsigned short* Yv  = ws + 26214400;        //  8,388,608
    float* Mcat         = (float*)(ws + 34603008);  // 8192 floats

    const float scale = 0.17677669529663687f;               // 1024^-0.25
    const float qscale = 0.17677669529663687f * 1.4426950408889634f; // * log2(e)

    build_xcb_k<<<4096, 256, 0, stream>>>(x, ctx, xcb);
    mcat_k<<<32, 256, 0, stream>>>(mask, cmask, Mcat);
    dim3 wt(16, 16);
    wtrans_k<<<wt, 256, 0, stream>>>(Wq, WqT);
    wtrans_k<<<wt, 256, 0, stream>>>(Wk, WkT);
    wtrans_k<<<wt, 256, 0, stream>>>(Wv, WvT);
    wtrans_k<<<wt, 256, 0, stream>>>(Wu, WuT);

    gemm_bt_k<false><<<dim3(8, 64), 256, 0, stream>>>(xcb, WkT, Yk, nullptr, 64, 8192);
    gemm_bt_k<false><<<dim3(8, 64), 256, 0, stream>>>(xcb, WvT, Yv, nullptr, 64, 8192);
    gemm_bt_k<false><<<dim3(8, 32), 256, 0, stream>>>(xcb, WqT, Yq, nullptr, 16, 4096);

    ln_head_k<<<16384, 256, 0, stream>>>(Yq, Qb, qlnw, qlnb, S_LEN, qscale);
    ln_head_pack_k<<<32768, 256, 0, stream>>>(Yk, KFb, klnw, klnb, scale);
    vpack_k<<<dim3(64, 32), 256, 0, stream>>>(Yv, VFb);

    attn32_k<<<1024, 256, 0, stream>>>(Qb, KFb, VFb, Mcat, Ob);

    gemm_bt_k<true><<<dim3(8, 32), 256, 0, stream>>>(Ob, WuT, d_out, bu, 32, 4096);
}

// Round 8
// 301.867 us; speedup vs baseline: 1.1732x; 1.0693x over previous
//
#include <hip/hip_runtime.h>
#include <hip/hip_bf16.h>
#include <cstdint>

#define B_SZ   2
#define S_LEN  2048
#define C_LEN  2048
#define T_LEN  4096
#define EMB_   1024
#define HEADS_ 16
#define D_     64

typedef __attribute__((ext_vector_type(8))) short bf16x8;
typedef __attribute__((ext_vector_type(4))) float f32x4;
typedef __attribute__((ext_vector_type(16))) float f32x16;
typedef __attribute__((ext_vector_type(2))) float f32x2;

__device__ __forceinline__ unsigned short f2bf(float f) {
    unsigned u = __builtin_bit_cast(unsigned, f);
    u += 0x7fffu + ((u >> 16) & 1u);
    return (unsigned short)(u >> 16);
}
__device__ __forceinline__ float bf2f(unsigned short h) {
    return __builtin_bit_cast(float, (unsigned)h << 16);
}
__device__ __forceinline__ f32x2 pk_add(f32x2 a, f32x2 b) {
    f32x2 d;
    asm("v_pk_add_f32 %0, %1, %2" : "=v"(d) : "v"(a), "v"(b));
    return d;
}

// ---------------------------------------------------------------- xcb build
__global__ void build_xcb_k(const float* __restrict__ x, const float* __restrict__ ctx,
                            unsigned short* __restrict__ xcb) {
    int i = blockIdx.x * blockDim.x + threadIdx.x;      // one 8-elem chunk
    size_t e8 = (size_t)i * 8;
    int b = (int)(e8 / ((size_t)T_LEN * EMB_));
    size_t rem = e8 % ((size_t)T_LEN * EMB_);
    int t = (int)(rem / EMB_);
    int c = (int)(rem % EMB_);
    const float* src = (t < S_LEN)
        ? &x[((size_t)b * S_LEN + t) * EMB_ + c]
        : &ctx[((size_t)b * C_LEN + (t - S_LEN)) * EMB_ + c];
    float4 v0 = ((const float4*)src)[0];
    float4 v1 = ((const float4*)src)[1];
    uint4 o;
    o.x = (unsigned)f2bf(v0.x) | ((unsigned)f2bf(v0.y) << 16);
    o.y = (unsigned)f2bf(v0.z) | ((unsigned)f2bf(v0.w) << 16);
    o.z = (unsigned)f2bf(v1.x) | ((unsigned)f2bf(v1.y) << 16);
    o.w = (unsigned)f2bf(v1.z) | ((unsigned)f2bf(v1.w) << 16);
    *(uint4*)&xcb[e8] = o;
}

// --------------------------------------------------------------- mask concat
__global__ void mcat_k(const float* __restrict__ mask, const float* __restrict__ cmask,
                       float* __restrict__ Mcat) {
    int i = blockIdx.x * 256 + threadIdx.x;   // B*T total
    int b = i / T_LEN, t = i % T_LEN;
    Mcat[i] = (t < S_LEN) ? mask[(size_t)b * S_LEN + t]
                          : cmask[(size_t)b * C_LEN + (t - S_LEN)];
}

// ---------------------- weight transpose+convert (all 4 weights, one launch)
__global__ void wtrans4_k(const float* __restrict__ W0, const float* __restrict__ W1,
                          const float* __restrict__ W2, const float* __restrict__ W3,
                          unsigned short* __restrict__ T0, unsigned short* __restrict__ T1,
                          unsigned short* __restrict__ T2, unsigned short* __restrict__ T3) {
    __shared__ __align__(16) unsigned short tile[64][72];
    int bx = blockIdx.x, by = blockIdx.y, bz = blockIdx.z;
    const float* W = (bz == 0) ? W0 : (bz == 1) ? W1 : (bz == 2) ? W2 : W3;
    unsigned short* WT = (bz == 0) ? T0 : (bz == 1) ? T1 : (bz == 2) ? T2 : T3;
    int tid = threadIdx.x;
#pragma unroll
    for (int r = 0; r < 4; ++r) {
        int idx = tid + r * 256;
        int row = idx >> 4, c4 = idx & 15;
        float4 v = ((const float4*)&W[((size_t)(by * 64 + row)) * EMB_ + bx * 64])[c4];
        tile[row][c4 * 4 + 0] = f2bf(v.x);
        tile[row][c4 * 4 + 1] = f2bf(v.y);
        tile[row][c4 * 4 + 2] = f2bf(v.z);
        tile[row][c4 * 4 + 3] = f2bf(v.w);
    }
    __syncthreads();
#pragma unroll
    for (int r = 0; r < 2; ++r) {
        int idx = tid + r * 256;
        int n = idx >> 3, k8 = idx & 7;
        uint4 o;
        unsigned q[4];
#pragma unroll
        for (int j = 0; j < 4; ++j)
            q[j] = (unsigned)tile[k8 * 8 + 2 * j][n] | ((unsigned)tile[k8 * 8 + 2 * j + 1][n] << 16);
        o.x = q[0]; o.y = q[1]; o.z = q[2]; o.w = q[3];
        *(uint4*)&WT[((size_t)(bx * 64 + n)) * EMB_ + by * 64 + k8 * 8] = o;
    }
}

// ---------------------------------------------------------------- GEMM (m97-style)
template <bool F32OUT>
__global__ __launch_bounds__(256) void gemm_bt_k(
    const unsigned short* __restrict__ A,
    const unsigned short* __restrict__ Bt,
    void* __restrict__ Cout,
    const float* __restrict__ bias,
    int mtiles_per_chunk, int chunk_stride) {
    constexpr int KTOT = 1024, NTOT = 1024;
    __shared__ __align__(16) unsigned short As[128 * 32];
    __shared__ __align__(16) unsigned short Bs[128 * 32];
    int nt = blockIdx.x, mt = blockIdx.y;
    int in_row0 = (mt / mtiles_per_chunk) * chunk_stride + (mt % mtiles_per_chunk) * 128;
    int out_row0 = mt * 128;
    int tid = threadIdx.x, w = tid >> 6, l = tid & 63, l15 = l & 15, lg = l >> 4;
    int wr = (w >> 1) * 64, wc = (w & 1) * 64;

    f32x4 zero4 = {0.f, 0.f, 0.f, 0.f};
    f32x4 acc[4][4];
#pragma unroll
    for (int i = 0; i < 4; ++i)
#pragma unroll
        for (int j = 0; j < 4; ++j) acc[i][j] = zero4;

    for (int k0 = 0; k0 < KTOT; k0 += 32) {
#pragma unroll
        for (int j = 0; j < 2; ++j) {
            int o = tid * 16 + j * 4096;        // byte offset in 8KB tile
            int row = o >> 6;                   // 64B per row (32 bf16)
            int ke = (o & 63) >> 1;             // element offset in row
            __builtin_amdgcn_global_load_lds(
                (const __attribute__((address_space(1))) void*)&A[(size_t)(in_row0 + row) * KTOT + k0 + ke],
                (__attribute__((address_space(3))) void*)&As[o >> 1], 16, 0, 0);
            __builtin_amdgcn_global_load_lds(
                (const __attribute__((address_space(1))) void*)&Bt[(size_t)(nt * 128 + row) * KTOT + k0 + ke],
                (__attribute__((address_space(3))) void*)&Bs[o >> 1], 16, 0, 0);
        }
        __syncthreads();
        bf16x8 af[4], bf[4];
#pragma unroll
        for (int fr = 0; fr < 4; ++fr)
            af[fr] = *(const bf16x8*)&As[(wr + fr * 16 + l15) * 32 + lg * 8];
#pragma unroll
        for (int fc = 0; fc < 4; ++fc)
            bf[fc] = *(const bf16x8*)&Bs[(wc + fc * 16 + l15) * 32 + lg * 8];
#pragma unroll
        for (int fr = 0; fr < 4; ++fr)
#pragma unroll
            for (int fc = 0; fc < 4; ++fc)
                acc[fr][fc] = __builtin_amdgcn_mfma_f32_16x16x32_bf16(af[fr], bf[fc], acc[fr][fc], 0, 0, 0);
        __syncthreads();
    }
#pragma unroll
    for (int fr = 0; fr < 4; ++fr) {
#pragma unroll
        for (int fc = 0; fc < 4; ++fc) {
            int row = out_row0 + wr + fr * 16 + lg * 4;
            int col = nt * 128 + wc + fc * 16 + l15;
#pragma unroll
            for (int i = 0; i < 4; ++i) {
                float v = acc[fr][fc][i];
                if (F32OUT) {
                    ((float*)Cout)[(size_t)(row + i) * NTOT + col] = v + bias[col];
                } else {
                    ((unsigned short*)Cout)[(size_t)(row + i) * NTOT + col] = f2bf(v);
                }
            }
        }
    }
}

// ----------------------- Q LayerNorm (+scale*log2e, mask-fold mq into rows)
__global__ void ln_head_k(const unsigned short* __restrict__ Y,
                          unsigned short* __restrict__ Out,
                          const float* __restrict__ lw, const float* __restrict__ lb,
                          const float* __restrict__ Mcat,
                          int rows_per_b, float scale) {
    int gw = blockIdx.x * 4 + (threadIdx.x >> 6);
    int lane = threadIdx.x & 63;
    int h = gw % HEADS_;
    int row = gw / HEADS_;                   // [0, B*rows_per_b)
    int b = row / rows_per_b, r = row % rows_per_b;
    float v = bf2f(Y[(size_t)row * EMB_ + h * 64 + lane]);
    float s = v, s2 = v * v;
#pragma unroll
    for (int m = 1; m <= 32; m <<= 1) {
        s += __shfl_xor(s, m);
        s2 += __shfl_xor(s2, m);
    }
    float mu = s * (1.f / 64.f);
    float var = s2 * (1.f / 64.f) - mu * mu;
    float o = (v - mu) * rsqrtf(var + 1e-5f) * lw[lane] + lb[lane];
    float mq = Mcat[(size_t)b * T_LEN + r];  // r < S
    Out[(((size_t)b * HEADS_ + h) * rows_per_b + r) * 64 + lane] = f2bf(o * scale * mq);
}

// ------------- K LayerNorm + pack into MFMA-fragment order (mt folded in)
// KF[bh][kt][s][l][j] = K[t=kt*32+(l&31)][d = s*16 + (l>>5)*8 + j] * mt
__global__ void ln_head_pack_k(const unsigned short* __restrict__ Y,
                               unsigned short* __restrict__ KF,
                               const float* __restrict__ lw, const float* __restrict__ lb,
                               const float* __restrict__ Mcat,
                               float scale) {
    int gw = blockIdx.x * 4 + (threadIdx.x >> 6);
    int lane = threadIdx.x & 63;
    int h = gw % HEADS_;
    int row = gw / HEADS_;                   // [0, B*T)
    int b = row / T_LEN, r = row % T_LEN;
    float v = bf2f(Y[(size_t)row * EMB_ + h * 64 + lane]);
    float s = v, s2 = v * v;
#pragma unroll
    for (int m = 1; m <= 32; m <<= 1) {
        s += __shfl_xor(s, m);
        s2 += __shfl_xor(s2, m);
    }
    float mu = s * (1.f / 64.f);
    float var = s2 * (1.f / 64.f) - mu * mu;
    float o = (v - mu) * rsqrtf(var + 1e-5f) * lw[lane] + lb[lane];
    float mt = Mcat[(size_t)b * T_LEN + r];
    int bh = b * HEADS_ + h;
    int kt = r >> 5, l31 = r & 31;
    int sf = lane >> 4, hi = (lane >> 3) & 1, j = lane & 7;
    size_t flat = ((((size_t)bh * 128 + kt) * 4 + sf) * 64 + hi * 32 + l31) * 8 + j;
    KF[flat] = f2bf(o * scale * mt);
}

// ------------------------- V pack into MFMA-fragment order (mt folded in)
// VF[bh][kt][f][l][j] = V^T[d][t] * mt:
//   d = (f>>1)*32 + (l&31)
//   t = kt*32 + (f&1)*16 + (j>>2)*8 + 4*(l>>5) + (j&3)
__global__ void vpack_k(const unsigned short* __restrict__ Yv, unsigned short* __restrict__ VF,
                        const float* __restrict__ Mcat) {
    __shared__ __align__(16) unsigned short tile[64][72];   // [t][d]
    __shared__ float msk[64];
    int t0 = blockIdx.x * 64;      // 64 t-rows = 2 kt tiles
    int bh = blockIdx.y;
    int b = bh >> 4, h = bh & 15;
    int tid = threadIdx.x;
    if (tid < 64) msk[tid] = Mcat[(size_t)b * T_LEN + t0 + tid];
#pragma unroll
    for (int rr = 0; rr < 2; ++rr) {
        int idx = tid + rr * 256;
        int row = idx >> 3, c8 = idx & 7;
        *(uint4*)&tile[row][c8 * 8] =
            *(const uint4*)&Yv[((size_t)b * T_LEN + t0 + row) * EMB_ + h * 64 + c8 * 8];
    }
    __syncthreads();
    int f = tid >> 6, l = tid & 63;
    int d = (f >> 1) * 32 + (l & 31);
    int tb = (f & 1) * 16 + 4 * (l >> 5);
#pragma unroll
    for (int ktl = 0; ktl < 2; ++ktl) {
        unsigned short e[8];
#pragma unroll
        for (int j = 0; j < 8; ++j) {
            int tt = ktl * 32 + tb + (j >> 2) * 8 + (j & 3);
            e[j] = f2bf(bf2f(tile[tt][d]) * msk[tt]);
        }
        uint4 o;
        o.x = (unsigned)e[0] | ((unsigned)e[1] << 16);
        o.y = (unsigned)e[2] | ((unsigned)e[3] << 16);
        o.z = (unsigned)e[4] | ((unsigned)e[5] << 16);
        o.w = (unsigned)e[6] | ((unsigned)e[7] << 16);
        size_t kt = (size_t)blockIdx.x * 2 + ktl;
        *(uint4*)&VF[((((size_t)bh * 128 + kt) * 4 + f) * 64 + l) * 8] = o;
    }
}

// ---------------------------------------------------------- flash attention
// Masks pre-folded: Q *= mq (and log2e), K *= mt, V *= mt. mq cancels in the
// final ratio (mq==0 rows zeroed in epilogue). IMMEDIATE rescale (e <= 1,
// r6 semantics — defer-rescale and pk_fma reverted after r7's accuracy fail).
#define SOFTMAX(SA, MM, LS, ACA, ACB, PB0, PB1) do {                              \
    float ta_ = fmaxf(fmaxf(SA[0], SA[1]), SA[2]);                                \
    float tb_ = fmaxf(fmaxf(SA[3], SA[4]), SA[5]);                                \
    float tc_ = fmaxf(fmaxf(SA[6], SA[7]), SA[8]);                                \
    float td_ = fmaxf(fmaxf(SA[9], SA[10]), SA[11]);                              \
    float te_ = fmaxf(fmaxf(SA[12], SA[13]), SA[14]);                             \
    float tm_ = fmaxf(fmaxf(fmaxf(ta_, tb_), tc_),                                \
                      fmaxf(fmaxf(td_, te_), SA[15]));                            \
    tm_ = fmaxf(tm_, __shfl_xor(tm_, 32));                                        \
    if (__any(tm_ > (MM))) {                                                      \
        float mn_ = fmaxf((MM), tm_);                                             \
        float al_ = __builtin_amdgcn_exp2f((MM) - mn_);                           \
        (MM) = mn_; (LS) *= al_; (ACA) *= al_; (ACB) *= al_;                      \
    }                                                                             \
    f32x2 nM_ = {-(MM), -(MM)};                                                   \
    f32x2 e2[8];                                                                  \
    _Pragma("unroll") for (int i_ = 0; i_ < 8; ++i_) {                            \
        e2[i_] = pk_add((f32x2){SA[2 * i_], SA[2 * i_ + 1]}, nM_);                \
        e2[i_][0] = __builtin_amdgcn_exp2f(e2[i_][0]);                            \
        e2[i_][1] = __builtin_amdgcn_exp2f(e2[i_][1]);                            \
    }                                                                             \
    {                                                                             \
        float rsA_ = 0.f, rsB_ = 0.f;                                             \
        _Pragma("unroll") for (int i_ = 0; i_ < 8; ++i_) {                        \
            rsA_ = fmaf(e2[i_][0], mt_[2 * i_], rsA_);                            \
            rsB_ = fmaf(e2[i_][1], mt_[2 * i_ + 1], rsB_);                        \
        }                                                                         \
        float rs_ = rsA_ + rsB_;                                                  \
        rs_ += __shfl_xor(rs_, 32);                                               \
        (LS) += rs_;                                                              \
    }                                                                             \
    unsigned pk_[8];                                                              \
    _Pragma("unroll") for (int d_ = 0; d_ < 8; ++d_)                              \
        asm("v_cvt_pk_bf16_f32 %0, %1, %2" : "=v"(pk_[d_])                        \
            : "v"(e2[d_][0]), "v"(e2[d_][1]));                                    \
    { uint4 u0_; u0_.x=pk_[0]; u0_.y=pk_[1]; u0_.z=pk_[2]; u0_.w=pk_[3];          \
      uint4 u1_; u1_.x=pk_[4]; u1_.y=pk_[5]; u1_.z=pk_[6]; u1_.w=pk_[7];          \
      (PB0) = __builtin_bit_cast(bf16x8, u0_);                                    \
      (PB1) = __builtin_bit_cast(bf16x8, u1_); }                                  \
} while (0)

#define LOADK(DST, KT) do {                                                       \
    const unsigned short* p_ = KFl + (size_t)(KT) * 2048;                         \
    DST[0] = *(const uint4*)(p_);                                                 \
    DST[1] = *(const uint4*)(p_ + 512);                                           \
    DST[2] = *(const uint4*)(p_ + 1024);                                          \
    DST[3] = *(const uint4*)(p_ + 1536);                                          \
} while (0)

__global__ __launch_bounds__(256) void attn32_k(
    const unsigned short* __restrict__ Q,    // [B,H,S,64], pre-scaled (log2e, mq)
    const unsigned short* __restrict__ KF,   // fragment-packed K (mt folded)
    const unsigned short* __restrict__ VF,   // fragment-packed V^T (mt folded)
    const float* __restrict__ Mcat,          // [B,T]
    unsigned short* __restrict__ O) {        // [B,S,EMB]
    __shared__ float Olds[4][32][64];
    __shared__ float Mlds[4][64];
    __shared__ float Llds[4][64];

    // XCD swizzle: each XCD owns 4 consecutive bh -> K/V fits its private L2.
    int bid = blockIdx.x;
    int xcd = bid & 7, slot = bid >> 3;        // 8 XCDs x 128 slots
    int bh = xcd * 4 + (slot >> 5);            // 4 bh per XCD
    int qblk = slot & 31;                      // 32 q-blocks of 64 rows
    int b = bh >> 4, h = bh & 15;
    int tid = threadIdx.x;
    int w = tid >> 6;
    int lane = tid & 63;
    int l31 = lane & 31;
    int hi = lane >> 5;
    int q0 = qblk * 64;

    const unsigned short* KFl = KF + (size_t)bh * 262144 + lane * 8;
    const unsigned short* VFl = VF + (size_t)bh * 262144 + lane * 8;
    const float* Mb = Mcat + (size_t)b * T_LEN;

    // Q fragments (held for whole kernel)
    bf16x8 qf0[4], qf1[4];
    {
        const unsigned short* Qp0 = Q + ((size_t)bh * S_LEN + q0 + l31) * 64 + hi * 8;
        const unsigned short* Qp1 = Qp0 + (size_t)32 * 64;
#pragma unroll
        for (int s = 0; s < 4; ++s) {
            qf0[s] = *(const bf16x8*)(Qp0 + s * 16);
            qf1[s] = *(const bf16x8*)(Qp1 + s * 16);
        }
    }

    f32x16 Z16;
#pragma unroll
    for (int i = 0; i < 16; ++i) Z16[i] = 0.f;
    f32x16 acc00 = Z16, acc01 = Z16, acc10 = Z16, acc11 = Z16;  // acc[db][qb]
    float mM0 = -1e38f, mM1 = -1e38f, lS0 = 0.f, lS1 = 0.f;

    auto TILE = [&](const uint4* kf, int kt) {
        // --- V fragment loads (coalesced; latency hides under QK+softmax) ---
        const unsigned short* pv = VFl + (size_t)kt * 2048;
        uint4 vfr0 = *(const uint4*)(pv);
        uint4 vfr1 = *(const uint4*)(pv + 512);
        uint4 vfr2 = *(const uint4*)(pv + 1024);
        uint4 vfr3 = *(const uint4*)(pv + 1536);
        // --- t-mask loads (only needed for the denominator sum) ---
        const float* mbase = Mb + kt * 32 + 4 * hi;
        float4 mf0 = *(const float4*)(mbase);
        float4 mf1 = *(const float4*)(mbase + 8);
        float4 mf2 = *(const float4*)(mbase + 16);
        float4 mf3 = *(const float4*)(mbase + 24);
        // --- S^T = K · Q^T (masks pre-folded: sa IS z) ---
        f32x16 sa0 = Z16, sa1 = Z16;
#pragma unroll
        for (int s = 0; s < 4; ++s) {
            bf16x8 kfr = __builtin_bit_cast(bf16x8, kf[s]);
            sa0 = __builtin_amdgcn_mfma_f32_32x32x16_bf16(kfr, qf0[s], sa0, 0, 0, 0);
            sa1 = __builtin_amdgcn_mfma_f32_32x32x16_bf16(kfr, qf1[s], sa1, 0, 0, 0);
        }
        float mt_[16];
        mt_[0] = mf0.x; mt_[1] = mf0.y; mt_[2]  = mf0.z; mt_[3]  = mf0.w;
        mt_[4] = mf1.x; mt_[5] = mf1.y; mt_[6]  = mf1.z; mt_[7]  = mf1.w;
        mt_[8] = mf2.x; mt_[9] = mf2.y; mt_[10] = mf2.z; mt_[11] = mf2.w;
        mt_[12] = mf3.x; mt_[13] = mf3.y; mt_[14] = mf3.z; mt_[15] = mf3.w;
        // --- online softmax (lane-local; no mask muls on p path) ---
        bf16x8 p00, p01, p10, p11;
        SOFTMAX(sa0, mM0, lS0, acc00, acc10, p00, p01);
        SOFTMAX(sa1, mM1, lS1, acc01, acc11, p10, p11);
        // --- O^T += V^T · P^T (sigma-permuted k so P frags are lane-local) ---
        bf16x8 vf;
        vf = __builtin_bit_cast(bf16x8, vfr0);
        acc00 = __builtin_amdgcn_mfma_f32_32x32x16_bf16(vf, p00, acc00, 0, 0, 0);
        acc01 = __builtin_amdgcn_mfma_f32_32x32x16_bf16(vf, p10, acc01, 0, 0, 0);
        vf = __builtin_bit_cast(bf16x8, vfr1);
        acc00 = __builtin_amdgcn_mfma_f32_32x32x16_bf16(vf, p01, acc00, 0, 0, 0);
        acc01 = __builtin_amdgcn_mfma_f32_32x32x16_bf16(vf, p11, acc01, 0, 0, 0);
        vf = __builtin_bit_cast(bf16x8, vfr2);
        acc10 = __builtin_amdgcn_mfma_f32_32x32x16_bf16(vf, p00, acc10, 0, 0, 0);
        acc11 = __builtin_amdgcn_mfma_f32_32x32x16_bf16(vf, p10, acc11, 0, 0, 0);
        vf = __builtin_bit_cast(bf16x8, vfr3);
        acc10 = __builtin_amdgcn_mfma_f32_32x32x16_bf16(vf, p01, acc10, 0, 0, 0);
        acc11 = __builtin_amdgcn_mfma_f32_32x32x16_bf16(vf, p11, acc11, 0, 0, 0);
    };

    // --- main t-loop: wave w owns tiles kt = w, w+4, ..., w+124 (no barriers) ---
    uint4 ka[4], kb[4];
    LOADK(ka, w);
    for (int it = 0; it < 32; it += 2) {
        int kt0 = w + it * 4;
        LOADK(kb, kt0 + 4);
        TILE(ka, kt0);
        LOADK(ka, (it + 2 < 32) ? kt0 + 8 : kt0);
        TILE(kb, kt0 + 4);
    }

    // --- merge 4 waves' partial (m, l, O^T) via LDS, two d-halves ---
    if (hi == 0) {
        Mlds[w][l31] = mM0;      Llds[w][l31] = lS0;
        Mlds[w][32 + l31] = mM1; Llds[w][32 + l31] = lS1;
    }
    int qm = tid & 63;
    float f0, f1, f2, f3, invL;

    // pass 0: db = 0
#pragma unroll
    for (int r = 0; r < 16; ++r) {
        int dl = (r & 3) + 8 * (r >> 2) + 4 * hi;
        Olds[w][dl][l31] = acc00[r];
        Olds[w][dl][32 + l31] = acc01[r];
    }
    __syncthreads();
    {
        float m0_ = Mlds[0][qm], m1_ = Mlds[1][qm], m2_ = Mlds[2][qm], m3_ = Mlds[3][qm];
        float Mx = fmaxf(fmaxf(m0_, m1_), fmaxf(m2_, m3_));
        f0 = __builtin_amdgcn_exp2f(m0_ - Mx);
        f1 = __builtin_amdgcn_exp2f(m1_ - Mx);
        f2 = __builtin_amdgcn_exp2f(m2_ - Mx);
        f3 = __builtin_amdgcn_exp2f(m3_ - Mx);
        float L = Llds[0][qm] * f0 + Llds[1][qm] * f1 + Llds[2][qm] * f2 + Llds[3][qm] * f3;
        invL = 1.f / (L + 1e-13f);
        float mqz = Mb[q0 + qm];                // zero out rows with mq == 0
        invL = (mqz != 0.f) ? invL : 0.f;
    }
    {
        float v_[8];
#pragma unroll
        for (int dd = 0; dd < 8; ++dd) {
            int d = w * 8 + dd;
            v_[dd] = (Olds[0][d][qm] * f0 + Olds[1][d][qm] * f1 +
                      Olds[2][d][qm] * f2 + Olds[3][d][qm] * f3) * invL;
        }
        unsigned po_[4];
#pragma unroll
        for (int d2 = 0; d2 < 4; ++d2)
            asm("v_cvt_pk_bf16_f32 %0, %1, %2" : "=v"(po_[d2]) : "v"(v_[2*d2]), "v"(v_[2*d2+1]));
        uint4 st; st.x = po_[0]; st.y = po_[1]; st.z = po_[2]; st.w = po_[3];
        *(uint4*)&O[((size_t)b * S_LEN + q0 + qm) * EMB_ + h * 64 + w * 8] = st;
    }
    __syncthreads();
    // pass 1: db = 1
#pragma unroll
    for (int r = 0; r < 16; ++r) {
        int dl = (r & 3) + 8 * (r >> 2) + 4 * hi;
        Olds[w][dl][l31] = acc10[r];
        Olds[w][dl][32 + l31] = acc11[r];
    }
    __syncthreads();
    {
        float v_[8];
#pragma unroll
        for (int dd = 0; dd < 8; ++dd) {
            int d = w * 8 + dd;
            v_[dd] = (Olds[0][d][qm] * f0 + Olds[1][d][qm] * f1 +
                      Olds[2][d][qm] * f2 + Olds[3][d][qm] * f3) * invL;
        }
        unsigned po_[4];
#pragma unroll
        for (int d2 = 0; d2 < 4; ++d2)
            asm("v_cvt_pk_bf16_f32 %0, %1, %2" : "=v"(po_[d2]) : "v"(v_[2*d2]), "v"(v_[2*d2+1]));
        uint4 st; st.x = po_[0]; st.y = po_[1]; st.z = po_[2]; st.w = po_[3];
        *(uint4*)&O[((size_t)b * S_LEN + q0 + qm) * EMB_ + h * 64 + 32 + w * 8] = st;
    }
}

// ------------------------------------------------------------------ launch
extern "C" void kernel_launch(void* const* d_in, const int* in_sizes, int n_in,
                              void* d_out, int out_size, void* d_ws, size_t ws_size,
                              hipStream_t stream) {
    const float* x     = (const float*)d_in[0];
    const float* ctx   = (const float*)d_in[1];
    const float* mask  = (const float*)d_in[2];
    const float* cmask = (const float*)d_in[3];
    const float* Wq    = (const float*)d_in[4];
    const float* Wk    = (const float*)d_in[5];
    const float* Wv    = (const float*)d_in[6];
    const float* Wu    = (const float*)d_in[7];
    const float* bu    = (const float*)d_in[8];
    const float* qlnw  = (const float*)d_in[9];
    const float* qlnb  = (const float*)d_in[10];
    const float* klnw  = (const float*)d_in[11];
    const float* klnb  = (const float*)d_in[12];

    unsigned short* ws = (unsigned short*)d_ws;
    unsigned short* xcb = ws + 0;               //  8,388,608 elems
    unsigned short* WqT = ws + 8388608;         //  1,048,576
    unsigned short* WkT = ws + 9437184;
    unsigned short* WvT = ws + 10485760;
    unsigned short* Qb  = ws + 0;               //  4,194,304 (over dead xcb)
    unsigned short* KFb = ws + 4194304;         //  8,388,608 (over dead xcb/W*T)
    unsigned short* WuT = ws + 12582912;        //  1,048,576 (lives to the end)
    unsigned short* Yq  = ws + 13631488;        //  4,194,304 ; reused as O
    unsigned short* Ob  = Yq;
    unsigned short* Yk  = ws + 17825792;        //  8,388,608 ; reused as VF
    unsigned short* VFb = Yk;
    unsigned short* Yv  = ws + 26214400;        //  8,388,608
    float* Mcat         = (float*)(ws + 34603008);  // 8192 floats

    const float scale = 0.17677669529663687f;               // 1024^-0.25
    const float qscale = 0.17677669529663687f * 1.4426950408889634f; // * log2(e)

    build_xcb_k<<<4096, 256, 0, stream>>>(x, ctx, xcb);
    mcat_k<<<32, 256, 0, stream>>>(mask, cmask, Mcat);
    wtrans4_k<<<dim3(16, 16, 4), 256, 0, stream>>>(Wq, Wk, Wv, Wu, WqT, WkT, WvT, WuT);

    gemm_bt_k<false><<<dim3(8, 64), 256, 0, stream>>>(xcb, WkT, Yk, nullptr, 64, 8192);
    gemm_bt_k<false><<<dim3(8, 64), 256, 0, stream>>>(xcb, WvT, Yv, nullptr, 64, 8192);
    gemm_bt_k<false><<<dim3(8, 32), 256, 0, stream>>>(xcb, WqT, Yq, nullptr, 16, 4096);

    ln_head_k<<<16384, 256, 0, stream>>>(Yq, Qb, qlnw, qlnb, Mcat, S_LEN, qscale);
    ln_head_pack_k<<<32768, 256, 0, stream>>>(Yk, KFb, klnw, klnb, Mcat, scale);
    vpack_k<<<dim3(64, 32), 256, 0, stream>>>(Yv, VFb, Mcat);

    attn32_k<<<1024, 256, 0, stream>>>(Qb, KFb, VFb, Mcat, Ob);

    gemm_bt_k<true><<<dim3(8, 32), 256, 0, stream>>>(Ob, WuT, d_out, bu, 32, 4096);
}

// Round 9
// 294.117 us; speedup vs baseline: 1.2041x; 1.0263x over previous
//
#include <hip/hip_runtime.h>
#include <hip/hip_bf16.h>
#include <cstdint>

#define B_SZ   2
#define S_LEN  2048
#define C_LEN  2048
#define T_LEN  4096
#define EMB_   1024
#define HEADS_ 16
#define D_     64

typedef __attribute__((ext_vector_type(8))) short bf16x8;
typedef __attribute__((ext_vector_type(4))) float f32x4;
typedef __attribute__((ext_vector_type(16))) float f32x16;
typedef __attribute__((ext_vector_type(2))) float f32x2;

__device__ __forceinline__ unsigned short f2bf(float f) {
    unsigned u = __builtin_bit_cast(unsigned, f);
    u += 0x7fffu + ((u >> 16) & 1u);
    return (unsigned short)(u >> 16);
}
__device__ __forceinline__ float bf2f(unsigned short h) {
    return __builtin_bit_cast(float, (unsigned)h << 16);
}

// ---------------------------------------------------------------- xcb build
__global__ void build_xcb_k(const float* __restrict__ x, const float* __restrict__ ctx,
                            unsigned short* __restrict__ xcb) {
    int i = blockIdx.x * blockDim.x + threadIdx.x;      // one 8-elem chunk
    size_t e8 = (size_t)i * 8;
    int b = (int)(e8 / ((size_t)T_LEN * EMB_));
    size_t rem = e8 % ((size_t)T_LEN * EMB_);
    int t = (int)(rem / EMB_);
    int c = (int)(rem % EMB_);
    const float* src = (t < S_LEN)
        ? &x[((size_t)b * S_LEN + t) * EMB_ + c]
        : &ctx[((size_t)b * C_LEN + (t - S_LEN)) * EMB_ + c];
    float4 v0 = ((const float4*)src)[0];
    float4 v1 = ((const float4*)src)[1];
    uint4 o;
    o.x = (unsigned)f2bf(v0.x) | ((unsigned)f2bf(v0.y) << 16);
    o.y = (unsigned)f2bf(v0.z) | ((unsigned)f2bf(v0.w) << 16);
    o.z = (unsigned)f2bf(v1.x) | ((unsigned)f2bf(v1.y) << 16);
    o.w = (unsigned)f2bf(v1.z) | ((unsigned)f2bf(v1.w) << 16);
    *(uint4*)&xcb[e8] = o;
}

// --------------------------------------------------------------- mask concat
__global__ void mcat_k(const float* __restrict__ mask, const float* __restrict__ cmask,
                       float* __restrict__ Mcat) {
    int i = blockIdx.x * 256 + threadIdx.x;   // B*T total
    int b = i / T_LEN, t = i % T_LEN;
    Mcat[i] = (t < S_LEN) ? mask[(size_t)b * S_LEN + t]
                          : cmask[(size_t)b * C_LEN + (t - S_LEN)];
}

// ---------------------- weight transpose+convert (all 4 weights, one launch)
__global__ void wtrans4_k(const float* __restrict__ W0, const float* __restrict__ W1,
                          const float* __restrict__ W2, const float* __restrict__ W3,
                          unsigned short* __restrict__ T0, unsigned short* __restrict__ T1,
                          unsigned short* __restrict__ T2, unsigned short* __restrict__ T3) {
    __shared__ __align__(16) unsigned short tile[64][72];
    int bx = blockIdx.x, by = blockIdx.y, bz = blockIdx.z;
    const float* W = (bz == 0) ? W0 : (bz == 1) ? W1 : (bz == 2) ? W2 : W3;
    unsigned short* WT = (bz == 0) ? T0 : (bz == 1) ? T1 : (bz == 2) ? T2 : T3;
    int tid = threadIdx.x;
#pragma unroll
    for (int r = 0; r < 4; ++r) {
        int idx = tid + r * 256;
        int row = idx >> 4, c4 = idx & 15;
        float4 v = ((const float4*)&W[((size_t)(by * 64 + row)) * EMB_ + bx * 64])[c4];
        tile[row][c4 * 4 + 0] = f2bf(v.x);
        tile[row][c4 * 4 + 1] = f2bf(v.y);
        tile[row][c4 * 4 + 2] = f2bf(v.z);
        tile[row][c4 * 4 + 3] = f2bf(v.w);
    }
    __syncthreads();
#pragma unroll
    for (int r = 0; r < 2; ++r) {
        int idx = tid + r * 256;
        int n = idx >> 3, k8 = idx & 7;
        uint4 o;
        unsigned q[4];
#pragma unroll
        for (int j = 0; j < 4; ++j)
            q[j] = (unsigned)tile[k8 * 8 + 2 * j][n] | ((unsigned)tile[k8 * 8 + 2 * j + 1][n] << 16);
        o.x = q[0]; o.y = q[1]; o.z = q[2]; o.w = q[3];
        *(uint4*)&WT[((size_t)(bx * 64 + n)) * EMB_ + by * 64 + k8 * 8] = o;
    }
}

// ---------------------------------------------------------------- GEMM (m97-style)
template <bool F32OUT>
__global__ __launch_bounds__(256) void gemm_bt_k(
    const unsigned short* __restrict__ A,
    const unsigned short* __restrict__ Bt,
    void* __restrict__ Cout,
    const float* __restrict__ bias,
    int mtiles_per_chunk, int chunk_stride) {
    constexpr int KTOT = 1024, NTOT = 1024;
    __shared__ __align__(16) unsigned short As[128 * 32];
    __shared__ __align__(16) unsigned short Bs[128 * 32];
    int nt = blockIdx.x, mt = blockIdx.y;
    int in_row0 = (mt / mtiles_per_chunk) * chunk_stride + (mt % mtiles_per_chunk) * 128;
    int out_row0 = mt * 128;
    int tid = threadIdx.x, w = tid >> 6, l = tid & 63, l15 = l & 15, lg = l >> 4;
    int wr = (w >> 1) * 64, wc = (w & 1) * 64;

    f32x4 zero4 = {0.f, 0.f, 0.f, 0.f};
    f32x4 acc[4][4];
#pragma unroll
    for (int i = 0; i < 4; ++i)
#pragma unroll
        for (int j = 0; j < 4; ++j) acc[i][j] = zero4;

    for (int k0 = 0; k0 < KTOT; k0 += 32) {
#pragma unroll
        for (int j = 0; j < 2; ++j) {
            int o = tid * 16 + j * 4096;        // byte offset in 8KB tile
            int row = o >> 6;                   // 64B per row (32 bf16)
            int ke = (o & 63) >> 1;             // element offset in row
            __builtin_amdgcn_global_load_lds(
                (const __attribute__((address_space(1))) void*)&A[(size_t)(in_row0 + row) * KTOT + k0 + ke],
                (__attribute__((address_space(3))) void*)&As[o >> 1], 16, 0, 0);
            __builtin_amdgcn_global_load_lds(
                (const __attribute__((address_space(1))) void*)&Bt[(size_t)(nt * 128 + row) * KTOT + k0 + ke],
                (__attribute__((address_space(3))) void*)&Bs[o >> 1], 16, 0, 0);
        }
        __syncthreads();
        bf16x8 af[4], bf[4];
#pragma unroll
        for (int fr = 0; fr < 4; ++fr)
            af[fr] = *(const bf16x8*)&As[(wr + fr * 16 + l15) * 32 + lg * 8];
#pragma unroll
        for (int fc = 0; fc < 4; ++fc)
            bf[fc] = *(const bf16x8*)&Bs[(wc + fc * 16 + l15) * 32 + lg * 8];
#pragma unroll
        for (int fr = 0; fr < 4; ++fr)
#pragma unroll
            for (int fc = 0; fc < 4; ++fc)
                acc[fr][fc] = __builtin_amdgcn_mfma_f32_16x16x32_bf16(af[fr], bf[fc], acc[fr][fc], 0, 0, 0);
        __syncthreads();
    }
#pragma unroll
    for (int fr = 0; fr < 4; ++fr) {
#pragma unroll
        for (int fc = 0; fc < 4; ++fc) {
            int row = out_row0 + wr + fr * 16 + lg * 4;
            int col = nt * 128 + wc + fc * 16 + l15;
#pragma unroll
            for (int i = 0; i < 4; ++i) {
                float v = acc[fr][fc][i];
                if (F32OUT) {
                    ((float*)Cout)[(size_t)(row + i) * NTOT + col] = v + bias[col];
                } else {
                    ((unsigned short*)Cout)[(size_t)(row + i) * NTOT + col] = f2bf(v);
                }
            }
        }
    }
}

// ----------------------- Q LayerNorm (+scale*log2e, mask-fold mq into rows)
__global__ void ln_head_k(const unsigned short* __restrict__ Y,
                          unsigned short* __restrict__ Out,
                          const float* __restrict__ lw, const float* __restrict__ lb,
                          const float* __restrict__ Mcat,
                          int rows_per_b, float scale) {
    int gw = blockIdx.x * 4 + (threadIdx.x >> 6);
    int lane = threadIdx.x & 63;
    int h = gw % HEADS_;
    int row = gw / HEADS_;                   // [0, B*rows_per_b)
    int b = row / rows_per_b, r = row % rows_per_b;
    float v = bf2f(Y[(size_t)row * EMB_ + h * 64 + lane]);
    float s = v, s2 = v * v;
#pragma unroll
    for (int m = 1; m <= 32; m <<= 1) {
        s += __shfl_xor(s, m);
        s2 += __shfl_xor(s2, m);
    }
    float mu = s * (1.f / 64.f);
    float var = s2 * (1.f / 64.f) - mu * mu;
    float o = (v - mu) * rsqrtf(var + 1e-5f) * lw[lane] + lb[lane];
    float mq = Mcat[(size_t)b * T_LEN + r];  // r < S
    Out[(((size_t)b * HEADS_ + h) * rows_per_b + r) * 64 + lane] = f2bf(o * scale * mq);
}

// ------------- K LayerNorm + pack into MFMA-fragment order (mt folded in)
// KF[bh][kt][s][l][j] = K[t=kt*32+(l&31)][d = s*16 + (l>>5)*8 + j] * mt
__global__ void ln_head_pack_k(const unsigned short* __restrict__ Y,
                               unsigned short* __restrict__ KF,
                               const float* __restrict__ lw, const float* __restrict__ lb,
                               const float* __restrict__ Mcat,
                               float scale) {
    int gw = blockIdx.x * 4 + (threadIdx.x >> 6);
    int lane = threadIdx.x & 63;
    int h = gw % HEADS_;
    int row = gw / HEADS_;                   // [0, B*T)
    int b = row / T_LEN, r = row % T_LEN;
    float v = bf2f(Y[(size_t)row * EMB_ + h * 64 + lane]);
    float s = v, s2 = v * v;
#pragma unroll
    for (int m = 1; m <= 32; m <<= 1) {
        s += __shfl_xor(s, m);
        s2 += __shfl_xor(s2, m);
    }
    float mu = s * (1.f / 64.f);
    float var = s2 * (1.f / 64.f) - mu * mu;
    float o = (v - mu) * rsqrtf(var + 1e-5f) * lw[lane] + lb[lane];
    float mt = Mcat[(size_t)b * T_LEN + r];
    int bh = b * HEADS_ + h;
    int kt = r >> 5, l31 = r & 31;
    int sf = lane >> 4, hi = (lane >> 3) & 1, j = lane & 7;
    size_t flat = ((((size_t)bh * 128 + kt) * 4 + sf) * 64 + hi * 32 + l31) * 8 + j;
    KF[flat] = f2bf(o * scale * mt);
}

// ------------------------- V pack into MFMA-fragment order (mt folded in)
// VF[bh][kt][f][l][j] = V^T[d][t] * mt:
//   d = (f>>1)*32 + (l&31)
//   t = kt*32 + (f&1)*16 + (j>>2)*8 + 4*(l>>5) + (j&3)
__global__ void vpack_k(const unsigned short* __restrict__ Yv, unsigned short* __restrict__ VF,
                        const float* __restrict__ Mcat) {
    __shared__ __align__(16) unsigned short tile[64][72];   // [t][d]
    __shared__ float msk[64];
    int t0 = blockIdx.x * 64;      // 64 t-rows = 2 kt tiles
    int bh = blockIdx.y;
    int b = bh >> 4, h = bh & 15;
    int tid = threadIdx.x;
    if (tid < 64) msk[tid] = Mcat[(size_t)b * T_LEN + t0 + tid];
#pragma unroll
    for (int rr = 0; rr < 2; ++rr) {
        int idx = tid + rr * 256;
        int row = idx >> 3, c8 = idx & 7;
        *(uint4*)&tile[row][c8 * 8] =
            *(const uint4*)&Yv[((size_t)b * T_LEN + t0 + row) * EMB_ + h * 64 + c8 * 8];
    }
    __syncthreads();
    int f = tid >> 6, l = tid & 63;
    int d = (f >> 1) * 32 + (l & 31);
    int tb = (f & 1) * 16 + 4 * (l >> 5);
#pragma unroll
    for (int ktl = 0; ktl < 2; ++ktl) {
        unsigned short e[8];
#pragma unroll
        for (int j = 0; j < 8; ++j) {
            int tt = ktl * 32 + tb + (j >> 2) * 8 + (j & 3);
            e[j] = f2bf(bf2f(tile[tt][d]) * msk[tt]);
        }
        uint4 o;
        o.x = (unsigned)e[0] | ((unsigned)e[1] << 16);
        o.y = (unsigned)e[2] | ((unsigned)e[3] << 16);
        o.z = (unsigned)e[4] | ((unsigned)e[5] << 16);
        o.w = (unsigned)e[6] | ((unsigned)e[7] << 16);
        size_t kt = (size_t)blockIdx.x * 2 + ktl;
        *(uint4*)&VF[((((size_t)bh * 128 + kt) * 4 + f) * 64 + l) * 8] = o;
    }
}

// ---------------------------------------------------------- flash attention
// Masks pre-folded: Q *= mq (and log2e), K *= mt, V *= mt. mq cancels in the
// final ratio (mq==0 rows zeroed in epilogue). NO ONLINE MAX: post-LN scores
// have |z| ~ O(3) in log2 domain (scale 1024^-0.25 folded), so p = exp2(z)
// directly is f32-safe; removes fmax tree, rescale branch, acc rescales, and
// the (z - m) subtraction. Merge across waves is then a plain sum.
#define SOFTMAX(SA, LS, PB0, PB1) do {                                            \
    f32x2 e2[8];                                                                  \
    _Pragma("unroll") for (int i_ = 0; i_ < 8; ++i_) {                            \
        e2[i_][0] = __builtin_amdgcn_exp2f(SA[2 * i_]);                           \
        e2[i_][1] = __builtin_amdgcn_exp2f(SA[2 * i_ + 1]);                       \
    }                                                                             \
    {                                                                             \
        float rsA_ = 0.f, rsB_ = 0.f;                                             \
        _Pragma("unroll") for (int i_ = 0; i_ < 8; ++i_) {                        \
            rsA_ = fmaf(e2[i_][0], mt_[2 * i_], rsA_);                            \
            rsB_ = fmaf(e2[i_][1], mt_[2 * i_ + 1], rsB_);                        \
        }                                                                         \
        float rs_ = rsA_ + rsB_;                                                  \
        rs_ += __shfl_xor(rs_, 32);                                               \
        (LS) += rs_;                                                              \
    }                                                                             \
    unsigned pk_[8];                                                              \
    _Pragma("unroll") for (int d_ = 0; d_ < 8; ++d_)                              \
        asm("v_cvt_pk_bf16_f32 %0, %1, %2" : "=v"(pk_[d_])                        \
            : "v"(e2[d_][0]), "v"(e2[d_][1]));                                    \
    { uint4 u0_; u0_.x=pk_[0]; u0_.y=pk_[1]; u0_.z=pk_[2]; u0_.w=pk_[3];          \
      uint4 u1_; u1_.x=pk_[4]; u1_.y=pk_[5]; u1_.z=pk_[6]; u1_.w=pk_[7];          \
      (PB0) = __builtin_bit_cast(bf16x8, u0_);                                    \
      (PB1) = __builtin_bit_cast(bf16x8, u1_); }                                  \
} while (0)

#define LOADK(DST, KT) do {                                                       \
    const unsigned short* p_ = KFl + (size_t)(KT) * 2048;                         \
    DST[0] = *(const uint4*)(p_);                                                 \
    DST[1] = *(const uint4*)(p_ + 512);                                           \
    DST[2] = *(const uint4*)(p_ + 1024);                                          \
    DST[3] = *(const uint4*)(p_ + 1536);                                          \
} while (0)

__global__ __launch_bounds__(256) void attn32_k(
    const unsigned short* __restrict__ Q,    // [B,H,S,64], pre-scaled (log2e, mq)
    const unsigned short* __restrict__ KF,   // fragment-packed K (mt folded)
    const unsigned short* __restrict__ VF,   // fragment-packed V^T (mt folded)
    const float* __restrict__ Mcat,          // [B,T]
    unsigned short* __restrict__ O) {        // [B,S,EMB]
    __shared__ float Olds[4][32][64];
    __shared__ float Llds[4][64];

    // XCD swizzle: each XCD owns 4 consecutive bh -> K/V fits its private L2.
    int bid = blockIdx.x;
    int xcd = bid & 7, slot = bid >> 3;        // 8 XCDs x 128 slots
    int bh = xcd * 4 + (slot >> 5);            // 4 bh per XCD
    int qblk = slot & 31;                      // 32 q-blocks of 64 rows
    int b = bh >> 4, h = bh & 15;
    int tid = threadIdx.x;
    int w = tid >> 6;
    int lane = tid & 63;
    int l31 = lane & 31;
    int hi = lane >> 5;
    int q0 = qblk * 64;

    const unsigned short* KFl = KF + (size_t)bh * 262144 + lane * 8;
    const unsigned short* VFl = VF + (size_t)bh * 262144 + lane * 8;
    const float* Mb = Mcat + (size_t)b * T_LEN;

    // Q fragments (held for whole kernel)
    bf16x8 qf0[4], qf1[4];
    {
        const unsigned short* Qp0 = Q + ((size_t)bh * S_LEN + q0 + l31) * 64 + hi * 8;
        const unsigned short* Qp1 = Qp0 + (size_t)32 * 64;
#pragma unroll
        for (int s = 0; s < 4; ++s) {
            qf0[s] = *(const bf16x8*)(Qp0 + s * 16);
            qf1[s] = *(const bf16x8*)(Qp1 + s * 16);
        }
    }

    f32x16 Z16;
#pragma unroll
    for (int i = 0; i < 16; ++i) Z16[i] = 0.f;
    f32x16 acc00 = Z16, acc01 = Z16, acc10 = Z16, acc11 = Z16;  // acc[db][qb]
    float lS0 = 0.f, lS1 = 0.f;

    auto TILE = [&](const uint4* kf, int kt) {
        // --- V fragment loads (coalesced; latency hides under QK+softmax) ---
        const unsigned short* pv = VFl + (size_t)kt * 2048;
        uint4 vfr0 = *(const uint4*)(pv);
        uint4 vfr1 = *(const uint4*)(pv + 512);
        uint4 vfr2 = *(const uint4*)(pv + 1024);
        uint4 vfr3 = *(const uint4*)(pv + 1536);
        // --- t-mask loads (only needed for the denominator sum) ---
        const float* mbase = Mb + kt * 32 + 4 * hi;
        float4 mf0 = *(const float4*)(mbase);
        float4 mf1 = *(const float4*)(mbase + 8);
        float4 mf2 = *(const float4*)(mbase + 16);
        float4 mf3 = *(const float4*)(mbase + 24);
        // --- S^T = K · Q^T (masks pre-folded: sa IS z) ---
        f32x16 sa0 = Z16, sa1 = Z16;
#pragma unroll
        for (int s = 0; s < 4; ++s) {
            bf16x8 kfr = __builtin_bit_cast(bf16x8, kf[s]);
            sa0 = __builtin_amdgcn_mfma_f32_32x32x16_bf16(kfr, qf0[s], sa0, 0, 0, 0);
            sa1 = __builtin_amdgcn_mfma_f32_32x32x16_bf16(kfr, qf1[s], sa1, 0, 0, 0);
        }
        float mt_[16];
        mt_[0] = mf0.x; mt_[1] = mf0.y; mt_[2]  = mf0.z; mt_[3]  = mf0.w;
        mt_[4] = mf1.x; mt_[5] = mf1.y; mt_[6]  = mf1.z; mt_[7]  = mf1.w;
        mt_[8] = mf2.x; mt_[9] = mf2.y; mt_[10] = mf2.z; mt_[11] = mf2.w;
        mt_[12] = mf3.x; mt_[13] = mf3.y; mt_[14] = mf3.z; mt_[15] = mf3.w;
        // --- softmax numerator/denominator (no max tracking) ---
        bf16x8 p00, p01, p10, p11;
        SOFTMAX(sa0, lS0, p00, p01);
        SOFTMAX(sa1, lS1, p10, p11);
        // --- O^T += V^T · P^T (sigma-permuted k so P frags are lane-local) ---
        bf16x8 vf;
        vf = __builtin_bit_cast(bf16x8, vfr0);
        acc00 = __builtin_amdgcn_mfma_f32_32x32x16_bf16(vf, p00, acc00, 0, 0, 0);
        acc01 = __builtin_amdgcn_mfma_f32_32x32x16_bf16(vf, p10, acc01, 0, 0, 0);
        vf = __builtin_bit_cast(bf16x8, vfr1);
        acc00 = __builtin_amdgcn_mfma_f32_32x32x16_bf16(vf, p01, acc00, 0, 0, 0);
        acc01 = __builtin_amdgcn_mfma_f32_32x32x16_bf16(vf, p11, acc01, 0, 0, 0);
        vf = __builtin_bit_cast(bf16x8, vfr2);
        acc10 = __builtin_amdgcn_mfma_f32_32x32x16_bf16(vf, p00, acc10, 0, 0, 0);
        acc11 = __builtin_amdgcn_mfma_f32_32x32x16_bf16(vf, p10, acc11, 0, 0, 0);
        vf = __builtin_bit_cast(bf16x8, vfr3);
        acc10 = __builtin_amdgcn_mfma_f32_32x32x16_bf16(vf, p01, acc10, 0, 0, 0);
        acc11 = __builtin_amdgcn_mfma_f32_32x32x16_bf16(vf, p11, acc11, 0, 0, 0);
    };

    // --- main t-loop: wave w owns tiles kt = w, w+4, ..., w+124 (no barriers) ---
    uint4 ka[4], kb[4];
    LOADK(ka, w);
    for (int it = 0; it < 32; it += 2) {
        int kt0 = w + it * 4;
        LOADK(kb, kt0 + 4);
        TILE(ka, kt0);
        LOADK(ka, (it + 2 < 32) ? kt0 + 8 : kt0);
        TILE(kb, kt0 + 4);
    }

    // --- merge 4 waves' partial (l, O^T) via LDS, two d-halves (plain sums) ---
    if (hi == 0) {
        Llds[w][l31] = lS0;
        Llds[w][32 + l31] = lS1;
    }
    int qm = tid & 63;
    float invL;

    // pass 0: db = 0
#pragma unroll
    for (int r = 0; r < 16; ++r) {
        int dl = (r & 3) + 8 * (r >> 2) + 4 * hi;
        Olds[w][dl][l31] = acc00[r];
        Olds[w][dl][32 + l31] = acc01[r];
    }
    __syncthreads();
    {
        float L = Llds[0][qm] + Llds[1][qm] + Llds[2][qm] + Llds[3][qm];
        invL = 1.f / (L + 1e-13f);
        float mqz = Mb[q0 + qm];                // zero out rows with mq == 0
        invL = (mqz != 0.f) ? invL : 0.f;
    }
    {
        float v_[8];
#pragma unroll
        for (int dd = 0; dd < 8; ++dd) {
            int d = w * 8 + dd;
            v_[dd] = (Olds[0][d][qm] + Olds[1][d][qm] +
                      Olds[2][d][qm] + Olds[3][d][qm]) * invL;
        }
        unsigned po_[4];
#pragma unroll
        for (int d2 = 0; d2 < 4; ++d2)
            asm("v_cvt_pk_bf16_f32 %0, %1, %2" : "=v"(po_[d2]) : "v"(v_[2*d2]), "v"(v_[2*d2+1]));
        uint4 st; st.x = po_[0]; st.y = po_[1]; st.z = po_[2]; st.w = po_[3];
        *(uint4*)&O[((size_t)b * S_LEN + q0 + qm) * EMB_ + h * 64 + w * 8] = st;
    }
    __syncthreads();
    // pass 1: db = 1
#pragma unroll
    for (int r = 0; r < 16; ++r) {
        int dl = (r & 3) + 8 * (r >> 2) + 4 * hi;
        Olds[w][dl][l31] = acc10[r];
        Olds[w][dl][32 + l31] = acc11[r];
    }
    __syncthreads();
    {
        float v_[8];
#pragma unroll
        for (int dd = 0; dd < 8; ++dd) {
            int d = w * 8 + dd;
            v_[dd] = (Olds[0][d][qm] + Olds[1][d][qm] +
                      Olds[2][d][qm] + Olds[3][d][qm]) * invL;
        }
        unsigned po_[4];
#pragma unroll
        for (int d2 = 0; d2 < 4; ++d2)
            asm("v_cvt_pk_bf16_f32 %0, %1, %2" : "=v"(po_[d2]) : "v"(v_[2*d2]), "v"(v_[2*d2+1]));
        uint4 st; st.x = po_[0]; st.y = po_[1]; st.z = po_[2]; st.w = po_[3];
        *(uint4*)&O[((size_t)b * S_LEN + q0 + qm) * EMB_ + h * 64 + 32 + w * 8] = st;
    }
}

// ------------------------------------------------------------------ launch
extern "C" void kernel_launch(void* const* d_in, const int* in_sizes, int n_in,
                              void* d_out, int out_size, void* d_ws, size_t ws_size,
                              hipStream_t stream) {
    const float* x     = (const float*)d_in[0];
    const float* ctx   = (const float*)d_in[1];
    const float* mask  = (const float*)d_in[2];
    const float* cmask = (const float*)d_in[3];
    const float* Wq    = (const float*)d_in[4];
    const float* Wk    = (const float*)d_in[5];
    const float* Wv    = (const float*)d_in[6];
    const float* Wu    = (const float*)d_in[7];
    const float* bu    = (const float*)d_in[8];
    const float* qlnw  = (const float*)d_in[9];
    const float* qlnb  = (const float*)d_in[10];
    const float* klnw  = (const float*)d_in[11];
    const float* klnb  = (const float*)d_in[12];

    unsigned short* ws = (unsigned short*)d_ws;
    unsigned short* xcb = ws + 0;               //  8,388,608 elems
    unsigned short* WqT = ws + 8388608;         //  1,048,576
    unsigned short* WkT = ws + 9437184;
    unsigned short* WvT = ws + 10485760;
    unsigned short* Qb  = ws + 0;               //  4,194,304 (over dead xcb)
    unsigned short* KFb = ws + 4194304;         //  8,388,608 (over dead xcb/W*T)
    unsigned short* WuT = ws + 12582912;        //  1,048,576 (lives to the end)
    unsigned short* Yq  = ws + 13631488;        //  4,194,304 ; reused as O
    unsigned short* Ob  = Yq;
    unsigned short* Yk  = ws + 17825792;        //  8,388,608 ; reused as VF
    unsigned short* VFb = Yk;
    unsigned short* Yv  = ws + 26214400;        //  8,388,608
    float* Mcat         = (float*)(ws + 34603008);  // 8192 floats

    const float scale = 0.17677669529663687f;               // 1024^-0.25
    const float qscale = 0.17677669529663687f * 1.4426950408889634f; // * log2(e)

    build_xcb_k<<<4096, 256, 0, stream>>>(x, ctx, xcb);
    mcat_k<<<32, 256, 0, stream>>>(mask, cmask, Mcat);
    wtrans4_k<<<dim3(16, 16, 4), 256, 0, stream>>>(Wq, Wk, Wv, Wu, WqT, WkT, WvT, WuT);

    gemm_bt_k<false><<<dim3(8, 64), 256, 0, stream>>>(xcb, WkT, Yk, nullptr, 64, 8192);
    gemm_bt_k<false><<<dim3(8, 64), 256, 0, stream>>>(xcb, WvT, Yv, nullptr, 64, 8192);
    gemm_bt_k<false><<<dim3(8, 32), 256, 0, stream>>>(xcb, WqT, Yq, nullptr, 16, 4096);

    ln_head_k<<<16384, 256, 0, stream>>>(Yq, Qb, qlnw, qlnb, Mcat, S_LEN, qscale);
    ln_head_pack_k<<<32768, 256, 0, stream>>>(Yk, KFb, klnw, klnb, Mcat, scale);
    vpack_k<<<dim3(64, 32), 256, 0, stream>>>(Yv, VFb, Mcat);

    attn32_k<<<1024, 256, 0, stream>>>(Qb, KFb, VFb, Mcat, Ob);

    gemm_bt_k<true><<<dim3(8, 32), 256, 0, stream>>>(Ob, WuT, d_out, bu, 32, 4096);
}

// Round 11
// 271.884 us; speedup vs baseline: 1.3026x; 1.0818x over previous
//
#include <hip/hip_runtime.h>
#include <hip/hip_bf16.h>
#include <cstdint>

#define B_SZ   2
#define S_LEN  2048
#define C_LEN  2048
#define T_LEN  4096
#define EMB_   1024
#define HEADS_ 16
#define D_     64

typedef __attribute__((ext_vector_type(8))) short bf16x8;
typedef __attribute__((ext_vector_type(4))) float f32x4;
typedef __attribute__((ext_vector_type(16))) float f32x16;
typedef __attribute__((ext_vector_type(2))) float f32x2;

__device__ __forceinline__ unsigned short f2bf(float f) {
    unsigned u = __builtin_bit_cast(unsigned, f);
    u += 0x7fffu + ((u >> 16) & 1u);
    return (unsigned short)(u >> 16);
}
__device__ __forceinline__ float bf2f(unsigned short h) {
    return __builtin_bit_cast(float, (unsigned)h << 16);
}

// ---------------------------------------------------------------- xcb build
__global__ void build_xcb_k(const float* __restrict__ x, const float* __restrict__ ctx,
                            unsigned short* __restrict__ xcb) {
    int i = blockIdx.x * blockDim.x + threadIdx.x;      // one 8-elem chunk
    size_t e8 = (size_t)i * 8;
    int b = (int)(e8 / ((size_t)T_LEN * EMB_));
    size_t rem = e8 % ((size_t)T_LEN * EMB_);
    int t = (int)(rem / EMB_);
    int c = (int)(rem % EMB_);
    const float* src = (t < S_LEN)
        ? &x[((size_t)b * S_LEN + t) * EMB_ + c]
        : &ctx[((size_t)b * C_LEN + (t - S_LEN)) * EMB_ + c];
    float4 v0 = ((const float4*)src)[0];
    float4 v1 = ((const float4*)src)[1];
    uint4 o;
    o.x = (unsigned)f2bf(v0.x) | ((unsigned)f2bf(v0.y) << 16);
    o.y = (unsigned)f2bf(v0.z) | ((unsigned)f2bf(v0.w) << 16);
    o.z = (unsigned)f2bf(v1.x) | ((unsigned)f2bf(v1.y) << 16);
    o.w = (unsigned)f2bf(v1.z) | ((unsigned)f2bf(v1.w) << 16);
    *(uint4*)&xcb[e8] = o;
}

// --------------------------------------------------------------- mask concat
__global__ void mcat_k(const float* __restrict__ mask, const float* __restrict__ cmask,
                       float* __restrict__ Mcat) {
    int i = blockIdx.x * 256 + threadIdx.x;   // B*T total
    int b = i / T_LEN, t = i % T_LEN;
    Mcat[i] = (t < S_LEN) ? mask[(size_t)b * S_LEN + t]
                          : cmask[(size_t)b * C_LEN + (t - S_LEN)];
}

// ---------------------- weight transpose+convert (all 4 weights, one launch)
__global__ void wtrans4_k(const float* __restrict__ W0, const float* __restrict__ W1,
                          const float* __restrict__ W2, const float* __restrict__ W3,
                          unsigned short* __restrict__ T0, unsigned short* __restrict__ T1,
                          unsigned short* __restrict__ T2, unsigned short* __restrict__ T3) {
    __shared__ __align__(16) unsigned short tile[64][72];
    int bx = blockIdx.x, by = blockIdx.y, bz = blockIdx.z;
    const float* W = (bz == 0) ? W0 : (bz == 1) ? W1 : (bz == 2) ? W2 : W3;
    unsigned short* WT = (bz == 0) ? T0 : (bz == 1) ? T1 : (bz == 2) ? T2 : T3;
    int tid = threadIdx.x;
#pragma unroll
    for (int r = 0; r < 4; ++r) {
        int idx = tid + r * 256;
        int row = idx >> 4, c4 = idx & 15;
        float4 v = ((const float4*)&W[((size_t)(by * 64 + row)) * EMB_ + bx * 64])[c4];
        tile[row][c4 * 4 + 0] = f2bf(v.x);
        tile[row][c4 * 4 + 1] = f2bf(v.y);
        tile[row][c4 * 4 + 2] = f2bf(v.z);
        tile[row][c4 * 4 + 3] = f2bf(v.w);
    }
    __syncthreads();
#pragma unroll
    for (int r = 0; r < 2; ++r) {
        int idx = tid + r * 256;
        int n = idx >> 3, k8 = idx & 7;
        uint4 o;
        unsigned q[4];
#pragma unroll
        for (int j = 0; j < 4; ++j)
            q[j] = (unsigned)tile[k8 * 8 + 2 * j][n] | ((unsigned)tile[k8 * 8 + 2 * j + 1][n] << 16);
        o.x = q[0]; o.y = q[1]; o.z = q[2]; o.w = q[3];
        *(uint4*)&WT[((size_t)(bx * 64 + n)) * EMB_ + by * 64 + k8 * 8] = o;
    }
}

// ------------------------------- fused QKV GEMM (one launch, m97-style body)
// Bt = contiguous [Wk; Wv; Wq]^T (3072 x 1024). nt<8 -> Yk, nt<16 -> Yv,
// nt<24 -> Yq (only x-rows: tile (mt&31)<16; context-row Q blocks exit).
__global__ __launch_bounds__(256) void gemm_qkv_k(
    const unsigned short* __restrict__ A,     // xcb [8192][1024]
    const unsigned short* __restrict__ Bt,    // [3072][1024]
    unsigned short* __restrict__ Yk,
    unsigned short* __restrict__ Yv,
    unsigned short* __restrict__ Yq) {
    constexpr int KTOT = 1024, NTOT = 1024;
    int nt = blockIdx.x, mt = blockIdx.y;
    if (nt >= 16 && (mt & 31) >= 16) return;  // Q over context rows: no output
    __shared__ __align__(16) unsigned short As[128 * 32];
    __shared__ __align__(16) unsigned short Bs[128 * 32];
    int in_row0 = mt * 128;
    unsigned short* Cout;
    int col0, out_row0;
    if (nt < 8)       { Cout = Yk; col0 = nt * 128;        out_row0 = mt * 128; }
    else if (nt < 16) { Cout = Yv; col0 = (nt - 8) * 128;  out_row0 = mt * 128; }
    else              { Cout = Yq; col0 = (nt - 16) * 128;
                        out_row0 = (mt >> 5) * 2048 + (mt & 31) * 128; }
    int tid = threadIdx.x, w = tid >> 6, l = tid & 63, l15 = l & 15, lg = l >> 4;
    int wr = (w >> 1) * 64, wc = (w & 1) * 64;

    f32x4 zero4 = {0.f, 0.f, 0.f, 0.f};
    f32x4 acc[4][4];
#pragma unroll
    for (int i = 0; i < 4; ++i)
#pragma unroll
        for (int j = 0; j < 4; ++j) acc[i][j] = zero4;

    for (int k0 = 0; k0 < KTOT; k0 += 32) {
#pragma unroll
        for (int j = 0; j < 2; ++j) {
            int o = tid * 16 + j * 4096;
            int row = o >> 6;
            int ke = (o & 63) >> 1;
            __builtin_amdgcn_global_load_lds(
                (const __attribute__((address_space(1))) void*)&A[(size_t)(in_row0 + row) * KTOT + k0 + ke],
                (__attribute__((address_space(3))) void*)&As[o >> 1], 16, 0, 0);
            __builtin_amdgcn_global_load_lds(
                (const __attribute__((address_space(1))) void*)&Bt[(size_t)(nt * 128 + row) * KTOT + k0 + ke],
                (__attribute__((address_space(3))) void*)&Bs[o >> 1], 16, 0, 0);
        }
        __syncthreads();
        bf16x8 af[4], bf[4];
#pragma unroll
        for (int fr = 0; fr < 4; ++fr)
            af[fr] = *(const bf16x8*)&As[(wr + fr * 16 + l15) * 32 + lg * 8];
#pragma unroll
        for (int fc = 0; fc < 4; ++fc)
            bf[fc] = *(const bf16x8*)&Bs[(wc + fc * 16 + l15) * 32 + lg * 8];
#pragma unroll
        for (int fr = 0; fr < 4; ++fr)
#pragma unroll
            for (int fc = 0; fc < 4; ++fc)
                acc[fr][fc] = __builtin_amdgcn_mfma_f32_16x16x32_bf16(af[fr], bf[fc], acc[fr][fc], 0, 0, 0);
        __syncthreads();
    }
#pragma unroll
    for (int fr = 0; fr < 4; ++fr) {
#pragma unroll
        for (int fc = 0; fc < 4; ++fc) {
            int row = out_row0 + wr + fr * 16 + lg * 4;
            int col = col0 + wc + fc * 16 + l15;
#pragma unroll
            for (int i = 0; i < 4; ++i)
                Cout[(size_t)(row + i) * NTOT + col] = f2bf(acc[fr][fc][i]);
        }
    }
}

// ---------------------------------------------------------------- GEMM (m97-style)
template <bool F32OUT>
__global__ __launch_bounds__(256) void gemm_bt_k(
    const unsigned short* __restrict__ A,
    const unsigned short* __restrict__ Bt,
    void* __restrict__ Cout,
    const float* __restrict__ bias,
    int mtiles_per_chunk, int chunk_stride) {
    constexpr int KTOT = 1024, NTOT = 1024;
    __shared__ __align__(16) unsigned short As[128 * 32];
    __shared__ __align__(16) unsigned short Bs[128 * 32];
    int nt = blockIdx.x, mt = blockIdx.y;
    int in_row0 = (mt / mtiles_per_chunk) * chunk_stride + (mt % mtiles_per_chunk) * 128;
    int out_row0 = mt * 128;
    int tid = threadIdx.x, w = tid >> 6, l = tid & 63, l15 = l & 15, lg = l >> 4;
    int wr = (w >> 1) * 64, wc = (w & 1) * 64;

    f32x4 zero4 = {0.f, 0.f, 0.f, 0.f};
    f32x4 acc[4][4];
#pragma unroll
    for (int i = 0; i < 4; ++i)
#pragma unroll
        for (int j = 0; j < 4; ++j) acc[i][j] = zero4;

    for (int k0 = 0; k0 < KTOT; k0 += 32) {
#pragma unroll
        for (int j = 0; j < 2; ++j) {
            int o = tid * 16 + j * 4096;
            int row = o >> 6;
            int ke = (o & 63) >> 1;
            __builtin_amdgcn_global_load_lds(
                (const __attribute__((address_space(1))) void*)&A[(size_t)(in_row0 + row) * KTOT + k0 + ke],
                (__attribute__((address_space(3))) void*)&As[o >> 1], 16, 0, 0);
            __builtin_amdgcn_global_load_lds(
                (const __attribute__((address_space(1))) void*)&Bt[(size_t)(nt * 128 + row) * KTOT + k0 + ke],
                (__attribute__((address_space(3))) void*)&Bs[o >> 1], 16, 0, 0);
        }
        __syncthreads();
        bf16x8 af[4], bf[4];
#pragma unroll
        for (int fr = 0; fr < 4; ++fr)
            af[fr] = *(const bf16x8*)&As[(wr + fr * 16 + l15) * 32 + lg * 8];
#pragma unroll
        for (int fc = 0; fc < 4; ++fc)
            bf[fc] = *(const bf16x8*)&Bs[(wc + fc * 16 + l15) * 32 + lg * 8];
#pragma unroll
        for (int fr = 0; fr < 4; ++fr)
#pragma unroll
            for (int fc = 0; fc < 4; ++fc)
                acc[fr][fc] = __builtin_amdgcn_mfma_f32_16x16x32_bf16(af[fr], bf[fc], acc[fr][fc], 0, 0, 0);
        __syncthreads();
    }
#pragma unroll
    for (int fr = 0; fr < 4; ++fr) {
#pragma unroll
        for (int fc = 0; fc < 4; ++fc) {
            int row = out_row0 + wr + fr * 16 + lg * 4;
            int col = nt * 128 + wc + fc * 16 + l15;
#pragma unroll
            for (int i = 0; i < 4; ++i) {
                float v = acc[fr][fc][i];
                if (F32OUT) {
                    ((float*)Cout)[(size_t)(row + i) * NTOT + col] = v + bias[col];
                } else {
                    ((unsigned short*)Cout)[(size_t)(row + i) * NTOT + col] = f2bf(v);
                }
            }
        }
    }
}

// ----------------------- Q LayerNorm (+scale*log2e, mask-fold mq into rows)
__global__ void ln_head_k(const unsigned short* __restrict__ Y,
                          unsigned short* __restrict__ Out,
                          const float* __restrict__ lw, const float* __restrict__ lb,
                          const float* __restrict__ Mcat,
                          int rows_per_b, float scale) {
    int gw = blockIdx.x * 4 + (threadIdx.x >> 6);
    int lane = threadIdx.x & 63;
    int h = gw % HEADS_;
    int row = gw / HEADS_;                   // [0, B*rows_per_b)
    int b = row / rows_per_b, r = row % rows_per_b;
    float v = bf2f(Y[(size_t)row * EMB_ + h * 64 + lane]);
    float s = v, s2 = v * v;
#pragma unroll
    for (int m = 1; m <= 32; m <<= 1) {
        s += __shfl_xor(s, m);
        s2 += __shfl_xor(s2, m);
    }
    float mu = s * (1.f / 64.f);
    float var = s2 * (1.f / 64.f) - mu * mu;
    float o = (v - mu) * rsqrtf(var + 1e-5f) * lw[lane] + lb[lane];
    float mq = Mcat[(size_t)b * T_LEN + r];  // r < S
    Out[(((size_t)b * HEADS_ + h) * rows_per_b + r) * 64 + lane] = f2bf(o * scale * mq);
}

// ------------- K LayerNorm + pack into MFMA-fragment order (mt folded in)
// KF[bh][kt][s][l][j] = K[t=kt*32+(l&31)][d = s*16 + (l>>5)*8 + j] * mt
__global__ void ln_head_pack_k(const unsigned short* __restrict__ Y,
                               unsigned short* __restrict__ KF,
                               const float* __restrict__ lw, const float* __restrict__ lb,
                               const float* __restrict__ Mcat,
                               float scale) {
    int gw = blockIdx.x * 4 + (threadIdx.x >> 6);
    int lane = threadIdx.x & 63;
    int h = gw % HEADS_;
    int row = gw / HEADS_;                   // [0, B*T)
    int b = row / T_LEN, r = row % T_LEN;
    float v = bf2f(Y[(size_t)row * EMB_ + h * 64 + lane]);
    float s = v, s2 = v * v;
#pragma unroll
    for (int m = 1; m <= 32; m <<= 1) {
        s += __shfl_xor(s, m);
        s2 += __shfl_xor(s2, m);
    }
    float mu = s * (1.f / 64.f);
    float var = s2 * (1.f / 64.f) - mu * mu;
    float o = (v - mu) * rsqrtf(var + 1e-5f) * lw[lane] + lb[lane];
    float mt = Mcat[(size_t)b * T_LEN + r];
    int bh = b * HEADS_ + h;
    int kt = r >> 5, l31 = r & 31;
    int sf = lane >> 4, hi = (lane >> 3) & 1, j = lane & 7;
    size_t flat = ((((size_t)bh * 128 + kt) * 4 + sf) * 64 + hi * 32 + l31) * 8 + j;
    KF[flat] = f2bf(o * scale * mt);
}

// ------------------------- V pack into MFMA-fragment order (mt folded in)
// VF[bh][kt][f][l][j] = V^T[d][t] * mt:
//   d = (f>>1)*32 + (l&31)
//   t = kt*32 + (f&1)*16 + (j>>2)*8 + 4*(l>>5) + (j&3)
__global__ void vpack_k(const unsigned short* __restrict__ Yv, unsigned short* __restrict__ VF,
                        const float* __restrict__ Mcat) {
    __shared__ __align__(16) unsigned short tile[64][72];   // [t][d]
    __shared__ float msk[64];
    int t0 = blockIdx.x * 64;      // 64 t-rows = 2 kt tiles
    int bh = blockIdx.y;
    int b = bh >> 4, h = bh & 15;
    int tid = threadIdx.x;
    if (tid < 64) msk[tid] = Mcat[(size_t)b * T_LEN + t0 + tid];
#pragma unroll
    for (int rr = 0; rr < 2; ++rr) {
        int idx = tid + rr * 256;
        int row = idx >> 3, c8 = idx & 7;
        *(uint4*)&tile[row][c8 * 8] =
            *(const uint4*)&Yv[((size_t)b * T_LEN + t0 + row) * EMB_ + h * 64 + c8 * 8];
    }
    __syncthreads();
    int f = tid >> 6, l = tid & 63;
    int d = (f >> 1) * 32 + (l & 31);
    int tb = (f & 1) * 16 + 4 * (l >> 5);
#pragma unroll
    for (int ktl = 0; ktl < 2; ++ktl) {
        unsigned short e[8];
#pragma unroll
        for (int j = 0; j < 8; ++j) {
            int tt = ktl * 32 + tb + (j >> 2) * 8 + (j & 3);
            e[j] = f2bf(bf2f(tile[tt][d]) * msk[tt]);
        }
        uint4 o;
        o.x = (unsigned)e[0] | ((unsigned)e[1] << 16);
        o.y = (unsigned)e[2] | ((unsigned)e[3] << 16);
        o.z = (unsigned)e[4] | ((unsigned)e[5] << 16);
        o.w = (unsigned)e[6] | ((unsigned)e[7] << 16);
        size_t kt = (size_t)blockIdx.x * 2 + ktl;
        *(uint4*)&VF[((((size_t)bh * 128 + kt) * 4 + f) * 64 + l) * 8] = o;
    }
}

// ---------------------------------------------------------- flash attention
// Masks pre-folded; max-free softmax (p = exp2(sa) directly). K AND V both
// double-buffered (prefetch into the OTHER buffer, one full iteration ahead
// - the proven-safe pattern; never reload a buffer just consumed by MFMA).
#define SOFTMAX(SA, LS, PB0, PB1) do {                                            \
    f32x2 e2[8];                                                                  \
    _Pragma("unroll") for (int i_ = 0; i_ < 8; ++i_) {                            \
        e2[i_][0] = __builtin_amdgcn_exp2f(SA[2 * i_]);                           \
        e2[i_][1] = __builtin_amdgcn_exp2f(SA[2 * i_ + 1]);                       \
    }                                                                             \
    {                                                                             \
        float rsA_ = 0.f, rsB_ = 0.f;                                             \
        _Pragma("unroll") for (int i_ = 0; i_ < 8; ++i_) {                        \
            rsA_ = fmaf(e2[i_][0], mt_[2 * i_], rsA_);                            \
            rsB_ = fmaf(e2[i_][1], mt_[2 * i_ + 1], rsB_);                        \
        }                                                                         \
        float rs_ = rsA_ + rsB_;                                                  \
        rs_ += __shfl_xor(rs_, 32);                                               \
        (LS) += rs_;                                                              \
    }                                                                             \
    unsigned pk_[8];                                                              \
    _Pragma("unroll") for (int d_ = 0; d_ < 8; ++d_)                              \
        asm("v_cvt_pk_bf16_f32 %0, %1, %2" : "=v"(pk_[d_])                        \
            : "v"(e2[d_][0]), "v"(e2[d_][1]));                                    \
    { uint4 u0_; u0_.x=pk_[0]; u0_.y=pk_[1]; u0_.z=pk_[2]; u0_.w=pk_[3];          \
      uint4 u1_; u1_.x=pk_[4]; u1_.y=pk_[5]; u1_.z=pk_[6]; u1_.w=pk_[7];          \
      (PB0) = __builtin_bit_cast(bf16x8, u0_);                                    \
      (PB1) = __builtin_bit_cast(bf16x8, u1_); }                                  \
} while (0)

#define LOADK(DST, KT) do {                                                       \
    const unsigned short* p_ = KFl + (size_t)(KT) * 2048;                         \
    DST[0] = *(const uint4*)(p_);                                                 \
    DST[1] = *(const uint4*)(p_ + 512);                                           \
    DST[2] = *(const uint4*)(p_ + 1024);                                          \
    DST[3] = *(const uint4*)(p_ + 1536);                                          \
} while (0)

#define LOADV(DST, KT) do {                                                       \
    const unsigned short* p_ = VFl + (size_t)(KT) * 2048;                         \
    DST[0] = *(const uint4*)(p_);                                                 \
    DST[1] = *(const uint4*)(p_ + 512);                                           \
    DST[2] = *(const uint4*)(p_ + 1024);                                          \
    DST[3] = *(const uint4*)(p_ + 1536);                                          \
} while (0)

__global__ __launch_bounds__(256) void attn32_k(
    const unsigned short* __restrict__ Q,    // [B,H,S,64], pre-scaled (log2e, mq)
    const unsigned short* __restrict__ KF,   // fragment-packed K (mt folded)
    const unsigned short* __restrict__ VF,   // fragment-packed V^T (mt folded)
    const float* __restrict__ Mcat,          // [B,T]
    unsigned short* __restrict__ O) {        // [B,S,EMB]
    __shared__ float Olds[4][32][64];
    __shared__ float Llds[4][64];

    // XCD swizzle: each XCD owns 4 consecutive bh -> K/V fits its private L2.
    int bid = blockIdx.x;
    int xcd = bid & 7, slot = bid >> 3;        // 8 XCDs x 128 slots
    int bh = xcd * 4 + (slot >> 5);            // 4 bh per XCD
    int qblk = slot & 31;                      // 32 q-blocks of 64 rows
    int b = bh >> 4, h = bh & 15;
    int tid = threadIdx.x;
    int w = tid >> 6;
    int lane = tid & 63;
    int l31 = lane & 31;
    int hi = lane >> 5;
    int q0 = qblk * 64;

    const unsigned short* KFl = KF + (size_t)bh * 262144 + lane * 8;
    const unsigned short* VFl = VF + (size_t)bh * 262144 + lane * 8;
    const float* Mb = Mcat + (size_t)b * T_LEN;

    // Q fragments (held for whole kernel)
    bf16x8 qf0[4], qf1[4];
    {
        const unsigned short* Qp0 = Q + ((size_t)bh * S_LEN + q0 + l31) * 64 + hi * 8;
        const unsigned short* Qp1 = Qp0 + (size_t)32 * 64;
#pragma unroll
        for (int s = 0; s < 4; ++s) {
            qf0[s] = *(const bf16x8*)(Qp0 + s * 16);
            qf1[s] = *(const bf16x8*)(Qp1 + s * 16);
        }
    }

    f32x16 Z16;
#pragma unroll
    for (int i = 0; i < 16; ++i) Z16[i] = 0.f;
    f32x16 acc00 = Z16, acc01 = Z16, acc10 = Z16, acc11 = Z16;  // acc[db][qb]
    float lS0 = 0.f, lS1 = 0.f;

    auto TILE = [&](const uint4* kf, const uint4* vv, int kt) {
        // --- t-mask loads (denominator only; early-issued, late-used) ---
        const float* mbase = Mb + kt * 32 + 4 * hi;
        float4 mf0 = *(const float4*)(mbase);
        float4 mf1 = *(const float4*)(mbase + 8);
        float4 mf2 = *(const float4*)(mbase + 16);
        float4 mf3 = *(const float4*)(mbase + 24);
        // --- S^T = K · Q^T (masks pre-folded: sa IS z) ---
        f32x16 sa0 = Z16, sa1 = Z16;
#pragma unroll
        for (int s = 0; s < 4; ++s) {
            bf16x8 kfr = __builtin_bit_cast(bf16x8, kf[s]);
            sa0 = __builtin_amdgcn_mfma_f32_32x32x16_bf16(kfr, qf0[s], sa0, 0, 0, 0);
            sa1 = __builtin_amdgcn_mfma_f32_32x32x16_bf16(kfr, qf1[s], sa1, 0, 0, 0);
        }
        float mt_[16];
        mt_[0] = mf0.x; mt_[1] = mf0.y; mt_[2]  = mf0.z; mt_[3]  = mf0.w;
        mt_[4] = mf1.x; mt_[5] = mf1.y; mt_[6]  = mf1.z; mt_[7]  = mf1.w;
        mt_[8] = mf2.x; mt_[9] = mf2.y; mt_[10] = mf2.z; mt_[11] = mf2.w;
        mt_[12] = mf3.x; mt_[13] = mf3.y; mt_[14] = mf3.z; mt_[15] = mf3.w;
        // --- softmax numerator/denominator (no max tracking) ---
        bf16x8 p00, p01, p10, p11;
        SOFTMAX(sa0, lS0, p00, p01);
        SOFTMAX(sa1, lS1, p10, p11);
        // --- O^T += V^T · P^T (sigma-permuted k so P frags are lane-local) ---
        bf16x8 vf;
        vf = __builtin_bit_cast(bf16x8, vv[0]);
        acc00 = __builtin_amdgcn_mfma_f32_32x32x16_bf16(vf, p00, acc00, 0, 0, 0);
        acc01 = __builtin_amdgcn_mfma_f32_32x32x16_bf16(vf, p10, acc01, 0, 0, 0);
        vf = __builtin_bit_cast(bf16x8, vv[1]);
        acc00 = __builtin_amdgcn_mfma_f32_32x32x16_bf16(vf, p01, acc00, 0, 0, 0);
        acc01 = __builtin_amdgcn_mfma_f32_32x32x16_bf16(vf, p11, acc01, 0, 0, 0);
        vf = __builtin_bit_cast(bf16x8, vv[2]);
        acc10 = __builtin_amdgcn_mfma_f32_32x32x16_bf16(vf, p00, acc10, 0, 0, 0);
        acc11 = __builtin_amdgcn_mfma_f32_32x32x16_bf16(vf, p10, acc11, 0, 0, 0);
        vf = __builtin_bit_cast(bf16x8, vv[3]);
        acc10 = __builtin_amdgcn_mfma_f32_32x32x16_bf16(vf, p01, acc10, 0, 0, 0);
        acc11 = __builtin_amdgcn_mfma_f32_32x32x16_bf16(vf, p11, acc11, 0, 0, 0);
    };

    // --- main t-loop: wave w owns tiles kt = w+4i; K and V both prefetched
    // one iteration ahead into the alternate buffer (no same-reg reload).
    uint4 ka[4], kb[4], va[4], vb[4];
    LOADK(ka, w); LOADV(va, w);
    for (int it = 0; it < 32; it += 2) {
        int kt0 = w + it * 4;
        LOADK(kb, kt0 + 4); LOADV(vb, kt0 + 4);
        TILE(ka, va, kt0);
        int nxt = (it + 2 < 32) ? kt0 + 8 : kt0;
        LOADK(ka, nxt); LOADV(va, nxt);
        TILE(kb, vb, kt0 + 4);
    }

    // --- merge 4 waves' partial (l, O^T) via LDS, two d-halves (plain sums) ---
    if (hi == 0) {
        Llds[w][l31] = lS0;
        Llds[w][32 + l31] = lS1;
    }
    int qm = tid & 63;
    float invL;

    // pass 0: db = 0
#pragma unroll
    for (int r = 0; r < 16; ++r) {
        int dl = (r & 3) + 8 * (r >> 2) + 4 * hi;
        Olds[w][dl][l31] = acc00[r];
        Olds[w][dl][32 + l31] = acc01[r];
    }
    __syncthreads();
    {
        float L = Llds[0][qm] + Llds[1][qm] + Llds[2][qm] + Llds[3][qm];
        invL = 1.f / (L + 1e-13f);
        float mqz = Mb[q0 + qm];                // zero out rows with mq == 0
        invL = (mqz != 0.f) ? invL : 0.f;
    }
    {
        float v_[8];
#pragma unroll
        for (int dd = 0; dd < 8; ++dd) {
            int d = w * 8 + dd;
            v_[dd] = (Olds[0][d][qm] + Olds[1][d][qm] +
                      Olds[2][d][qm] + Olds[3][d][qm]) * invL;
        }
        unsigned po_[4];
#pragma unroll
        for (int d2 = 0; d2 < 4; ++d2)
            asm("v_cvt_pk_bf16_f32 %0, %1, %2" : "=v"(po_[d2]) : "v"(v_[2*d2]), "v"(v_[2*d2+1]));
        uint4 st; st.x = po_[0]; st.y = po_[1]; st.z = po_[2]; st.w = po_[3];
        *(uint4*)&O[((size_t)b * S_LEN + q0 + qm) * EMB_ + h * 64 + w * 8] = st;
    }
    __syncthreads();
    // pass 1: db = 1
#pragma unroll
    for (int r = 0; r < 16; ++r) {
        int dl = (r & 3) + 8 * (r >> 2) + 4 * hi;
        Olds[w][dl][l31] = acc10[r];
        Olds[w][dl][32 + l31] = acc11[r];
    }
    __syncthreads();
    {
        float v_[8];
#pragma unroll
        for (int dd = 0; dd < 8; ++dd) {
            int d = w * 8 + dd;
            v_[dd] = (Olds[0][d][qm] + Olds[1][d][qm] +
                      Olds[2][d][qm] + Olds[3][d][qm]) * invL;
        }
        unsigned po_[4];
#pragma unroll
        for (int d2 = 0; d2 < 4; ++d2)
            asm("v_cvt_pk_bf16_f32 %0, %1, %2" : "=v"(po_[d2]) : "v"(v_[2*d2]), "v"(v_[2*d2+1]));
        uint4 st; st.x = po_[0]; st.y = po_[1]; st.z = po_[2]; st.w = po_[3];
        *(uint4*)&O[((size_t)b * S_LEN + q0 + qm) * EMB_ + h * 64 + 32 + w * 8] = st;
    }
}

// ------------------------------------------------------------------ launch
extern "C" void kernel_launch(void* const* d_in, const int* in_sizes, int n_in,
                              void* d_out, int out_size, void* d_ws, size_t ws_size,
                              hipStream_t stream) {
    const float* x     = (const float*)d_in[0];
    const float* ctx   = (const float*)d_in[1];
    const float* mask  = (const float*)d_in[2];
    const float* cmask = (const float*)d_in[3];
    const float* Wq    = (const float*)d_in[4];
    const float* Wk    = (const float*)d_in[5];
    const float* Wv    = (const float*)d_in[6];
    const float* Wu    = (const float*)d_in[7];
    const float* bu    = (const float*)d_in[8];
    const float* qlnw  = (const float*)d_in[9];
    const float* qlnb  = (const float*)d_in[10];
    const float* klnw  = (const float*)d_in[11];
    const float* klnb  = (const float*)d_in[12];

    unsigned short* ws = (unsigned short*)d_ws;
    unsigned short* xcb = ws + 0;               //  8,388,608 elems
    // W^T in contiguous K|V|Q order for the fused QKV GEMM:
    unsigned short* WkT = ws + 8388608;         //  1,048,576
    unsigned short* WvT = ws + 9437184;
    unsigned short* WqT = ws + 10485760;
    unsigned short* Qb  = ws + 0;               //  4,194,304 (over dead xcb)
    unsigned short* KFb = ws + 4194304;         //  8,388,608 (over dead xcb/W*T)
    unsigned short* WuT = ws + 12582912;        //  1,048,576 (lives to the end)
    unsigned short* Yq  = ws + 13631488;        //  4,194,304 ; reused as O
    unsigned short* Ob  = Yq;
    unsigned short* Yk  = ws + 17825792;        //  8,388,608 ; reused as VF
    unsigned short* VFb = Yk;
    unsigned short* Yv  = ws + 26214400;        //  8,388,608
    float* Mcat         = (float*)(ws + 34603008);  // 8192 floats

    const float scale = 0.17677669529663687f;               // 1024^-0.25
    const float qscale = 0.17677669529663687f * 1.4426950408889634f; // * log2(e)

    build_xcb_k<<<4096, 256, 0, stream>>>(x, ctx, xcb);
    mcat_k<<<32, 256, 0, stream>>>(mask, cmask, Mcat);
    wtrans4_k<<<dim3(16, 16, 4), 256, 0, stream>>>(Wk, Wv, Wq, Wu, WkT, WvT, WqT, WuT);

    gemm_qkv_k<<<dim3(24, 64), 256, 0, stream>>>(xcb, WkT, Yk, Yv, Yq);

    ln_head_k<<<16384, 256, 0, stream>>>(Yq, Qb, qlnw, qlnb, Mcat, S_LEN, qscale);
    ln_head_pack_k<<<32768, 256, 0, stream>>>(Yk, KFb, klnw, klnb, Mcat, scale);
    vpack_k<<<dim3(64, 32), 256, 0, stream>>>(Yv, VFb, Mcat);

    attn32_k<<<1024, 256, 0, stream>>>(Qb, KFb, VFb, Mcat, Ob);

    gemm_bt_k<true><<<dim3(8, 32), 256, 0, stream>>>(Ob, WuT, d_out, bu, 32, 4096);
}

// Round 12
// 265.866 us; speedup vs baseline: 1.3320x; 1.0226x over previous
//
#include <hip/hip_runtime.h>
#include <hip/hip_bf16.h>
#include <cstdint>

#define B_SZ   2
#define S_LEN  2048
#define C_LEN  2048
#define T_LEN  4096
#define EMB_   1024
#define HEADS_ 16
#define D_     64

typedef __attribute__((ext_vector_type(8))) short bf16x8;
typedef __attribute__((ext_vector_type(4))) float f32x4;
typedef __attribute__((ext_vector_type(16))) float f32x16;
typedef __attribute__((ext_vector_type(2))) float f32x2;

__device__ __forceinline__ unsigned short f2bf(float f) {
    unsigned u = __builtin_bit_cast(unsigned, f);
    u += 0x7fffu + ((u >> 16) & 1u);
    return (unsigned short)(u >> 16);
}
__device__ __forceinline__ float bf2f(unsigned short h) {
    return __builtin_bit_cast(float, (unsigned)h << 16);
}

// ---------------------------------------------------------------- xcb build
__global__ void build_xcb_k(const float* __restrict__ x, const float* __restrict__ ctx,
                            unsigned short* __restrict__ xcb) {
    int i = blockIdx.x * blockDim.x + threadIdx.x;      // one 8-elem chunk
    size_t e8 = (size_t)i * 8;
    int b = (int)(e8 / ((size_t)T_LEN * EMB_));
    size_t rem = e8 % ((size_t)T_LEN * EMB_);
    int t = (int)(rem / EMB_);
    int c = (int)(rem % EMB_);
    const float* src = (t < S_LEN)
        ? &x[((size_t)b * S_LEN + t) * EMB_ + c]
        : &ctx[((size_t)b * C_LEN + (t - S_LEN)) * EMB_ + c];
    float4 v0 = ((const float4*)src)[0];
    float4 v1 = ((const float4*)src)[1];
    uint4 o;
    o.x = (unsigned)f2bf(v0.x) | ((unsigned)f2bf(v0.y) << 16);
    o.y = (unsigned)f2bf(v0.z) | ((unsigned)f2bf(v0.w) << 16);
    o.z = (unsigned)f2bf(v1.x) | ((unsigned)f2bf(v1.y) << 16);
    o.w = (unsigned)f2bf(v1.z) | ((unsigned)f2bf(v1.w) << 16);
    *(uint4*)&xcb[e8] = o;
}

// --------------------------------------------------------------- mask concat
__global__ void mcat_k(const float* __restrict__ mask, const float* __restrict__ cmask,
                       float* __restrict__ Mcat) {
    int i = blockIdx.x * 256 + threadIdx.x;   // B*T total
    int b = i / T_LEN, t = i % T_LEN;
    Mcat[i] = (t < S_LEN) ? mask[(size_t)b * S_LEN + t]
                          : cmask[(size_t)b * C_LEN + (t - S_LEN)];
}

// ---------------------- weight transpose+convert (all 4 weights, one launch)
__global__ void wtrans4_k(const float* __restrict__ W0, const float* __restrict__ W1,
                          const float* __restrict__ W2, const float* __restrict__ W3,
                          unsigned short* __restrict__ T0, unsigned short* __restrict__ T1,
                          unsigned short* __restrict__ T2, unsigned short* __restrict__ T3) {
    __shared__ __align__(16) unsigned short tile[64][72];
    int bx = blockIdx.x, by = blockIdx.y, bz = blockIdx.z;
    const float* W = (bz == 0) ? W0 : (bz == 1) ? W1 : (bz == 2) ? W2 : W3;
    unsigned short* WT = (bz == 0) ? T0 : (bz == 1) ? T1 : (bz == 2) ? T2 : T3;
    int tid = threadIdx.x;
#pragma unroll
    for (int r = 0; r < 4; ++r) {
        int idx = tid + r * 256;
        int row = idx >> 4, c4 = idx & 15;
        float4 v = ((const float4*)&W[((size_t)(by * 64 + row)) * EMB_ + bx * 64])[c4];
        tile[row][c4 * 4 + 0] = f2bf(v.x);
        tile[row][c4 * 4 + 1] = f2bf(v.y);
        tile[row][c4 * 4 + 2] = f2bf(v.z);
        tile[row][c4 * 4 + 3] = f2bf(v.w);
    }
    __syncthreads();
#pragma unroll
    for (int r = 0; r < 2; ++r) {
        int idx = tid + r * 256;
        int n = idx >> 3, k8 = idx & 7;
        uint4 o;
        unsigned q[4];
#pragma unroll
        for (int j = 0; j < 4; ++j)
            q[j] = (unsigned)tile[k8 * 8 + 2 * j][n] | ((unsigned)tile[k8 * 8 + 2 * j + 1][n] << 16);
        o.x = q[0]; o.y = q[1]; o.z = q[2]; o.w = q[3];
        *(uint4*)&WT[((size_t)(bx * 64 + n)) * EMB_ + by * 64 + k8 * 8] = o;
    }
}

// ------------------------------- fused QKV GEMM (one launch, m97-style body)
__global__ __launch_bounds__(256) void gemm_qkv_k(
    const unsigned short* __restrict__ A,     // xcb [8192][1024]
    const unsigned short* __restrict__ Bt,    // [3072][1024]
    unsigned short* __restrict__ Yk,
    unsigned short* __restrict__ Yv,
    unsigned short* __restrict__ Yq) {
    constexpr int KTOT = 1024, NTOT = 1024;
    int nt = blockIdx.x, mt = blockIdx.y;
    if (nt >= 16 && (mt & 31) >= 16) return;  // Q over context rows: no output
    __shared__ __align__(16) unsigned short As[128 * 32];
    __shared__ __align__(16) unsigned short Bs[128 * 32];
    int in_row0 = mt * 128;
    unsigned short* Cout;
    int col0, out_row0;
    if (nt < 8)       { Cout = Yk; col0 = nt * 128;        out_row0 = mt * 128; }
    else if (nt < 16) { Cout = Yv; col0 = (nt - 8) * 128;  out_row0 = mt * 128; }
    else              { Cout = Yq; col0 = (nt - 16) * 128;
                        out_row0 = (mt >> 5) * 2048 + (mt & 31) * 128; }
    int tid = threadIdx.x, w = tid >> 6, l = tid & 63, l15 = l & 15, lg = l >> 4;
    int wr = (w >> 1) * 64, wc = (w & 1) * 64;

    f32x4 zero4 = {0.f, 0.f, 0.f, 0.f};
    f32x4 acc[4][4];
#pragma unroll
    for (int i = 0; i < 4; ++i)
#pragma unroll
        for (int j = 0; j < 4; ++j) acc[i][j] = zero4;

    for (int k0 = 0; k0 < KTOT; k0 += 32) {
#pragma unroll
        for (int j = 0; j < 2; ++j) {
            int o = tid * 16 + j * 4096;
            int row = o >> 6;
            int ke = (o & 63) >> 1;
            __builtin_amdgcn_global_load_lds(
                (const __attribute__((address_space(1))) void*)&A[(size_t)(in_row0 + row) * KTOT + k0 + ke],
                (__attribute__((address_space(3))) void*)&As[o >> 1], 16, 0, 0);
            __builtin_amdgcn_global_load_lds(
                (const __attribute__((address_space(1))) void*)&Bt[(size_t)(nt * 128 + row) * KTOT + k0 + ke],
                (__attribute__((address_space(3))) void*)&Bs[o >> 1], 16, 0, 0);
        }
        __syncthreads();
        bf16x8 af[4], bf[4];
#pragma unroll
        for (int fr = 0; fr < 4; ++fr)
            af[fr] = *(const bf16x8*)&As[(wr + fr * 16 + l15) * 32 + lg * 8];
#pragma unroll
        for (int fc = 0; fc < 4; ++fc)
            bf[fc] = *(const bf16x8*)&Bs[(wc + fc * 16 + l15) * 32 + lg * 8];
#pragma unroll
        for (int fr = 0; fr < 4; ++fr)
#pragma unroll
            for (int fc = 0; fc < 4; ++fc)
                acc[fr][fc] = __builtin_amdgcn_mfma_f32_16x16x32_bf16(af[fr], bf[fc], acc[fr][fc], 0, 0, 0);
        __syncthreads();
    }
#pragma unroll
    for (int fr = 0; fr < 4; ++fr) {
#pragma unroll
        for (int fc = 0; fc < 4; ++fc) {
            int row = out_row0 + wr + fr * 16 + lg * 4;
            int col = col0 + wc + fc * 16 + l15;
#pragma unroll
            for (int i = 0; i < 4; ++i)
                Cout[(size_t)(row + i) * NTOT + col] = f2bf(acc[fr][fc][i]);
        }
    }
}

// ---------------------------------------------------------------- GEMM (m97-style)
template <bool F32OUT>
__global__ __launch_bounds__(256) void gemm_bt_k(
    const unsigned short* __restrict__ A,
    const unsigned short* __restrict__ Bt,
    void* __restrict__ Cout,
    const float* __restrict__ bias,
    int mtiles_per_chunk, int chunk_stride) {
    constexpr int KTOT = 1024, NTOT = 1024;
    __shared__ __align__(16) unsigned short As[128 * 32];
    __shared__ __align__(16) unsigned short Bs[128 * 32];
    int nt = blockIdx.x, mt = blockIdx.y;
    int in_row0 = (mt / mtiles_per_chunk) * chunk_stride + (mt % mtiles_per_chunk) * 128;
    int out_row0 = mt * 128;
    int tid = threadIdx.x, w = tid >> 6, l = tid & 63, l15 = l & 15, lg = l >> 4;
    int wr = (w >> 1) * 64, wc = (w & 1) * 64;

    f32x4 zero4 = {0.f, 0.f, 0.f, 0.f};
    f32x4 acc[4][4];
#pragma unroll
    for (int i = 0; i < 4; ++i)
#pragma unroll
        for (int j = 0; j < 4; ++j) acc[i][j] = zero4;

    for (int k0 = 0; k0 < KTOT; k0 += 32) {
#pragma unroll
        for (int j = 0; j < 2; ++j) {
            int o = tid * 16 + j * 4096;
            int row = o >> 6;
            int ke = (o & 63) >> 1;
            __builtin_amdgcn_global_load_lds(
                (const __attribute__((address_space(1))) void*)&A[(size_t)(in_row0 + row) * KTOT + k0 + ke],
                (__attribute__((address_space(3))) void*)&As[o >> 1], 16, 0, 0);
            __builtin_amdgcn_global_load_lds(
                (const __attribute__((address_space(1))) void*)&Bt[(size_t)(nt * 128 + row) * KTOT + k0 + ke],
                (__attribute__((address_space(3))) void*)&Bs[o >> 1], 16, 0, 0);
        }
        __syncthreads();
        bf16x8 af[4], bf[4];
#pragma unroll
        for (int fr = 0; fr < 4; ++fr)
            af[fr] = *(const bf16x8*)&As[(wr + fr * 16 + l15) * 32 + lg * 8];
#pragma unroll
        for (int fc = 0; fc < 4; ++fc)
            bf[fc] = *(const bf16x8*)&Bs[(wc + fc * 16 + l15) * 32 + lg * 8];
#pragma unroll
        for (int fr = 0; fr < 4; ++fr)
#pragma unroll
            for (int fc = 0; fc < 4; ++fc)
                acc[fr][fc] = __builtin_amdgcn_mfma_f32_16x16x32_bf16(af[fr], bf[fc], acc[fr][fc], 0, 0, 0);
        __syncthreads();
    }
#pragma unroll
    for (int fr = 0; fr < 4; ++fr) {
#pragma unroll
        for (int fc = 0; fc < 4; ++fc) {
            int row = out_row0 + wr + fr * 16 + lg * 4;
            int col = nt * 128 + wc + fc * 16 + l15;
#pragma unroll
            for (int i = 0; i < 4; ++i) {
                float v = acc[fr][fc][i];
                if (F32OUT) {
                    ((float*)Cout)[(size_t)(row + i) * NTOT + col] = v + bias[col];
                } else {
                    ((unsigned short*)Cout)[(size_t)(row + i) * NTOT + col] = f2bf(v);
                }
            }
        }
    }
}

// ----------------------- Q LayerNorm (+scale*log2e, mask-fold mq into rows)
__global__ void ln_head_k(const unsigned short* __restrict__ Y,
                          unsigned short* __restrict__ Out,
                          const float* __restrict__ lw, const float* __restrict__ lb,
                          const float* __restrict__ Mcat,
                          int rows_per_b, float scale) {
    int gw = blockIdx.x * 4 + (threadIdx.x >> 6);
    int lane = threadIdx.x & 63;
    int h = gw % HEADS_;
    int row = gw / HEADS_;                   // [0, B*rows_per_b)
    int b = row / rows_per_b, r = row % rows_per_b;
    float v = bf2f(Y[(size_t)row * EMB_ + h * 64 + lane]);
    float s = v, s2 = v * v;
#pragma unroll
    for (int m = 1; m <= 32; m <<= 1) {
        s += __shfl_xor(s, m);
        s2 += __shfl_xor(s2, m);
    }
    float mu = s * (1.f / 64.f);
    float var = s2 * (1.f / 64.f) - mu * mu;
    float o = (v - mu) * rsqrtf(var + 1e-5f) * lw[lane] + lb[lane];
    float mq = Mcat[(size_t)b * T_LEN + r];  // r < S
    Out[(((size_t)b * HEADS_ + h) * rows_per_b + r) * 64 + lane] = f2bf(o * scale * mq);
}

// ------------- K LayerNorm + pack into MFMA-fragment order (mt folded in)
// KF[bh][kt][s][l][j] = K[t=kt*32+(l&31)][d = s*16 + (l>>5)*8 + j] * mt
__global__ void ln_head_pack_k(const unsigned short* __restrict__ Y,
                               unsigned short* __restrict__ KF,
                               const float* __restrict__ lw, const float* __restrict__ lb,
                               const float* __restrict__ Mcat,
                               float scale) {
    int gw = blockIdx.x * 4 + (threadIdx.x >> 6);
    int lane = threadIdx.x & 63;
    int h = gw % HEADS_;
    int row = gw / HEADS_;                   // [0, B*T)
    int b = row / T_LEN, r = row % T_LEN;
    float v = bf2f(Y[(size_t)row * EMB_ + h * 64 + lane]);
    float s = v, s2 = v * v;
#pragma unroll
    for (int m = 1; m <= 32; m <<= 1) {
        s += __shfl_xor(s, m);
        s2 += __shfl_xor(s2, m);
    }
    float mu = s * (1.f / 64.f);
    float var = s2 * (1.f / 64.f) - mu * mu;
    float o = (v - mu) * rsqrtf(var + 1e-5f) * lw[lane] + lb[lane];
    float mt = Mcat[(size_t)b * T_LEN + r];
    int bh = b * HEADS_ + h;
    int kt = r >> 5, l31 = r & 31;
    int sf = lane >> 4, hi = (lane >> 3) & 1, j = lane & 7;
    size_t flat = ((((size_t)bh * 128 + kt) * 4 + sf) * 64 + hi * 32 + l31) * 8 + j;
    KF[flat] = f2bf(o * scale * mt);
}

// ------------------------- V pack into MFMA-fragment order (mt folded in)
__global__ void vpack_k(const unsigned short* __restrict__ Yv, unsigned short* __restrict__ VF,
                        const float* __restrict__ Mcat) {
    __shared__ __align__(16) unsigned short tile[64][72];   // [t][d]
    __shared__ float msk[64];
    int t0 = blockIdx.x * 64;      // 64 t-rows = 2 kt tiles
    int bh = blockIdx.y;
    int b = bh >> 4, h = bh & 15;
    int tid = threadIdx.x;
    if (tid < 64) msk[tid] = Mcat[(size_t)b * T_LEN + t0 + tid];
#pragma unroll
    for (int rr = 0; rr < 2; ++rr) {
        int idx = tid + rr * 256;
        int row = idx >> 3, c8 = idx & 7;
        *(uint4*)&tile[row][c8 * 8] =
            *(const uint4*)&Yv[((size_t)b * T_LEN + t0 + row) * EMB_ + h * 64 + c8 * 8];
    }
    __syncthreads();
    int f = tid >> 6, l = tid & 63;
    int d = (f >> 1) * 32 + (l & 31);
    int tb = (f & 1) * 16 + 4 * (l >> 5);
#pragma unroll
    for (int ktl = 0; ktl < 2; ++ktl) {
        unsigned short e[8];
#pragma unroll
        for (int j = 0; j < 8; ++j) {
            int tt = ktl * 32 + tb + (j >> 2) * 8 + (j & 3);
            e[j] = f2bf(bf2f(tile[tt][d]) * msk[tt]);
        }
        uint4 o;
        o.x = (unsigned)e[0] | ((unsigned)e[1] << 16);
        o.y = (unsigned)e[2] | ((unsigned)e[3] << 16);
        o.z = (unsigned)e[4] | ((unsigned)e[5] << 16);
        o.w = (unsigned)e[6] | ((unsigned)e[7] << 16);
        size_t kt = (size_t)blockIdx.x * 2 + ktl;
        *(uint4*)&VF[((((size_t)bh * 128 + kt) * 4 + f) * 64 + l) * 8] = o;
    }
}

// ---------------------------------------------------------- flash attention
// LDS-shared K/V (GEMM-proven 2-phase global_load_lds staging, double-buffered),
// 4 waves share each kt tile; each wave owns 32 q rows and sweeps ALL of T ->
// no cross-wave merge, grid 512 = 2 blocks/CU exactly (no tail round).
// Masks pre-folded; max-free softmax (p = exp2(sa) directly).
#define SOFTMAX(SA, LS, PB0, PB1) do {                                            \
    f32x2 e2[8];                                                                  \
    _Pragma("unroll") for (int i_ = 0; i_ < 8; ++i_) {                            \
        e2[i_][0] = __builtin_amdgcn_exp2f(SA[2 * i_]);                           \
        e2[i_][1] = __builtin_amdgcn_exp2f(SA[2 * i_ + 1]);                       \
    }                                                                             \
    {                                                                             \
        float rsA_ = 0.f, rsB_ = 0.f;                                             \
        _Pragma("unroll") for (int i_ = 0; i_ < 8; ++i_) {                        \
            rsA_ = fmaf(e2[i_][0], mt_[2 * i_], rsA_);                            \
            rsB_ = fmaf(e2[i_][1], mt_[2 * i_ + 1], rsB_);                        \
        }                                                                         \
        float rs_ = rsA_ + rsB_;                                                  \
        rs_ += __shfl_xor(rs_, 32);                                               \
        (LS) += rs_;                                                              \
    }                                                                             \
    unsigned pk_[8];                                                              \
    _Pragma("unroll") for (int d_ = 0; d_ < 8; ++d_)                              \
        asm("v_cvt_pk_bf16_f32 %0, %1, %2" : "=v"(pk_[d_])                        \
            : "v"(e2[d_][0]), "v"(e2[d_][1]));                                    \
    { uint4 u0_; u0_.x=pk_[0]; u0_.y=pk_[1]; u0_.z=pk_[2]; u0_.w=pk_[3];          \
      uint4 u1_; u1_.x=pk_[4]; u1_.y=pk_[5]; u1_.z=pk_[6]; u1_.w=pk_[7];          \
      (PB0) = __builtin_bit_cast(bf16x8, u0_);                                    \
      (PB1) = __builtin_bit_cast(bf16x8, u1_); }                                  \
} while (0)

__global__ __launch_bounds__(256) void attn32_k(
    const unsigned short* __restrict__ Q,    // [B,H,S,64], pre-scaled (log2e, mq)
    const unsigned short* __restrict__ KF,   // fragment-packed K (mt folded)
    const unsigned short* __restrict__ VF,   // fragment-packed V^T (mt folded)
    const float* __restrict__ Mcat,          // [B,T]
    unsigned short* __restrict__ O) {        // [B,S,EMB]
    __shared__ __align__(16) unsigned short Ks[2][2048];   // 4KB per buf
    __shared__ __align__(16) unsigned short Vs[2][2048];
    __shared__ float OldsF[4][64][32];                     // 32KB epilogue
    __shared__ float Llds[4][32];

    // XCD swizzle: each XCD owns 4 consecutive bh -> K/V fits its private L2.
    int bid = blockIdx.x;                      // 512 blocks
    int xcd = bid & 7, slot = bid >> 3;        // 8 XCDs x 64 slots
    int bh = xcd * 4 + (slot >> 4);            // 4 bh per XCD
    int qblk = slot & 15;                      // 16 q-blocks of 128 rows
    int b = bh >> 4, h = bh & 15;
    int tid = threadIdx.x;
    int w = tid >> 6;
    int lane = tid & 63;
    int l31 = lane & 31;
    int hi = lane >> 5;
    int q0 = qblk * 128;
    int qw = q0 + w * 32;                      // this wave's first q row

    const unsigned short* KFb_ = KF + (size_t)bh * 262144;
    const unsigned short* VFb_ = VF + (size_t)bh * 262144;
    const float* Mb = Mcat + (size_t)b * T_LEN;

    // Q fragments (held for whole kernel): 32 q rows per wave
    bf16x8 qf[4];
    {
        const unsigned short* Qp = Q + ((size_t)bh * S_LEN + qw + l31) * 64 + hi * 8;
#pragma unroll
        for (int s = 0; s < 4; ++s) qf[s] = *(const bf16x8*)(Qp + s * 16);
    }

    f32x16 Z16;
#pragma unroll
    for (int i = 0; i < 16; ++i) Z16[i] = 0.f;
    f32x16 acc0 = Z16, acc1 = Z16;             // O^T: d 0..31 / 32..63 x 32 q
    float lS = 0.f;

#define STAGE(BUF, KT) do {                                                        \
    __builtin_amdgcn_global_load_lds(                                              \
        (const __attribute__((address_space(1))) void*)(KFb_ + (size_t)(KT) * 2048 + tid * 8), \
        (__attribute__((address_space(3))) void*)&Ks[BUF][tid * 8], 16, 0, 0);     \
    __builtin_amdgcn_global_load_lds(                                              \
        (const __attribute__((address_space(1))) void*)(VFb_ + (size_t)(KT) * 2048 + tid * 8), \
        (__attribute__((address_space(3))) void*)&Vs[BUF][tid * 8], 16, 0, 0);     \
} while (0)

    STAGE(0, 0);
    __syncthreads();

    for (int kt = 0; kt < 128; ++kt) {
        int cur = kt & 1;
        if (kt + 1 < 128) STAGE(cur ^ 1, kt + 1);   // prefetch next tile
        // --- t-mask loads (denominator only) ---
        const float* mbase = Mb + kt * 32 + 4 * hi;
        float4 mf0 = *(const float4*)(mbase);
        float4 mf1 = *(const float4*)(mbase + 8);
        float4 mf2 = *(const float4*)(mbase + 16);
        float4 mf3 = *(const float4*)(mbase + 24);
        // --- LDS -> fragment regs (linear 16B/lane, conflict-free) ---
        bf16x8 kfr[4], vfr[4];
#pragma unroll
        for (int s = 0; s < 4; ++s) {
            kfr[s] = *(const bf16x8*)&Ks[cur][s * 512 + lane * 8];
            vfr[s] = *(const bf16x8*)&Vs[cur][s * 512 + lane * 8];
        }
        // --- S^T = K · Q^T (masks pre-folded: sa IS z) ---
        f32x16 sa = Z16;
#pragma unroll
        for (int s = 0; s < 4; ++s)
            sa = __builtin_amdgcn_mfma_f32_32x32x16_bf16(kfr[s], qf[s], sa, 0, 0, 0);
        float mt_[16];
        mt_[0] = mf0.x; mt_[1] = mf0.y; mt_[2]  = mf0.z; mt_[3]  = mf0.w;
        mt_[4] = mf1.x; mt_[5] = mf1.y; mt_[6]  = mf1.z; mt_[7]  = mf1.w;
        mt_[8] = mf2.x; mt_[9] = mf2.y; mt_[10] = mf2.z; mt_[11] = mf2.w;
        mt_[12] = mf3.x; mt_[13] = mf3.y; mt_[14] = mf3.z; mt_[15] = mf3.w;
        // --- softmax numerator/denominator (no max tracking) ---
        bf16x8 p0, p1;
        SOFTMAX(sa, lS, p0, p1);
        // --- O^T += V^T · P^T ---
        acc0 = __builtin_amdgcn_mfma_f32_32x32x16_bf16(vfr[0], p0, acc0, 0, 0, 0);
        acc0 = __builtin_amdgcn_mfma_f32_32x32x16_bf16(vfr[1], p1, acc0, 0, 0, 0);
        acc1 = __builtin_amdgcn_mfma_f32_32x32x16_bf16(vfr[2], p0, acc1, 0, 0, 0);
        acc1 = __builtin_amdgcn_mfma_f32_32x32x16_bf16(vfr[3], p1, acc1, 0, 0, 0);
        __syncthreads();   // reads of buf[cur] done; prefetch drained
    }
#undef STAGE

    // --- per-wave epilogue: LDS transpose for coalesced O writes ---
#pragma unroll
    for (int r = 0; r < 16; ++r) {
        int dl = (r & 3) + 8 * (r >> 2) + 4 * hi;
        OldsF[w][dl][l31] = acc0[r];
        OldsF[w][dl + 32][l31] = acc1[r];
    }
    if (hi == 0) Llds[w][l31] = lS;
    __syncthreads();
    {
        int rr = lane >> 1, hf = lane & 1;     // lane -> (q row, d half)
        float L = Llds[w][rr];
        float invL = 1.f / (L + 1e-13f);
        float mqz = Mb[q0 + w * 32 + rr];      // zero out rows with mq == 0
        invL = (mqz != 0.f) ? invL : 0.f;
        float v_[32];
#pragma unroll
        for (int dd = 0; dd < 32; ++dd)
            v_[dd] = OldsF[w][hf * 32 + dd][rr] * invL;
        unsigned po_[16];
#pragma unroll
        for (int d2 = 0; d2 < 16; ++d2)
            asm("v_cvt_pk_bf16_f32 %0, %1, %2" : "=v"(po_[d2]) : "v"(v_[2*d2]), "v"(v_[2*d2+1]));
        unsigned short* Orow = &O[((size_t)b * S_LEN + qw + rr) * EMB_ + h * 64 + hf * 32];
#pragma unroll
        for (int i = 0; i < 4; ++i) {
            uint4 st;
            st.x = po_[4*i]; st.y = po_[4*i+1]; st.z = po_[4*i+2]; st.w = po_[4*i+3];
            *(uint4*)(Orow + i * 8) = st;
        }
    }
}

// ------------------------------------------------------------------ launch
extern "C" void kernel_launch(void* const* d_in, const int* in_sizes, int n_in,
                              void* d_out, int out_size, void* d_ws, size_t ws_size,
                              hipStream_t stream) {
    const float* x     = (const float*)d_in[0];
    const float* ctx   = (const float*)d_in[1];
    const float* mask  = (const float*)d_in[2];
    const float* cmask = (const float*)d_in[3];
    const float* Wq    = (const float*)d_in[4];
    const float* Wk    = (const float*)d_in[5];
    const float* Wv    = (const float*)d_in[6];
    const float* Wu    = (const float*)d_in[7];
    const float* bu    = (const float*)d_in[8];
    const float* qlnw  = (const float*)d_in[9];
    const float* qlnb  = (const float*)d_in[10];
    const float* klnw  = (const float*)d_in[11];
    const float* klnb  = (const float*)d_in[12];

    unsigned short* ws = (unsigned short*)d_ws;
    unsigned short* xcb = ws + 0;               //  8,388,608 elems
    // W^T in contiguous K|V|Q order for the fused QKV GEMM:
    unsigned short* WkT = ws + 8388608;         //  1,048,576
    unsigned short* WvT = ws + 9437184;
    unsigned short* WqT = ws + 10485760;
    unsigned short* Qb  = ws + 0;               //  4,194,304 (over dead xcb)
    unsigned short* KFb = ws + 4194304;         //  8,388,608 (over dead xcb/W*T)
    unsigned short* WuT = ws + 12582912;        //  1,048,576 (lives to the end)
    unsigned short* Yq  = ws + 13631488;        //  4,194,304 ; reused as O
    unsigned short* Ob  = Yq;
    unsigned short* Yk  = ws + 17825792;        //  8,388,608 ; reused as VF
    unsigned short* VFb = Yk;
    unsigned short* Yv  = ws + 26214400;        //  8,388,608
    float* Mcat         = (float*)(ws + 34603008);  // 8192 floats

    const float scale = 0.17677669529663687f;               // 1024^-0.25
    const float qscale = 0.17677669529663687f * 1.4426950408889634f; // * log2(e)

    build_xcb_k<<<4096, 256, 0, stream>>>(x, ctx, xcb);
    mcat_k<<<32, 256, 0, stream>>>(mask, cmask, Mcat);
    wtrans4_k<<<dim3(16, 16, 4), 256, 0, stream>>>(Wk, Wv, Wq, Wu, WkT, WvT, WqT, WuT);

    gemm_qkv_k<<<dim3(24, 64), 256, 0, stream>>>(xcb, WkT, Yk, Yv, Yq);

    ln_head_k<<<16384, 256, 0, stream>>>(Yq, Qb, qlnw, qlnb, Mcat, S_LEN, qscale);
    ln_head_pack_k<<<32768, 256, 0, stream>>>(Yk, KFb, klnw, klnb, Mcat, scale);
    vpack_k<<<dim3(64, 32), 256, 0, stream>>>(Yv, VFb, Mcat);

    attn32_k<<<512, 256, 0, stream>>>(Qb, KFb, VFb, Mcat, Ob);

    gemm_bt_k<true><<<dim3(8, 32), 256, 0, stream>>>(Ob, WuT, d_out, bu, 32, 4096);
}

// Round 13
// 239.054 us; speedup vs baseline: 1.4815x; 1.1122x over previous
//
#include <hip/hip_runtime.h>
#include <hip/hip_bf16.h>
#include <cstdint>

#define B_SZ   2
#define S_LEN  2048
#define C_LEN  2048
#define T_LEN  4096
#define EMB_   1024
#define HEADS_ 16
#define D_     64

typedef __attribute__((ext_vector_type(8))) short bf16x8;
typedef __attribute__((ext_vector_type(4))) float f32x4;
typedef __attribute__((ext_vector_type(16))) float f32x16;
typedef __attribute__((ext_vector_type(2))) float f32x2;

__device__ __forceinline__ unsigned short f2bf(float f) {
    unsigned u = __builtin_bit_cast(unsigned, f);
    u += 0x7fffu + ((u >> 16) & 1u);
    return (unsigned short)(u >> 16);
}
__device__ __forceinline__ float bf2f(unsigned short h) {
    return __builtin_bit_cast(float, (unsigned)h << 16);
}

// ---------------------------------------------------------------- xcb build
__global__ void build_xcb_k(const float* __restrict__ x, const float* __restrict__ ctx,
                            unsigned short* __restrict__ xcb) {
    int i = blockIdx.x * blockDim.x + threadIdx.x;      // one 8-elem chunk
    size_t e8 = (size_t)i * 8;
    int b = (int)(e8 / ((size_t)T_LEN * EMB_));
    size_t rem = e8 % ((size_t)T_LEN * EMB_);
    int t = (int)(rem / EMB_);
    int c = (int)(rem % EMB_);
    const float* src = (t < S_LEN)
        ? &x[((size_t)b * S_LEN + t) * EMB_ + c]
        : &ctx[((size_t)b * C_LEN + (t - S_LEN)) * EMB_ + c];
    float4 v0 = ((const float4*)src)[0];
    float4 v1 = ((const float4*)src)[1];
    uint4 o;
    o.x = (unsigned)f2bf(v0.x) | ((unsigned)f2bf(v0.y) << 16);
    o.y = (unsigned)f2bf(v0.z) | ((unsigned)f2bf(v0.w) << 16);
    o.z = (unsigned)f2bf(v1.x) | ((unsigned)f2bf(v1.y) << 16);
    o.w = (unsigned)f2bf(v1.z) | ((unsigned)f2bf(v1.w) << 16);
    *(uint4*)&xcb[e8] = o;
}

// --------------------------------------------------------------- mask concat
__global__ void mcat_k(const float* __restrict__ mask, const float* __restrict__ cmask,
                       float* __restrict__ Mcat) {
    int i = blockIdx.x * 256 + threadIdx.x;   // B*T total
    int b = i / T_LEN, t = i % T_LEN;
    Mcat[i] = (t < S_LEN) ? mask[(size_t)b * S_LEN + t]
                          : cmask[(size_t)b * C_LEN + (t - S_LEN)];
}

// ---------------------- weight transpose+convert (all 4 weights, one launch)
__global__ void wtrans4_k(const float* __restrict__ W0, const float* __restrict__ W1,
                          const float* __restrict__ W2, const float* __restrict__ W3,
                          unsigned short* __restrict__ T0, unsigned short* __restrict__ T1,
                          unsigned short* __restrict__ T2, unsigned short* __restrict__ T3) {
    __shared__ __align__(16) unsigned short tile[64][72];
    int bx = blockIdx.x, by = blockIdx.y, bz = blockIdx.z;
    const float* W = (bz == 0) ? W0 : (bz == 1) ? W1 : (bz == 2) ? W2 : W3;
    unsigned short* WT = (bz == 0) ? T0 : (bz == 1) ? T1 : (bz == 2) ? T2 : T3;
    int tid = threadIdx.x;
#pragma unroll
    for (int r = 0; r < 4; ++r) {
        int idx = tid + r * 256;
        int row = idx >> 4, c4 = idx & 15;
        float4 v = ((const float4*)&W[((size_t)(by * 64 + row)) * EMB_ + bx * 64])[c4];
        tile[row][c4 * 4 + 0] = f2bf(v.x);
        tile[row][c4 * 4 + 1] = f2bf(v.y);
        tile[row][c4 * 4 + 2] = f2bf(v.z);
        tile[row][c4 * 4 + 3] = f2bf(v.w);
    }
    __syncthreads();
#pragma unroll
    for (int r = 0; r < 2; ++r) {
        int idx = tid + r * 256;
        int n = idx >> 3, k8 = idx & 7;
        uint4 o;
        unsigned q[4];
#pragma unroll
        for (int j = 0; j < 4; ++j)
            q[j] = (unsigned)tile[k8 * 8 + 2 * j][n] | ((unsigned)tile[k8 * 8 + 2 * j + 1][n] << 16);
        o.x = q[0]; o.y = q[1]; o.z = q[2]; o.w = q[3];
        *(uint4*)&WT[((size_t)(bx * 64 + n)) * EMB_ + by * 64 + k8 * 8] = o;
    }
}

// ------------------------------- fused QKV GEMM (one launch, m97-style body)
__global__ __launch_bounds__(256) void gemm_qkv_k(
    const unsigned short* __restrict__ A,     // xcb [8192][1024]
    const unsigned short* __restrict__ Bt,    // [3072][1024]
    unsigned short* __restrict__ Yk,
    unsigned short* __restrict__ Yv,
    unsigned short* __restrict__ Yq) {
    constexpr int KTOT = 1024, NTOT = 1024;
    int nt = blockIdx.x, mt = blockIdx.y;
    if (nt >= 16 && (mt & 31) >= 16) return;  // Q over context rows: no output
    __shared__ __align__(16) unsigned short As[128 * 32];
    __shared__ __align__(16) unsigned short Bs[128 * 32];
    int in_row0 = mt * 128;
    unsigned short* Cout;
    int col0, out_row0;
    if (nt < 8)       { Cout = Yk; col0 = nt * 128;        out_row0 = mt * 128; }
    else if (nt < 16) { Cout = Yv; col0 = (nt - 8) * 128;  out_row0 = mt * 128; }
    else              { Cout = Yq; col0 = (nt - 16) * 128;
                        out_row0 = (mt >> 5) * 2048 + (mt & 31) * 128; }
    int tid = threadIdx.x, w = tid >> 6, l = tid & 63, l15 = l & 15, lg = l >> 4;
    int wr = (w >> 1) * 64, wc = (w & 1) * 64;

    f32x4 zero4 = {0.f, 0.f, 0.f, 0.f};
    f32x4 acc[4][4];
#pragma unroll
    for (int i = 0; i < 4; ++i)
#pragma unroll
        for (int j = 0; j < 4; ++j) acc[i][j] = zero4;

    for (int k0 = 0; k0 < KTOT; k0 += 32) {
#pragma unroll
        for (int j = 0; j < 2; ++j) {
            int o = tid * 16 + j * 4096;
            int row = o >> 6;
            int ke = (o & 63) >> 1;
            __builtin_amdgcn_global_load_lds(
                (const __attribute__((address_space(1))) void*)&A[(size_t)(in_row0 + row) * KTOT + k0 + ke],
                (__attribute__((address_space(3))) void*)&As[o >> 1], 16, 0, 0);
            __builtin_amdgcn_global_load_lds(
                (const __attribute__((address_space(1))) void*)&Bt[(size_t)(nt * 128 + row) * KTOT + k0 + ke],
                (__attribute__((address_space(3))) void*)&Bs[o >> 1], 16, 0, 0);
        }
        __syncthreads();
        bf16x8 af[4], bf[4];
#pragma unroll
        for (int fr = 0; fr < 4; ++fr)
            af[fr] = *(const bf16x8*)&As[(wr + fr * 16 + l15) * 32 + lg * 8];
#pragma unroll
        for (int fc = 0; fc < 4; ++fc)
            bf[fc] = *(const bf16x8*)&Bs[(wc + fc * 16 + l15) * 32 + lg * 8];
#pragma unroll
        for (int fr = 0; fr < 4; ++fr)
#pragma unroll
            for (int fc = 0; fc < 4; ++fc)
                acc[fr][fc] = __builtin_amdgcn_mfma_f32_16x16x32_bf16(af[fr], bf[fc], acc[fr][fc], 0, 0, 0);
        __syncthreads();
    }
#pragma unroll
    for (int fr = 0; fr < 4; ++fr) {
#pragma unroll
        for (int fc = 0; fc < 4; ++fc) {
            int row = out_row0 + wr + fr * 16 + lg * 4;
            int col = col0 + wc + fc * 16 + l15;
#pragma unroll
            for (int i = 0; i < 4; ++i)
                Cout[(size_t)(row + i) * NTOT + col] = f2bf(acc[fr][fc][i]);
        }
    }
}

// ---------------------------------------------------------------- GEMM (m97-style)
template <bool F32OUT>
__global__ __launch_bounds__(256) void gemm_bt_k(
    const unsigned short* __restrict__ A,
    const unsigned short* __restrict__ Bt,
    void* __restrict__ Cout,
    const float* __restrict__ bias,
    int mtiles_per_chunk, int chunk_stride) {
    constexpr int KTOT = 1024, NTOT = 1024;
    __shared__ __align__(16) unsigned short As[128 * 32];
    __shared__ __align__(16) unsigned short Bs[128 * 32];
    int nt = blockIdx.x, mt = blockIdx.y;
    int in_row0 = (mt / mtiles_per_chunk) * chunk_stride + (mt % mtiles_per_chunk) * 128;
    int out_row0 = mt * 128;
    int tid = threadIdx.x, w = tid >> 6, l = tid & 63, l15 = l & 15, lg = l >> 4;
    int wr = (w >> 1) * 64, wc = (w & 1) * 64;

    f32x4 zero4 = {0.f, 0.f, 0.f, 0.f};
    f32x4 acc[4][4];
#pragma unroll
    for (int i = 0; i < 4; ++i)
#pragma unroll
        for (int j = 0; j < 4; ++j) acc[i][j] = zero4;

    for (int k0 = 0; k0 < KTOT; k0 += 32) {
#pragma unroll
        for (int j = 0; j < 2; ++j) {
            int o = tid * 16 + j * 4096;
            int row = o >> 6;
            int ke = (o & 63) >> 1;
            __builtin_amdgcn_global_load_lds(
                (const __attribute__((address_space(1))) void*)&A[(size_t)(in_row0 + row) * KTOT + k0 + ke],
                (__attribute__((address_space(3))) void*)&As[o >> 1], 16, 0, 0);
            __builtin_amdgcn_global_load_lds(
                (const __attribute__((address_space(1))) void*)&Bt[(size_t)(nt * 128 + row) * KTOT + k0 + ke],
                (__attribute__((address_space(3))) void*)&Bs[o >> 1], 16, 0, 0);
        }
        __syncthreads();
        bf16x8 af[4], bf[4];
#pragma unroll
        for (int fr = 0; fr < 4; ++fr)
            af[fr] = *(const bf16x8*)&As[(wr + fr * 16 + l15) * 32 + lg * 8];
#pragma unroll
        for (int fc = 0; fc < 4; ++fc)
            bf[fc] = *(const bf16x8*)&Bs[(wc + fc * 16 + l15) * 32 + lg * 8];
#pragma unroll
        for (int fr = 0; fr < 4; ++fr)
#pragma unroll
            for (int fc = 0; fc < 4; ++fc)
                acc[fr][fc] = __builtin_amdgcn_mfma_f32_16x16x32_bf16(af[fr], bf[fc], acc[fr][fc], 0, 0, 0);
        __syncthreads();
    }
#pragma unroll
    for (int fr = 0; fr < 4; ++fr) {
#pragma unroll
        for (int fc = 0; fc < 4; ++fc) {
            int row = out_row0 + wr + fr * 16 + lg * 4;
            int col = nt * 128 + wc + fc * 16 + l15;
#pragma unroll
            for (int i = 0; i < 4; ++i) {
                float v = acc[fr][fc][i];
                if (F32OUT) {
                    ((float*)Cout)[(size_t)(row + i) * NTOT + col] = v + bias[col];
                } else {
                    ((unsigned short*)Cout)[(size_t)(row + i) * NTOT + col] = f2bf(v);
                }
            }
        }
    }
}

// ----------------------- Q LayerNorm (+scale*log2e, mask-fold mq into rows)
__global__ void ln_head_k(const unsigned short* __restrict__ Y,
                          unsigned short* __restrict__ Out,
                          const float* __restrict__ lw, const float* __restrict__ lb,
                          const float* __restrict__ Mcat,
                          int rows_per_b, float scale) {
    int gw = blockIdx.x * 4 + (threadIdx.x >> 6);
    int lane = threadIdx.x & 63;
    int h = gw % HEADS_;
    int row = gw / HEADS_;                   // [0, B*rows_per_b)
    int b = row / rows_per_b, r = row % rows_per_b;
    float v = bf2f(Y[(size_t)row * EMB_ + h * 64 + lane]);
    float s = v, s2 = v * v;
#pragma unroll
    for (int m = 1; m <= 32; m <<= 1) {
        s += __shfl_xor(s, m);
        s2 += __shfl_xor(s2, m);
    }
    float mu = s * (1.f / 64.f);
    float var = s2 * (1.f / 64.f) - mu * mu;
    float o = (v - mu) * rsqrtf(var + 1e-5f) * lw[lane] + lb[lane];
    float mq = Mcat[(size_t)b * T_LEN + r];  // r < S
    Out[(((size_t)b * HEADS_ + h) * rows_per_b + r) * 64 + lane] = f2bf(o * scale * mq);
}

// ------------- K LayerNorm + pack into MFMA-fragment order (mt folded in)
// KF[bh][kt][s][l][j] = K[t=kt*32+(l&31)][d = s*16 + (l>>5)*8 + j] * mt
__global__ void ln_head_pack_k(const unsigned short* __restrict__ Y,
                               unsigned short* __restrict__ KF,
                               const float* __restrict__ lw, const float* __restrict__ lb,
                               const float* __restrict__ Mcat,
                               float scale) {
    int gw = blockIdx.x * 4 + (threadIdx.x >> 6);
    int lane = threadIdx.x & 63;
    int h = gw % HEADS_;
    int row = gw / HEADS_;                   // [0, B*T)
    int b = row / T_LEN, r = row % T_LEN;
    float v = bf2f(Y[(size_t)row * EMB_ + h * 64 + lane]);
    float s = v, s2 = v * v;
#pragma unroll
    for (int m = 1; m <= 32; m <<= 1) {
        s += __shfl_xor(s, m);
        s2 += __shfl_xor(s2, m);
    }
    float mu = s * (1.f / 64.f);
    float var = s2 * (1.f / 64.f) - mu * mu;
    float o = (v - mu) * rsqrtf(var + 1e-5f) * lw[lane] + lb[lane];
    float mt = Mcat[(size_t)b * T_LEN + r];
    int bh = b * HEADS_ + h;
    int kt = r >> 5, l31 = r & 31;
    int sf = lane >> 4, hi = (lane >> 3) & 1, j = lane & 7;
    size_t flat = ((((size_t)bh * 128 + kt) * 4 + sf) * 64 + hi * 32 + l31) * 8 + j;
    KF[flat] = f2bf(o * scale * mt);
}

// ------------------------- V pack into MFMA-fragment order (mt folded in)
__global__ void vpack_k(const unsigned short* __restrict__ Yv, unsigned short* __restrict__ VF,
                        const float* __restrict__ Mcat) {
    __shared__ __align__(16) unsigned short tile[64][72];   // [t][d]
    __shared__ float msk[64];
    int t0 = blockIdx.x * 64;      // 64 t-rows = 2 kt tiles
    int bh = blockIdx.y;
    int b = bh >> 4, h = bh & 15;
    int tid = threadIdx.x;
    if (tid < 64) msk[tid] = Mcat[(size_t)b * T_LEN + t0 + tid];
#pragma unroll
    for (int rr = 0; rr < 2; ++rr) {
        int idx = tid + rr * 256;
        int row = idx >> 3, c8 = idx & 7;
        *(uint4*)&tile[row][c8 * 8] =
            *(const uint4*)&Yv[((size_t)b * T_LEN + t0 + row) * EMB_ + h * 64 + c8 * 8];
    }
    __syncthreads();
    int f = tid >> 6, l = tid & 63;
    int d = (f >> 1) * 32 + (l & 31);
    int tb = (f & 1) * 16 + 4 * (l >> 5);
#pragma unroll
    for (int ktl = 0; ktl < 2; ++ktl) {
        unsigned short e[8];
#pragma unroll
        for (int j = 0; j < 8; ++j) {
            int tt = ktl * 32 + tb + (j >> 2) * 8 + (j & 3);
            e[j] = f2bf(bf2f(tile[tt][d]) * msk[tt]);
        }
        uint4 o;
        o.x = (unsigned)e[0] | ((unsigned)e[1] << 16);
        o.y = (unsigned)e[2] | ((unsigned)e[3] << 16);
        o.z = (unsigned)e[4] | ((unsigned)e[5] << 16);
        o.w = (unsigned)e[6] | ((unsigned)e[7] << 16);
        size_t kt = (size_t)blockIdx.x * 2 + ktl;
        *(uint4*)&VF[((((size_t)bh * 128 + kt) * 4 + f) * 64 + l) * 8] = o;
    }
}

// ---------------------------------------------------------- flash attention
// LDS-shared K/V, 4-buffer ring, TWO kt tiles per barrier interval: stage
// pair {2i+2,2i+3} while computing pair {2i,2i+1} as two independent chains
// (saA/saB) -> 2x per-wave ILP on the QK/softmax chain, half the barriers,
// double the latency cover. Masks pre-folded; max-free softmax.
#define SOFTMAX(SA, MT, LS, PB0, PB1) do {                                        \
    f32x2 e2[8];                                                                  \
    _Pragma("unroll") for (int i_ = 0; i_ < 8; ++i_) {                            \
        e2[i_][0] = __builtin_amdgcn_exp2f(SA[2 * i_]);                           \
        e2[i_][1] = __builtin_amdgcn_exp2f(SA[2 * i_ + 1]);                       \
    }                                                                             \
    {                                                                             \
        float rsA_ = 0.f, rsB_ = 0.f;                                             \
        _Pragma("unroll") for (int i_ = 0; i_ < 8; ++i_) {                        \
            rsA_ = fmaf(e2[i_][0], MT[2 * i_], rsA_);                             \
            rsB_ = fmaf(e2[i_][1], MT[2 * i_ + 1], rsB_);                         \
        }                                                                         \
        float rs_ = rsA_ + rsB_;                                                  \
        rs_ += __shfl_xor(rs_, 32);                                               \
        (LS) += rs_;                                                              \
    }                                                                             \
    unsigned pk_[8];                                                              \
    _Pragma("unroll") for (int d_ = 0; d_ < 8; ++d_)                              \
        asm("v_cvt_pk_bf16_f32 %0, %1, %2" : "=v"(pk_[d_])                        \
            : "v"(e2[d_][0]), "v"(e2[d_][1]));                                    \
    { uint4 u0_; u0_.x=pk_[0]; u0_.y=pk_[1]; u0_.z=pk_[2]; u0_.w=pk_[3];          \
      uint4 u1_; u1_.x=pk_[4]; u1_.y=pk_[5]; u1_.z=pk_[6]; u1_.w=pk_[7];          \
      (PB0) = __builtin_bit_cast(bf16x8, u0_);                                    \
      (PB1) = __builtin_bit_cast(bf16x8, u1_); }                                  \
} while (0)

__global__ __launch_bounds__(256) void attn32_k(
    const unsigned short* __restrict__ Q,    // [B,H,S,64], pre-scaled (log2e, mq)
    const unsigned short* __restrict__ KF,   // fragment-packed K (mt folded)
    const unsigned short* __restrict__ VF,   // fragment-packed V^T (mt folded)
    const float* __restrict__ Mcat,          // [B,T]
    unsigned short* __restrict__ O) {        // [B,S,EMB]
    __shared__ __align__(16) unsigned short Ks[4][2048];   // 4KB per buf
    __shared__ __align__(16) unsigned short Vs[4][2048];
    __shared__ float OldsF[4][64][32];                     // 32KB epilogue
    __shared__ float Llds[4][32];

    // XCD swizzle: each XCD owns 4 consecutive bh -> K/V fits its private L2.
    int bid = blockIdx.x;                      // 512 blocks
    int xcd = bid & 7, slot = bid >> 3;        // 8 XCDs x 64 slots
    int bh = xcd * 4 + (slot >> 4);            // 4 bh per XCD
    int qblk = slot & 15;                      // 16 q-blocks of 128 rows
    int b = bh >> 4, h = bh & 15;
    int tid = threadIdx.x;
    int w = tid >> 6;
    int lane = tid & 63;
    int l31 = lane & 31;
    int hi = lane >> 5;
    int q0 = qblk * 128;
    int qw = q0 + w * 32;                      // this wave's first q row

    const unsigned short* KFb_ = KF + (size_t)bh * 262144;
    const unsigned short* VFb_ = VF + (size_t)bh * 262144;
    const float* Mb = Mcat + (size_t)b * T_LEN;

    // Q fragments (held for whole kernel): 32 q rows per wave
    bf16x8 qf[4];
    {
        const unsigned short* Qp = Q + ((size_t)bh * S_LEN + qw + l31) * 64 + hi * 8;
#pragma unroll
        for (int s = 0; s < 4; ++s) qf[s] = *(const bf16x8*)(Qp + s * 16);
    }

    f32x16 Z16;
#pragma unroll
    for (int i = 0; i < 16; ++i) Z16[i] = 0.f;
    f32x16 acc0 = Z16, acc1 = Z16;             // O^T: d 0..31 / 32..63 x 32 q
    float lS = 0.f;

#define STAGE(BUF, KT) do {                                                        \
    __builtin_amdgcn_global_load_lds(                                              \
        (const __attribute__((address_space(1))) void*)(KFb_ + (size_t)(KT) * 2048 + tid * 8), \
        (__attribute__((address_space(3))) void*)&Ks[BUF][tid * 8], 16, 0, 0);     \
    __builtin_amdgcn_global_load_lds(                                              \
        (const __attribute__((address_space(1))) void*)(VFb_ + (size_t)(KT) * 2048 + tid * 8), \
        (__attribute__((address_space(3))) void*)&Vs[BUF][tid * 8], 16, 0, 0);     \
} while (0)

    STAGE(0, 0); STAGE(1, 1);
    __syncthreads();

    for (int it = 0; it < 64; ++it) {
        int base = (it & 1) << 1;              // compute bufs {base, base+1}
        int kt0 = it * 2;
        if (it < 63) {                          // stage next pair into other bufs
            STAGE(base ^ 2, kt0 + 2);
            STAGE((base ^ 2) + 1, kt0 + 3);
        }
        // --- t-mask loads for both tiles (denominator only) ---
        const float* mb0 = Mb + kt0 * 32 + 4 * hi;
        float4 am0 = *(const float4*)(mb0);
        float4 am1 = *(const float4*)(mb0 + 8);
        float4 am2 = *(const float4*)(mb0 + 16);
        float4 am3 = *(const float4*)(mb0 + 24);
        float4 bm0 = *(const float4*)(mb0 + 32);
        float4 bm1 = *(const float4*)(mb0 + 40);
        float4 bm2 = *(const float4*)(mb0 + 48);
        float4 bm3 = *(const float4*)(mb0 + 56);
        // --- LDS -> fragment regs (linear 16B/lane) ---
        bf16x8 kfrA[4], vfrA[4], kfrB[4], vfrB[4];
#pragma unroll
        for (int s = 0; s < 4; ++s) {
            kfrA[s] = *(const bf16x8*)&Ks[base][s * 512 + lane * 8];
            vfrA[s] = *(const bf16x8*)&Vs[base][s * 512 + lane * 8];
            kfrB[s] = *(const bf16x8*)&Ks[base + 1][s * 512 + lane * 8];
            vfrB[s] = *(const bf16x8*)&Vs[base + 1][s * 512 + lane * 8];
        }
        // --- S^T = K · Q^T : two independent chains ---
        f32x16 saA = Z16, saB = Z16;
#pragma unroll
        for (int s = 0; s < 4; ++s) {
            saA = __builtin_amdgcn_mfma_f32_32x32x16_bf16(kfrA[s], qf[s], saA, 0, 0, 0);
            saB = __builtin_amdgcn_mfma_f32_32x32x16_bf16(kfrB[s], qf[s], saB, 0, 0, 0);
        }
        float mtA_[16], mtB_[16];
        mtA_[0] = am0.x; mtA_[1] = am0.y; mtA_[2]  = am0.z; mtA_[3]  = am0.w;
        mtA_[4] = am1.x; mtA_[5] = am1.y; mtA_[6]  = am1.z; mtA_[7]  = am1.w;
        mtA_[8] = am2.x; mtA_[9] = am2.y; mtA_[10] = am2.z; mtA_[11] = am2.w;
        mtA_[12] = am3.x; mtA_[13] = am3.y; mtA_[14] = am3.z; mtA_[15] = am3.w;
        mtB_[0] = bm0.x; mtB_[1] = bm0.y; mtB_[2]  = bm0.z; mtB_[3]  = bm0.w;
        mtB_[4] = bm1.x; mtB_[5] = bm1.y; mtB_[6]  = bm1.z; mtB_[7]  = bm1.w;
        mtB_[8] = bm2.x; mtB_[9] = bm2.y; mtB_[10] = bm2.z; mtB_[11] = bm2.w;
        mtB_[12] = bm3.x; mtB_[13] = bm3.y; mtB_[14] = bm3.z; mtB_[15] = bm3.w;
        // --- softmax (two chains; compiler interleaves) ---
        bf16x8 p0A, p1A, p0B, p1B;
        SOFTMAX(saA, mtA_, lS, p0A, p1A);
        SOFTMAX(saB, mtB_, lS, p0B, p1B);
        // --- O^T += V^T · P^T for both tiles ---
        acc0 = __builtin_amdgcn_mfma_f32_32x32x16_bf16(vfrA[0], p0A, acc0, 0, 0, 0);
        acc1 = __builtin_amdgcn_mfma_f32_32x32x16_bf16(vfrA[2], p0A, acc1, 0, 0, 0);
        acc0 = __builtin_amdgcn_mfma_f32_32x32x16_bf16(vfrA[1], p1A, acc0, 0, 0, 0);
        acc1 = __builtin_amdgcn_mfma_f32_32x32x16_bf16(vfrA[3], p1A, acc1, 0, 0, 0);
        acc0 = __builtin_amdgcn_mfma_f32_32x32x16_bf16(vfrB[0], p0B, acc0, 0, 0, 0);
        acc1 = __builtin_amdgcn_mfma_f32_32x32x16_bf16(vfrB[2], p0B, acc1, 0, 0, 0);
        acc0 = __builtin_amdgcn_mfma_f32_32x32x16_bf16(vfrB[1], p1B, acc0, 0, 0, 0);
        acc1 = __builtin_amdgcn_mfma_f32_32x32x16_bf16(vfrB[3], p1B, acc1, 0, 0, 0);
        __syncthreads();   // reads of pair done; staged pair drained
    }
#undef STAGE

    // --- per-wave epilogue: LDS transpose for coalesced O writes ---
#pragma unroll
    for (int r = 0; r < 16; ++r) {
        int dl = (r & 3) + 8 * (r >> 2) + 4 * hi;
        OldsF[w][dl][l31] = acc0[r];
        OldsF[w][dl + 32][l31] = acc1[r];
    }
    if (hi == 0) Llds[w][l31] = lS;
    __syncthreads();
    {
        int rr = lane >> 1, hf = lane & 1;     // lane -> (q row, d half)
        float L = Llds[w][rr];
        float invL = 1.f / (L + 1e-13f);
        float mqz = Mb[q0 + w * 32 + rr];      // zero out rows with mq == 0
        invL = (mqz != 0.f) ? invL : 0.f;
        float v_[32];
#pragma unroll
        for (int dd = 0; dd < 32; ++dd)
            v_[dd] = OldsF[w][hf * 32 + dd][rr] * invL;
        unsigned po_[16];
#pragma unroll
        for (int d2 = 0; d2 < 16; ++d2)
            asm("v_cvt_pk_bf16_f32 %0, %1, %2" : "=v"(po_[d2]) : "v"(v_[2*d2]), "v"(v_[2*d2+1]));
        unsigned short* Orow = &O[((size_t)b * S_LEN + qw + rr) * EMB_ + h * 64 + hf * 32];
#pragma unroll
        for (int i = 0; i < 4; ++i) {
            uint4 st;
            st.x = po_[4*i]; st.y = po_[4*i+1]; st.z = po_[4*i+2]; st.w = po_[4*i+3];
            *(uint4*)(Orow + i * 8) = st;
        }
    }
}

// ------------------------------------------------------------------ launch
extern "C" void kernel_launch(void* const* d_in, const int* in_sizes, int n_in,
                              void* d_out, int out_size, void* d_ws, size_t ws_size,
                              hipStream_t stream) {
    const float* x     = (const float*)d_in[0];
    const float* ctx   = (const float*)d_in[1];
    const float* mask  = (const float*)d_in[2];
    const float* cmask = (const float*)d_in[3];
    const float* Wq    = (const float*)d_in[4];
    const float* Wk    = (const float*)d_in[5];
    const float* Wv    = (const float*)d_in[6];
    const float* Wu    = (const float*)d_in[7];
    const float* bu    = (const float*)d_in[8];
    const float* qlnw  = (const float*)d_in[9];
    const float* qlnb  = (const float*)d_in[10];
    const float* klnw  = (const float*)d_in[11];
    const float* klnb  = (const float*)d_in[12];

    unsigned short* ws = (unsigned short*)d_ws;
    unsigned short* xcb = ws + 0;               //  8,388,608 elems
    // W^T in contiguous K|V|Q order for the fused QKV GEMM:
    unsigned short* WkT = ws + 8388608;         //  1,048,576
    unsigned short* WvT = ws + 9437184;
    unsigned short* WqT = ws + 10485760;
    unsigned short* Qb  = ws + 0;               //  4,194,304 (over dead xcb)
    unsigned short* KFb = ws + 4194304;         //  8,388,608 (over dead xcb/W*T)
    unsigned short* WuT = ws + 12582912;        //  1,048,576 (lives to the end)
    unsigned short* Yq  = ws + 13631488;        //  4,194,304 ; reused as O
    unsigned short* Ob  = Yq;
    unsigned short* Yk  = ws + 17825792;        //  8,388,608 ; reused as VF
    unsigned short* VFb = Yk;
    unsigned short* Yv  = ws + 26214400;        //  8,388,608
    float* Mcat         = (float*)(ws + 34603008);  // 8192 floats

    const float scale = 0.17677669529663687f;               // 1024^-0.25
    const float qscale = 0.17677669529663687f * 1.4426950408889634f; // * log2(e)

    build_xcb_k<<<4096, 256, 0, stream>>>(x, ctx, xcb);
    mcat_k<<<32, 256, 0, stream>>>(mask, cmask, Mcat);
    wtrans4_k<<<dim3(16, 16, 4), 256, 0, stream>>>(Wk, Wv, Wq, Wu, WkT, WvT, WqT, WuT);

    gemm_qkv_k<<<dim3(24, 64), 256, 0, stream>>>(xcb, WkT, Yk, Yv, Yq);

    ln_head_k<<<16384, 256, 0, stream>>>(Yq, Qb, qlnw, qlnb, Mcat, S_LEN, qscale);
    ln_head_pack_k<<<32768, 256, 0, stream>>>(Yk, KFb, klnw, klnb, Mcat, scale);
    vpack_k<<<dim3(64, 32), 256, 0, stream>>>(Yv, VFb, Mcat);

    attn32_k<<<512, 256, 0, stream>>>(Qb, KFb, VFb, Mcat, Ob);

    gemm_bt_k<true><<<dim3(8, 32), 256, 0, stream>>>(Ob, WuT, d_out, bu, 32, 4096);
}